// Round 7
// baseline (460.591 us; speedup 1.0000x reference)
//
#include <hip/hip_runtime.h>
#include <hip/hip_bf16.h>

typedef __hip_bfloat16 bf16;
typedef __attribute__((ext_vector_type(8))) short short8;
typedef __attribute__((ext_vector_type(4))) short short4v;
typedef __attribute__((ext_vector_type(2))) short short2v;
typedef __attribute__((ext_vector_type(4))) float float4v;
typedef __attribute__((ext_vector_type(2))) float float2v;
__device__ __forceinline__ float b2f(bf16 v){ return __bfloat162float(v); }
__device__ __forceinline__ bf16 f2b(float v){ return __float2bfloat16(v); }
__device__ __forceinline__ void stv(float* p, long i, float v){ p[i] = v; }
__device__ __forceinline__ void stv(bf16*  p, long i, float v){ p[i] = f2b(v); }

#define MFMA __builtin_amdgcn_mfma_f32_16x16x32_bf16
#define AS1(p) ((const __attribute__((address_space(1))) void*)(p))
#define AS3(p) ((__attribute__((address_space(3))) void*)(p))

// Problem constants
#define BB   8
#define NN   2048
#define DIM  512
#define HID  2048
#define DQK  128
#define GRP  256
#define NG   8
#define KW   17
#define BK   32
#define NHQ  2176   // real merged N for h(2048) + qk(128)
#define NHQ2 2304   // padded to 9 x 256 so the 256-tile gemm handles qk too

// ---------------- LayerNorm: fp32 input, token-shift, float2-vectorized (all batches) ----
template<int D, int SHIFT_HALF>
__global__ __launch_bounds__(256) void ln_kernel_f(const float* __restrict__ in,
                                                   bf16* __restrict__ out)
{
    int row = blockIdx.x;
    int t = row % NN;
    int tid = threadIdx.x;
    int c0 = tid * 2;                      // D = 512, 2 floats/thread
    float2v v2 = {0.f, 0.f};
    if (SHIFT_HALF && c0 < D / 2) {
        if (t > 0) v2 = *(const float2v*)(in + ((long)row - 1) * D + c0);
    } else {
        v2 = *(const float2v*)(in + (long)row * D + c0);
    }
    float s = v2[0] + v2[1];
    float ss = v2[0] * v2[0] + v2[1] * v2[1];
    for (int o = 32; o > 0; o >>= 1) { s += __shfl_down(s, o); ss += __shfl_down(ss, o); }
    __shared__ float sm[4], sm2[4];
    int wid = tid >> 6, lane = tid & 63;
    if (lane == 0) { sm[wid] = s; sm2[wid] = ss; }
    __syncthreads();
    if (tid == 0) {
        float a = 0.f, q = 0.f;
        for (int w = 0; w < 4; w++) { a += sm[w]; q += sm2[w]; }
        sm[0] = a; sm2[0] = q;
    }
    __syncthreads();
    float mean = sm[0] / D;
    float var  = fmaxf(sm2[0] / D - mean * mean, 0.f);
    float rs = rsqrtf(var + 1e-5f);
    union { short2v v; bf16 h[2]; } o2;
    o2.h[0] = f2b((v2[0] - mean) * rs);
    o2.h[1] = f2b((v2[1] - mean) * rs);
    *(short2v*)(out + (long)row * D + c0) = o2.v;
}

// vectorized bf16 LN: D=1024, each thread owns 4 contiguous cols (8B loads/stores)
template<int D>
__global__ __launch_bounds__(256) void ln_kernel_bf(const bf16* __restrict__ in,
                                                    bf16* __restrict__ out)
{
    int row = blockIdx.x;
    int tid = threadIdx.x;
    int c0 = tid * 4;
    union { short4v v; bf16 h[4]; } u;
    u.v = *(const short4v*)(in + (long)row * D + c0);
    float vals[4];
    float s = 0.f, ss = 0.f;
    #pragma unroll
    for (int i = 0; i < 4; i++) {
        float v = b2f(u.h[i]);
        vals[i] = v; s += v; ss += v * v;
    }
    for (int o = 32; o > 0; o >>= 1) { s += __shfl_down(s, o); ss += __shfl_down(ss, o); }
    __shared__ float sm[4], sm2[4];
    int wid = tid >> 6, lane = tid & 63;
    if (lane == 0) { sm[wid] = s; sm2[wid] = ss; }
    __syncthreads();
    if (tid == 0) {
        float a = 0.f, q = 0.f;
        for (int w = 0; w < 4; w++) { a += sm[w]; q += sm2[w]; }
        sm[0] = a; sm2[0] = q;
    }
    __syncthreads();
    float mean = sm[0] / D;
    float var  = fmaxf(sm2[0] / D - mean * mean, 0.f);
    float rs = rsqrtf(var + 1e-5f);
    union { short4v v; bf16 h[4]; } o4;
    #pragma unroll
    for (int i = 0; i < 4; i++) o4.h[i] = f2b((vals[i] - mean) * rs);
    *(short4v*)(out + (long)row * D + c0) = o4.v;
}

// ---------------- merged weight prep: all 3 WT in one launch -----------------------------
__global__ __launch_bounds__(256) void prep_all(
    const float* __restrict__ W_h,  const float* __restrict__ g_h,  bf16* __restrict__ WT_h,
    const float* __restrict__ W_qk, const float* __restrict__ g_qk, bf16* __restrict__ WT_qk,
    const float* __restrict__ W_o,  const float* __restrict__ g_o,  bf16* __restrict__ WT_o)
{
    int i = blockIdx.x;
    const float *W, *g; bf16* WT; int K, N, k0, n0;
    if (i < 1024) {                 // W_h: K=512 (16 kb), N=2048 (64 nb)
        W = W_h; g = g_h; WT = WT_h; K = DIM; N = HID;
        k0 = (i & 15) * 32; n0 = (i >> 4) * 32;
    } else if (i < 1088) {          // W_qk: K=512 (16 kb), N=128 (4 nb)
        int j = i - 1024;
        W = W_qk; g = g_qk; WT = WT_qk; K = DIM; N = DQK;
        k0 = (j & 15) * 32; n0 = (j >> 4) * 32;
    } else {                        // W_o: K=1024 (32 kb), N=512 (16 nb)
        int j = i - 1088;
        W = W_o; g = g_o; WT = WT_o; K = 1024; N = DIM;
        k0 = (j & 31) * 32; n0 = (j >> 5) * 32;
    }
    __shared__ float Ws[32][33];
    int tid = threadIdx.x;
    for (int l = 0; l < 4; l++) {
        int e = tid + 256 * l;
        int kk = e >> 5, nn = e & 31;
        Ws[kk][nn] = g[k0 + kk] * W[(size_t)(k0 + kk) * N + n0 + nn];
    }
    __syncthreads();
    for (int l = 0; l < 4; l++) {
        int e = tid + 256 * l;
        int nn = e >> 5, kk = e & 31;
        WT[(size_t)(n0 + nn) * K + k0 + kk] = f2b(Ws[kk][nn]);
    }
}

// ---------------- merged bias init (bias_hq padded region zeroed) ------------------------
__global__ __launch_bounds__(256) void bias_init3(
    const float* __restrict__ b_h, const float* __restrict__ b_qk,
    const float* __restrict__ b_o, float* __restrict__ bias_hq,
    float* __restrict__ bias_o)
{
    int n = blockIdx.x * 256 + threadIdx.x;
    if (n < HID)                 bias_hq[n] = b_h[n];
    else if (n < NHQ)            bias_hq[n] = b_qk[n - HID];
    else if (n < NHQ2)           bias_hq[n] = 0.f;           // pad cols (never read)
    else if (n < NHQ2 + DIM)     bias_o[n - NHQ2] = b_o[n - NHQ2];
}

// ---------------- merged bias reduce (parallel over K, atomics — r5-proven) --------------
#define BKC 64
__global__ __launch_bounds__(256) void bias_reduce3(
    const float* __restrict__ W_h,  const float* __restrict__ lnb_h,
    const float* __restrict__ W_qk, const float* __restrict__ lnb_qk,
    const float* __restrict__ W_o,  const float* __restrict__ lnb_o,
    float* __restrict__ bias_hq, float* __restrict__ bias_o)
{
    int i = blockIdx.x;
    const float *W, *lnb; float* out; int N, n, k0;
    if (i < 64) {                   // W_h: N=2048 (8 nb), K=512 (8 kb)
        W = W_h; lnb = lnb_h; out = bias_hq; N = HID;
        n = (i & 7) * 256 + threadIdx.x; k0 = (i >> 3) * BKC;
    } else if (i < 72) {            // W_qk: N=128 (1 nb), K=512 (8 kb)
        int j = i - 64;
        W = W_qk; lnb = lnb_qk; out = bias_hq + HID; N = DQK;
        n = threadIdx.x; k0 = j * BKC;
    } else {                        // W_o: N=512 (2 nb), K=1024 (16 kb)
        int j = i - 72;
        W = W_o; lnb = lnb_o; out = bias_o; N = DIM;
        n = (j & 1) * 256 + threadIdx.x; k0 = (j >> 1) * BKC;
    }
    if (n >= N) return;
    float s = 0.f;
    #pragma unroll 8
    for (int k = k0; k < k0 + BKC; k++) s += lnb[k] * W[(size_t)k * N + n];
    atomicAdd(&out[n], s);
}

// ---------------- staging helper: 128 rows x 32 cols bf16 tile via global_load_lds -------
__device__ __forceinline__ void stage_tile(const bf16* base, size_t ld, bf16* dst,
                                           int wave, int lane)
{
    int lrow = lane >> 2, lcol = lane & 3;
    for (int cc = 0; cc < 2; cc++) {
        int c = wave * 2 + cc;
        int row = c * 16 + lrow;
        const bf16* g = base + (size_t)row * ld + lcol * 8;
        __builtin_amdgcn_global_load_lds(AS1(g), AS3(dst + c * 512), 16, 0, 0);
    }
}

// ============ shared 3-slot pipelined 128x128 GEMM core (T3/T4/T5, proven in r2) =========
#define PIPE_SLOT 8192   // As(128x32) + Bs(128x32) bf16 = 16 KiB

__device__ __forceinline__ void pipe_core(
    const bf16* __restrict__ Abase, size_t ldA,
    const bf16* __restrict__ Bbase, size_t ldB,
    int nit, bf16* lds, int wave, int lane, float4v acc[4][4])
{
    auto stage = [&](int it, int slot) {
        bf16* As = lds + slot * PIPE_SLOT;
        stage_tile(Abase + (size_t)it * 32, ldA, As, wave, lane);
        stage_tile(Bbase + (size_t)it * 32, ldB, As + 4096, wave, lane);
    };
    stage(0, 0);
    stage(1, 1);
    asm volatile("s_waitcnt vmcnt(4)" ::: "memory");
    __builtin_amdgcn_s_barrier();
    __builtin_amdgcn_sched_barrier(0);

    int wm = wave & 1, wn = wave >> 1;
    int col = lane & 15, quad = lane >> 4;
    int slot = 0;
    for (int it = 0; it < nit; it++) {
        const bf16* As = lds + slot * PIPE_SLOT;
        const bf16* Bs = As + 4096;
        short8 a[4], b[4];
        #pragma unroll
        for (int t = 0; t < 4; t++) {
            a[t] = *(const short8*)(As + (wm * 64 + t * 16 + col) * 32 + quad * 8);
            b[t] = *(const short8*)(Bs + (wn * 64 + t * 16 + col) * 32 + quad * 8);
        }
        int nslot = slot + 1; if (nslot == 3) nslot = 0;
        int pslot = nslot + 1; if (pslot == 3) pslot = 0;   // (slot+2)%3
        if (it + 2 < nit) stage(it + 2, pslot);
        asm volatile("s_waitcnt lgkmcnt(0)" ::: "memory");
        __builtin_amdgcn_sched_barrier(0);
        __builtin_amdgcn_s_setprio(1);
        #pragma unroll
        for (int i = 0; i < 4; i++)
            #pragma unroll
            for (int j = 0; j < 4; j++)
                acc[i][j] = MFMA(a[i], b[j], acc[i][j], 0, 0, 0);
        __builtin_amdgcn_s_setprio(0);
        __builtin_amdgcn_sched_barrier(0);
        if (it + 2 < nit) { asm volatile("s_waitcnt vmcnt(4)" ::: "memory"); }
        else              { asm volatile("s_waitcnt vmcnt(0)" ::: "memory"); }
        __builtin_amdgcn_s_barrier();
        __builtin_amdgcn_sched_barrier(0);
        slot = nslot;
    }
}

// ---------------- pipelined MFMA GEMM: C = silu(A@B^T + bias); XCD-affine m-blocks -------
__global__ __launch_bounds__(256) void gemm_pipe(
    const bf16* __restrict__ A, const bf16* __restrict__ BT,
    const float* __restrict__ bias, bf16* __restrict__ C,
    int M, int N, int K, int ldC)
{
    __shared__ __align__(16) bf16 lds[3 * PIPE_SLOT];
    int nb = N >> 7;
    int i = blockIdx.x;
    int xcd = i & 7, r = i >> 3;
    int m0 = (xcd + 8 * (r / nb)) << 7;   // same-A-panel blocks share an XCD
    int n0 = (r % nb) << 7;
    int tid = threadIdx.x, wave = tid >> 6, lane = tid & 63;
    float4v acc[4][4] = {};
    pipe_core(A + (size_t)m0 * K, K, BT + (size_t)n0 * K, K, K / 32,
              lds, wave, lane, acc);
    int wm = wave & 1, wn = wave >> 1;
    int col = lane & 15, quad = lane >> 4;
    for (int i2 = 0; i2 < 4; i2++) {
        for (int j = 0; j < 4; j++) {
            int n = n0 + wn * 64 + j * 16 + col;
            float bs = bias[n];
            for (int r2 = 0; r2 < 4; r2++) {
                int m = m0 + wm * 64 + i2 * 16 + quad * 4 + r2;
                float v = acc[i2][j][r2] + bs;
                v = v / (1.f + __expf(-v));
                C[(size_t)m * ldC + n] = f2b(v);
            }
        }
    }
}

// ============== 256x256 8-wave BK=64 multi-phase GEMM (T1+T2+T3/T4+T5) ==================
__device__ __forceinline__ void stage_half256(const bf16* __restrict__ g0, int ld,
                                              bf16* dst, int tid)
{
    int wb = tid & ~63;   // wave*64
    #pragma unroll
    for (int l = 0; l < 2; l++) {
        int idx = l * 512 + tid;
        int row = idx >> 3;
        int c8  = (idx & 7) ^ (row & 7);
        const bf16* g = g0 + (size_t)row * ld + c8 * 8;
        __builtin_amdgcn_global_load_lds(AS1(g), AS3(dst + (size_t)(l * 512 + wb) * 8), 16, 0, 0);
    }
}

__device__ __forceinline__ short8 ldsfrag(const bf16* h, int row, int g)
{
    return *(const short8*)(h + row * 64 + ((g ^ (row & 7)) << 3));
}

__global__ __launch_bounds__(512, 2) void gemm256(
    const bf16* __restrict__ A, const bf16* __restrict__ BT,
    const float* __restrict__ bias, bf16* __restrict__ C,
    int N, int K, int ldC)
{
    __shared__ __align__(16) bf16 As[2][2][128][64];
    __shared__ __align__(16) bf16 Bs[2][2][128][64];
    int nbx = N >> 8;
    int nwg = gridDim.x;
    int cpx = nwg >> 3;               // grid is always a multiple of 8 -> bijective
    int bid = blockIdx.x;
    int swz = (bid & 7) * cpx + (bid >> 3);
    int bx = swz % nbx, by = swz / nbx;
    int m0 = by << 8, n0 = bx << 8;
    int tid = threadIdx.x, wave = tid >> 6, lane = tid & 63;
    int wm = wave >> 2, wn = wave & 3;      // 2 (M) x 4 (N) waves
    int col = lane & 15, quad = lane >> 4;
    int nkt = K >> 6;
    float4v acc[8][4] = {};

    const bf16* Ag = A  + (size_t)m0 * K;
    const bf16* Bg = BT + (size_t)n0 * K;

    // prologue: stage K-tile 0 fully into buf0
    #pragma unroll
    for (int h = 0; h < 2; h++) {
        stage_half256(Ag + (size_t)h * 128 * K, K, &As[0][h][0][0], tid);
        stage_half256(Bg + (size_t)h * 128 * K, K, &Bs[0][h][0][0], tid);
    }
    asm volatile("s_waitcnt vmcnt(0)" ::: "memory");
    __builtin_amdgcn_s_barrier();

    for (int kt = 0; kt < nkt; kt++) {
        int buf = kt & 1;
        const bf16* Ah = &As[buf][wm][0][0];
        const bf16* Bh = &Bs[buf][wn >> 1][0][0];
        int brb = (wn & 1) * 64;
        short8 ar[2][4], br[2][2], br2[2][2];
        bool pf = (kt + 1 < nkt);

        // ---------------- P1: read a(qi=0), b(qj=0); stage A+B halves of kt+1 -----------
        #pragma unroll
        for (int i = 0; i < 4; i++)
            #pragma unroll
            for (int ks = 0; ks < 2; ks++)
                ar[ks][i] = ldsfrag(Ah, i * 16 + col, ks * 4 + quad);
        #pragma unroll
        for (int j = 0; j < 2; j++)
            #pragma unroll
            for (int ks = 0; ks < 2; ks++)
                br[ks][j] = ldsfrag(Bh, brb + j * 16 + col, ks * 4 + quad);
        if (pf) {
            #pragma unroll
            for (int h = 0; h < 2; h++) {
                stage_half256(Ag + (size_t)h * 128 * K + (kt + 1) * 64, K,
                              &As[buf ^ 1][h][0][0], tid);
                stage_half256(Bg + (size_t)h * 128 * K + (kt + 1) * 64, K,
                              &Bs[buf ^ 1][h][0][0], tid);
            }
        }
        __builtin_amdgcn_s_barrier();
        __builtin_amdgcn_s_setprio(1);
        #pragma unroll
        for (int i = 0; i < 4; i++)
            #pragma unroll
            for (int j = 0; j < 2; j++) {
                acc[i][j] = MFMA(ar[0][i], br[0][j], acc[i][j], 0, 0, 0);
                acc[i][j] = MFMA(ar[1][i], br[1][j], acc[i][j], 0, 0, 0);
            }
        __builtin_amdgcn_s_setprio(0);
        __builtin_amdgcn_s_barrier();

        // ---------------- P2: read b(qj=1) ----------------------------------------------
        #pragma unroll
        for (int j = 0; j < 2; j++)
            #pragma unroll
            for (int ks = 0; ks < 2; ks++)
                br2[ks][j] = ldsfrag(Bh, brb + (j + 2) * 16 + col, ks * 4 + quad);
        __builtin_amdgcn_s_barrier();
        __builtin_amdgcn_s_setprio(1);
        #pragma unroll
        for (int i = 0; i < 4; i++)
            #pragma unroll
            for (int j = 0; j < 2; j++) {
                acc[i][j + 2] = MFMA(ar[0][i], br2[0][j], acc[i][j + 2], 0, 0, 0);
                acc[i][j + 2] = MFMA(ar[1][i], br2[1][j], acc[i][j + 2], 0, 0, 0);
            }
        __builtin_amdgcn_s_setprio(0);
        __builtin_amdgcn_s_barrier();

        // ---------------- P3: read a(qi=1) ----------------------------------------------
        #pragma unroll
        for (int i = 0; i < 4; i++)
            #pragma unroll
            for (int ks = 0; ks < 2; ks++)
                ar[ks][i] = ldsfrag(Ah, (i + 4) * 16 + col, ks * 4 + quad);
        __builtin_amdgcn_s_barrier();
        __builtin_amdgcn_s_setprio(1);
        #pragma unroll
        for (int i = 0; i < 4; i++)
            #pragma unroll
            for (int j = 0; j < 2; j++) {
                acc[i + 4][j + 2] = MFMA(ar[0][i], br2[0][j], acc[i + 4][j + 2], 0, 0, 0);
                acc[i + 4][j + 2] = MFMA(ar[1][i], br2[1][j], acc[i + 4][j + 2], 0, 0, 0);
            }
        __builtin_amdgcn_s_setprio(0);
        __builtin_amdgcn_s_barrier();

        // ---------------- P4: read b(qj=0) again ----------------------------------------
        #pragma unroll
        for (int j = 0; j < 2; j++)
            #pragma unroll
            for (int ks = 0; ks < 2; ks++)
                br[ks][j] = ldsfrag(Bh, brb + j * 16 + col, ks * 4 + quad);
        __builtin_amdgcn_s_barrier();
        __builtin_amdgcn_s_setprio(1);
        #pragma unroll
        for (int i = 0; i < 4; i++)
            #pragma unroll
            for (int j = 0; j < 2; j++) {
                acc[i + 4][j] = MFMA(ar[0][i], br[0][j], acc[i + 4][j], 0, 0, 0);
                acc[i + 4][j] = MFMA(ar[1][i], br[1][j], acc[i + 4][j], 0, 0, 0);
            }
        __builtin_amdgcn_s_setprio(0);
        __builtin_amdgcn_sched_barrier(0);
        asm volatile("s_waitcnt vmcnt(0)" ::: "memory");
        __builtin_amdgcn_s_barrier();
    }

    // epilogue: bias + silu + store
    #pragma unroll
    for (int i = 0; i < 8; i++) {
        #pragma unroll
        for (int j = 0; j < 4; j++) {
            int n = n0 + wn * 64 + j * 16 + col;
            float bs = bias[n];
            #pragma unroll
            for (int r = 0; r < 4; r++) {
                int m = m0 + wm * 128 + i * 16 + quad * 4 + r;
                float v = acc[i][j][r] + bs;
                v = v / (1.f + __expf(-v));
                C[(size_t)m * ldC + n] = f2b(v);
            }
        }
    }
}

// ======== merged attn_score + linkv (one launch; both pipe_core; XCD-affine) =============
__global__ __launch_bounds__(256) void score_linkv(
    const bf16* __restrict__ quadq, const bf16* __restrict__ quadk,
    bf16* __restrict__ P,
    const bf16* __restrict__ hidT, const bf16* __restrict__ linkT,
    float* __restrict__ linkvT, int rowsC, int nScore)
{
    __shared__ __align__(16) bf16 lds[3 * PIPE_SLOT];
    int tid = threadIdx.x, wave = tid >> 6, lane = tid & 63;
    if ((int)blockIdx.x < nScore) {
        // ---- attn scores: P = relu(QK^T/256)^2, causal ----
        int i = blockIdx.x;
        int xcd = i & 7, r = i >> 3;
        int g = xcd + 8 * (r >> 2);
        int t = r & 3, bi = t >> 1, bj = t & 1;
        bf16* Pg = P + (size_t)g * GRP * GRP;
        if (bj > bi) {   // fully masked tile: write zeros
            short8 z = {};
            int rr = tid >> 1, half = tid & 1;
            short* dst = (short*)Pg + (size_t)(bi * 128 + rr) * GRP + bj * 128 + half * 64;
            for (int q = 0; q < 8; q++) ((short8*)dst)[q] = z;
            return;
        }
        float4v acc[4][4] = {};
        const bf16* Ab = quadq + (size_t)(g * GRP + bi * 128) * DQK;
        const bf16* Bb = quadk + (size_t)(g * GRP + bj * 128) * DQK;
        pipe_core(Ab, DQK, Bb, DQK, DQK / 32, lds, wave, lane, acc);
        int wm = wave & 1, wn = wave >> 1;
        int col = lane & 15, quad = lane >> 4;
        for (int i2 = 0; i2 < 4; i2++) {
            for (int j = 0; j < 4; j++) {
                int jj = bj * 128 + wn * 64 + j * 16 + col;
                for (int r2 = 0; r2 < 4; r2++) {
                    int ii = bi * 128 + wm * 64 + i2 * 16 + quad * 4 + r2;
                    float s = acc[i2][j][r2] * (1.f / GRP);
                    s = fmaxf(s, 0.f); s = s * s;
                    if (jj > ii) s = 0.f;
                    Pg[(size_t)ii * GRP + jj] = f2b(s);
                }
            }
        }
    } else {
        // ---- linkv: linkvT[g][e][d] = (hidT_g @ linkT_g^T)/256 ----
        int i = blockIdx.x - nScore;       // nScore % 8 == 0 -> XCD parity preserved
        int xcd = i & 7, r = i >> 3;
        int g = xcd + 8 * (r >> 4);
        int eb = r & 15;
        int e0 = eb * 128;
        float4v acc[4][4] = {};
        pipe_core(hidT + (size_t)e0 * rowsC + g * GRP, rowsC,
                  linkT + g * GRP, rowsC, GRP / 32, lds, wave, lane, acc);
        float* out = linkvT + (size_t)g * (HID * DQK);
        int wm = wave & 1, wn = wave >> 1;
        int col = lane & 15, quad = lane >> 4;
        for (int i2 = 0; i2 < 4; i2++) {
            for (int j = 0; j < 4; j++) {
                int d = wn * 64 + j * 16 + col;
                for (int r2 = 0; r2 < 4; r2++) {
                    int e = e0 + wm * 64 + i2 * 16 + quad * 4 + r2;
                    out[(size_t)e * DQK + d] = acc[i2][j][r2] * (1.f / GRP);
                }
            }
        }
    }
}

// ---------------- exclusive cumsum over group axis, fp32 in -> bf16 out (x4 vec) ---------
__global__ void cumsum_bf(const float* __restrict__ in, bf16* __restrict__ out)
{
    long idx4 = (long)blockIdx.x * blockDim.x + threadIdx.x;   // 4 elems per thread
    int b = (int)(idx4 / (DQK * HID / 4));
    long off = (idx4 % (DQK * HID / 4)) * 4;
    const float* pi = in + (long)b * NG * DQK * HID + off;
    bf16* po = out + (long)b * NG * DQK * HID + off;
    float4v run = {0.f, 0.f, 0.f, 0.f};
    for (int gi = 0; gi < NG; gi++) {
        short4v o4;
        union { short s; bf16 h; } cv;
        #pragma unroll
        for (int k = 0; k < 4; k++) { cv.h = f2b(run[k]); o4[k] = cv.s; }
        *(short4v*)(po + (long)gi * DQK * HID) = o4;
        run += *(const float4v*)(pi + (long)gi * DQK * HID);
    }
}

// ---------------- fused attn apply MFMA + gating — 3-slot pipelined, XCD-affine ----------
// gating now reads hidT (ch-major) — row-major `hid` buffer eliminated entirely
#define AP_SLOT (256 * BK + 128 * BK)   // 12288 bf16 = 24 KiB per slot

__global__ __launch_bounds__(256) void attn_apply_mfma(
    const bf16* __restrict__ P, const bf16* __restrict__ hidT,
    const bf16* __restrict__ linq, const bf16* __restrict__ linkvb,
    bf16* __restrict__ outg, int rowsC)
{
    int ib = blockIdx.x;
    int xcd = ib & 7, rb = ib >> 3;
    int g = xcd + 8 * (rb >> 4);          // all 16 e-blocks of a group share an XCD
    int e0 = (rb & 15) * 64;
    __shared__ __align__(16) bf16 lds[3 * AP_SLOT];
    int tid = threadIdx.x, wave = tid >> 6, lane = tid & 63;
    int lrow = lane >> 2, lcol = lane & 3;
    const bf16* Pg = P + (size_t)g * GRP * GRP;
    const bf16* Lg = linkvb + (size_t)g * (HID * DQK);

    // stage iteration 'it' (0..7: quad j0=it*32; 8..11: lin d0=(it-8)*32) into 'slot'
    auto stage = [&](int it, int slot) {
        bf16* As = lds + slot * AP_SLOT;
        bf16* Bs = As + 256 * BK;
        if (it < 8) {
            int j0 = it * 32;
            for (int cc = 0; cc < 4; cc++) {
                int c = wave * 4 + cc;
                int row = c * 16 + lrow;
                const bf16* ga = Pg + (size_t)row * GRP + j0 + lcol * 8;
                __builtin_amdgcn_global_load_lds(AS1(ga), AS3(As + c * 512), 16, 0, 0);
            }
            for (int cc = 0; cc < 2; cc++) {
                int c = wave * 2 + cc;
                int row = c * 16 + lrow;
                int er = (row < 64) ? (e0 + row) : (1024 + e0 + (row - 64));
                const bf16* gb = hidT + (size_t)er * rowsC + g * GRP + j0 + lcol * 8;
                __builtin_amdgcn_global_load_lds(AS1(gb), AS3(Bs + c * 512), 16, 0, 0);
            }
        } else {
            int d0 = (it - 8) * 32;
            for (int cc = 0; cc < 4; cc++) {
                int c = wave * 4 + cc;
                int row = c * 16 + lrow;
                const bf16* ga = linq + (size_t)(g * GRP + row) * DQK + d0 + lcol * 8;
                __builtin_amdgcn_global_load_lds(AS1(ga), AS3(As + c * 512), 16, 0, 0);
            }
            for (int cc = 0; cc < 2; cc++) {
                int c = wave * 2 + cc;
                int row = c * 16 + lrow;
                int er = (row < 64) ? (e0 + row) : (1024 + e0 + (row - 64));
                const bf16* gb = Lg + (size_t)er * DQK + d0 + lcol * 8;
                __builtin_amdgcn_global_load_lds(AS1(gb), AS3(Bs + c * 512), 16, 0, 0);
            }
        }
    };

    // prologue: slots 0 and 1 in flight; wait for slot 0 (6 loads of slot1 may remain)
    stage(0, 0);
    stage(1, 1);
    asm volatile("s_waitcnt vmcnt(6)" ::: "memory");
    __builtin_amdgcn_s_barrier();
    __builtin_amdgcn_sched_barrier(0);

    float4v acc[4][8] = {};
    int col = lane & 15, quad = lane >> 4;
    int slot = 0;
    for (int it = 0; it < 12; it++) {
        const bf16* As = lds + slot * AP_SLOT;
        const bf16* Bs = As + 256 * BK;
        short8 a[4], b[8];
        #pragma unroll
        for (int t = 0; t < 4; t++)
            a[t] = *(const short8*)(As + (wave * 64 + t * 16 + col) * BK + quad * 8);
        #pragma unroll
        for (int t = 0; t < 8; t++)
            b[t] = *(const short8*)(Bs + (t * 16 + col) * BK + quad * 8);
        int nslot = slot + 1; if (nslot == 3) nslot = 0;
        int pslot = nslot + 1; if (pslot == 3) pslot = 0;   // (slot+2)%3
        if (it + 2 < 12) stage(it + 2, pslot);
        asm volatile("s_waitcnt lgkmcnt(0)" ::: "memory");
        __builtin_amdgcn_sched_barrier(0);
        __builtin_amdgcn_s_setprio(1);
        #pragma unroll
        for (int i = 0; i < 4; i++)
            #pragma unroll
            for (int j = 0; j < 8; j++)
                acc[i][j] = MFMA(a[i], b[j], acc[i][j], 0, 0, 0);
        __builtin_amdgcn_s_setprio(0);
        __builtin_amdgcn_sched_barrier(0);
        if (it + 2 < 12) { asm volatile("s_waitcnt vmcnt(6)" ::: "memory"); }
        else             { asm volatile("s_waitcnt vmcnt(0)" ::: "memory"); }
        __builtin_amdgcn_s_barrier();
        __builtin_amdgcn_sched_barrier(0);
        slot = nslot;
    }

    // epilogue with gating (v,u read from hidT: row e contiguous in token)
    for (int mt = 0; mt < 4; mt++) {
        for (int nt = 0; nt < 4; nt++) {
            for (int r = 0; r < 4; r++) {
                int tokg = g * GRP + wave * 64 + mt * 16 + quad * 4 + r;
                int e = e0 + nt * 16 + col;
                float av = acc[mt][nt][r];
                float au = acc[mt][nt + 4][r];
                float v = b2f(hidT[(size_t)e * rowsC + tokg]);
                float u = b2f(hidT[(size_t)(1024 + e) * rowsC + tokg]);
                float gate = 1.f / (1.f + __expf(-av * u));
                outg[(size_t)tokg * 1024 + e] = f2b(au * v * gate);
            }
        }
    }
}

// ======== merged dwconv: h-path (hidT only) + qk-path (affine split), one launch =========
__global__ __launch_bounds__(256) void dwconv_both(
    const bf16* __restrict__ hq, const float* __restrict__ dw_h,
    bf16* __restrict__ hidT,
    const float* __restrict__ dw_qk,
    const float* __restrict__ gamma, const float* __restrict__ beta,
    bf16* __restrict__ quadq, bf16* __restrict__ quadk,
    bf16* __restrict__ linq, bf16* __restrict__ linkT,
    int rowsC, int nDual)
{
    __shared__ float s[80][64];
    __shared__ bf16 o[64][72];   // [ch][tok], row stride 144 B (16B-aligned)
    int tid = threadIdx.x;
    if ((int)blockIdx.x < nDual) {
        // ---- h path: hidT = h + dwconv(h), transposed write only ----
        int i = blockIdx.x;
        int c0 = (i & 31) * 64;            // HID/64 = 32
        int t0 = ((i >> 5) & 31) * 64;     // NN/64 = 32
        int b  = i >> 10;
        const bf16* base = hq + (size_t)b * NN * NHQ2 + c0;
        {
            int ch8 = (tid & 7) * 8, rw = tid >> 3;
            #pragma unroll
            for (int ps = 0; ps < 3; ps++) {
                int tt = rw + ps * 32;
                if (tt < 80) {
                    int t = t0 + tt - 8;
                    union { short8 v; bf16 h[8]; } u; u.v = short8{};
                    if (t >= 0 && t < NN)
                        u.v = *(const short8*)(base + (size_t)t * NHQ2 + ch8);
                    float* sp = &s[tt][ch8];
                    #pragma unroll
                    for (int k = 0; k < 8; k++) sp[k] = b2f(u.h[k]);
                }
            }
        }
        __syncthreads();
        int c = tid & 63, rp = tid >> 6;
        float w[KW];
        for (int k = 0; k < KW; k++) w[k] = dw_h[k * HID + c0 + c];
        for (int l = 0; l < 16; l++) {
            int r = rp + l * 4;
            float acc = s[r + 8][c];
            for (int k = 0; k < KW; k++) acc += s[r + k][c] * w[k];
            o[c][r] = f2b(acc);
        }
        __syncthreads();
        // write hidT (ch-major [ch][rowsC]) as short8
        {
            int t8 = (tid & 7) * 8, ch = tid >> 3;
            #pragma unroll
            for (int ps = 0; ps < 2; ps++) {
                int cc = ch + ps * 32;
                short8 v = *(const short8*)(&o[cc][t8]);
                *(short8*)(hidT + (size_t)(c0 + cc) * rowsC + b * NN + t0 + t8) = v;
            }
        }
    } else {
        // ---- qk path: conv + 4-way affine -> quadq/quadk/linq/linkT ----
        int i = blockIdx.x - nDual;
        int c0 = (i & 1) * 64;             // DQK/64 = 2
        int t0 = ((i >> 1) & 31) * 64;
        int b  = i >> 6;
        const bf16* base = hq + HID + (size_t)b * NN * NHQ2 + c0;
        {
            int ch8 = (tid & 7) * 8, rw = tid >> 3;
            #pragma unroll
            for (int ps = 0; ps < 3; ps++) {
                int tt = rw + ps * 32;
                if (tt < 80) {
                    int t = t0 + tt - 8;
                    union { short8 v; bf16 h[8]; } u; u.v = short8{};
                    if (t >= 0 && t < NN)
                        u.v = *(const short8*)(base + (size_t)t * NHQ2 + ch8);
                    float* sp = &s[tt][ch8];
                    #pragma unroll
                    for (int k = 0; k < 8; k++) sp[k] = b2f(u.h[k]);
                }
            }
        }
        __syncthreads();
        int c = tid & 63, rp = tid >> 6;
        float w[KW];
        for (int k = 0; k < KW; k++) w[k] = dw_qk[k * DQK + c0 + c];
        float ga0 = gamma[0 * DQK + c0 + c], be0 = beta[0 * DQK + c0 + c];
        float ga1 = gamma[1 * DQK + c0 + c], be1 = beta[1 * DQK + c0 + c];
        float ga2 = gamma[2 * DQK + c0 + c], be2 = beta[2 * DQK + c0 + c];
        float ga3 = gamma[3 * DQK + c0 + c], be3 = beta[3 * DQK + c0 + c];
        for (int l = 0; l < 16; l++) {
            int r = rp + l * 4;
            float acc = s[r + 8][c];
            for (int k = 0; k < KW; k++) acc += s[r + k][c] * w[k];
            size_t tok = (size_t)b * NN + t0 + r;
            quadq[tok * DQK + c0 + c] = f2b(acc * ga0 + be0);
            linq [tok * DQK + c0 + c] = f2b(acc * ga1 + be1);
            quadk[tok * DQK + c0 + c] = f2b(acc * ga2 + be2);
            o[c][r] = f2b(acc * ga3 + be3);
        }
        __syncthreads();
        // transposed write of linkT rows c0..c0+63
        int t8 = (tid & 7) * 8, ch = tid >> 3;
        #pragma unroll
        for (int ps = 0; ps < 2; ps++) {
            int cc = ch + ps * 32;
            short8 v = *(const short8*)(&o[cc][t8]);
            *(short8*)(linkT + (size_t)(c0 + cc) * rowsC + b * NN + t0 + t8) = v;
        }
    }
}

// ---------------- dwconv (generic, vectorized staging) -----------------------------------
template<typename TO>
__global__ __launch_bounds__(256) void dwconv_res(
    const bf16* __restrict__ src, const float* __restrict__ dw,
    const float* __restrict__ xres, TO* __restrict__ dst, int C, int ldS)
{
    int c0 = blockIdx.x * 64;
    int t0 = blockIdx.y * 64;
    int b  = blockIdx.z;
    __shared__ float s[80][64];
    int tid = threadIdx.x;
    int c = tid & 63;
    int rp = tid >> 6;
    const bf16* base = src + (size_t)b * NN * ldS + c0;
    {
        int ch8 = (tid & 7) * 8, rw = tid >> 3;
        #pragma unroll
        for (int ps = 0; ps < 3; ps++) {
            int tt = rw + ps * 32;
            if (tt < 80) {
                int t = t0 + tt - 8;
                union { short8 v; bf16 h[8]; } u; u.v = short8{};
                if (t >= 0 && t < NN)
                    u.v = *(const short8*)(base + (size_t)t * ldS + ch8);
                float* sp = &s[tt][ch8];
                #pragma unroll
                for (int k = 0; k < 8; k++) sp[k] = b2f(u.h[k]);
            }
        }
    }
    __syncthreads();
    float w[KW];
    for (int k = 0; k < KW; k++) w[k] = dw[k * C + c0 + c];
    for (int l = 0; l < 16; l++) {
        int r = rp + l * 4;
        float acc = s[r + 8][c];
        for (int k = 0; k < KW; k++) acc += s[r + k][c] * w[k];
        long gidx = ((long)b * NN + t0 + r) * C + c0 + c;
        if (xres) acc += xres[gidx];
        stv(dst, gidx, acc);
    }
}

extern "C" void kernel_launch(void* const* d_in, const int* in_sizes, int n_in,
                              void* d_out, int out_size, void* d_ws, size_t ws_size,
                              hipStream_t stream)
{
    const float* x      = (const float*)d_in[0];
    const float* ln_h_g = (const float*)d_in[1];
    const float* ln_h_b = (const float*)d_in[2];
    const float* W_h    = (const float*)d_in[3];
    const float* b_h    = (const float*)d_in[4];
    const float* dw_h   = (const float*)d_in[5];
    const float* ln_qk_g= (const float*)d_in[6];
    const float* ln_qk_b= (const float*)d_in[7];
    const float* W_qk   = (const float*)d_in[8];
    const float* b_qk   = (const float*)d_in[9];
    const float* dw_qk  = (const float*)d_in[10];
    const float* gamma  = (const float*)d_in[11];
    const float* beta   = (const float*)d_in[12];
    const float* ln_o_g = (const float*)d_in[13];
    const float* ln_o_b = (const float*)d_in[14];
    const float* W_o    = (const float*)d_in[15];
    const float* b_o    = (const float*)d_in[16];
    const float* dw_o   = (const float*)d_in[17];
    float* outp = (float*)d_out;

    // ---- fixed region ----
    char* p = (char*)d_ws;
    bf16* WT_hq = (bf16*)p;  p += (size_t)NHQ2 * DIM * 2;      // rows 2176..2303 = pad
    bf16* WT_o  = (bf16*)p;  p += (size_t)DIM * 1024 * 2;
    float* bias_hq = (float*)p; p += NHQ2 * 4;
    float* bias_o  = (float*)p; p += DIM * 4;
    bf16* hat1_all = (bf16*)p;  p += (size_t)BB * NN * DIM * 2;  // LN(x) for all batches
    p = (char*)(((uintptr_t)p + 255) & ~(uintptr_t)255);
    size_t fixed = (size_t)(p - (char*)d_ws);
    bf16* WT_h  = WT_hq;
    bf16* WT_qk = WT_hq + (size_t)HID * DIM;
    float* bias_h  = bias_hq;

    auto bytes_for = [fixed](int cb) -> size_t {
        size_t rows = (size_t)cb * NN;
        return fixed
             + rows * NHQ2 * 2          // s1 hq / linkvT / fin_pre
             + rows * 1024 * 2          // s2 hat2
             + rows * HID * 2           // s3 hidT
             + rows * 1024 * 2          // s4 outg
             + (size_t)cb * NG * GRP * GRP * 2   // s5 P
             + 4 * rows * DQK * 2       // s6 linkT + quadq/quadk/linq
             + rows * 1024 * 2          // s11 linkvb
             + 4096;
    };
    int CB = 1;
    if (bytes_for(4) <= ws_size) CB = 4;
    else if (bytes_for(2) <= ws_size) CB = 2;
    const int rowsC = CB * NN;
    const size_t rows = (size_t)rowsC;

    char* s1 = p;               p += rows * NHQ2 * 2;  // hq -> linkvT -> fin_pre
    char* s2 = p;               p += rows * 1024 * 2;  // hat2
    char* s3 = p;               p += rows * HID * 2;   // hidT
    char* s4 = p;               p += rows * 1024 * 2;  // outg
    char* s5 = p;               p += (size_t)CB * NG * GRP * GRP * 2;  // P
    char* s6 = p;               p += rows * DQK * 2;   // linkT
    char* s8 = p;               p += rows * DQK * 2;   // quadq
    char* s9 = p;               p += rows * DQK * 2;   // quadk
    char* s10 = p;              p += rows * DQK * 2;   // linq
    char* s11 = p;              p += rows * 1024 * 2;  // linkvb (bf16 cumsum out)

    bf16*  hq      = (bf16*)s1;
    float* linkvT  = (float*)s1;
    bf16*  fin_pre = (bf16*)s1;
    bf16*  hat2    = (bf16*)s2;
    bf16*  hidT    = (bf16*)s3;
    bf16*  outg    = (bf16*)s4;
    bf16*  P       = (bf16*)s5;
    bf16*  linkT   = (bf16*)s6;
    bf16*  quadq   = (bf16*)s8;
    bf16*  quadk   = (bf16*)s9;
    bf16*  linq    = (bf16*)s10;
    bf16*  linkvb  = (bf16*)s11;

    // ---- weight prep (3 launches) + LN of all batches (1 launch) ----
    prep_all<<<1600, 256, 0, stream>>>(W_h, ln_h_g, WT_h,
                                       W_qk, ln_qk_g, WT_qk,
                                       W_o, ln_o_g, WT_o);
    bias_init3<<<(NHQ2 + DIM + 255) / 256, 256, 0, stream>>>(b_h, b_qk, b_o, bias_hq, bias_o);
    bias_reduce3<<<104, 256, 0, stream>>>(W_h, ln_h_b, W_qk, ln_qk_b, W_o, ln_o_b,
                                          bias_hq, bias_o);
    ln_kernel_f<DIM, 1><<<BB * NN, 256, 0, stream>>>(x, hat1_all);

    const int G = CB * NG;   // groups per chunk
    for (int b0 = 0; b0 < BB; b0 += CB) {
        const float* xc = x    + (size_t)b0 * NN * DIM;
        float* outc     = outp + (size_t)b0 * NN * DIM;
        const bf16* hat1 = hat1_all + (size_t)b0 * NN * DIM;
        int R = rowsC;

        // 2) merged h+qk gemm on the 256x256 kernel (N padded to 2304)
        gemm256<<<dim3((R / 256) * (NHQ2 / 256)), 512, 0, stream>>>(
            hat1, WT_hq, bias_hq, hq, NHQ2, DIM, NHQ2);
        // 3+4+5) merged dwconv: h transposed-write + qk conv+affine
        {
            int nDual = (HID / 64) * (NN / 64) * CB;
            int nQk   = (DQK / 64) * (NN / 64) * CB;
            dwconv_both<<<nDual + nQk, 256, 0, stream>>>(
                hq, dw_h, hidT, dw_qk, gamma, beta,
                quadq, quadk, linq, linkT, rowsC, nDual);
        }
        // 6+7) merged scores + linkv (both depend only on dwconv outputs)
        score_linkv<<<4 * G + 16 * G, 256, 0, stream>>>(
            quadq, quadk, P, hidT, linkT, linkvT, rowsC, 4 * G);
        // 8) exclusive cumsum over groups -> linkvb bf16
        cumsum_bf<<<(CB * DQK * HID) / (256 * 4), 256, 0, stream>>>(linkvT, linkvb);
        // 9) fused apply + gating -> outg (v,u from hidT), XCD-affine per group
        attn_apply_mfma<<<dim3(16 * G), 256, 0, stream>>>(P, hidT, linq, linkvb, outg, rowsC);
        // 10) LN(outg) -> hat2
        ln_kernel_bf<1024><<<R, 256, 0, stream>>>(outg, hat2);
        // 11) fin_pre = silu(hat2 @ W_o' + bias_o')
        gemm_pipe<<<dim3((DIM / 128) * (R / 128)), 256, 0, stream>>>(
            hat2, WT_o, bias_o, fin_pre, R, DIM, 1024, DIM);
        // 12) d_out(fp32) = x + fin_pre + dwconv(fin_pre)
        dwconv_res<float><<<dim3(DIM / 64, NN / 64, CB), 256, 0, stream>>>(
            fin_pre, dw_o, xc, outc, DIM, DIM);
    }
}

// Round 8
// 430.948 us; speedup vs baseline: 1.0688x; 1.0688x over previous
//
#include <hip/hip_runtime.h>
#include <hip/hip_bf16.h>

typedef __hip_bfloat16 bf16;
typedef __attribute__((ext_vector_type(8))) short short8;
typedef __attribute__((ext_vector_type(4))) short short4v;
typedef __attribute__((ext_vector_type(2))) short short2v;
typedef __attribute__((ext_vector_type(4))) float float4v;
typedef __attribute__((ext_vector_type(2))) float float2v;
__device__ __forceinline__ float b2f(bf16 v){ return __bfloat162float(v); }
__device__ __forceinline__ bf16 f2b(float v){ return __float2bfloat16(v); }
__device__ __forceinline__ void stv(float* p, long i, float v){ p[i] = v; }
__device__ __forceinline__ void stv(bf16*  p, long i, float v){ p[i] = f2b(v); }

#define MFMA __builtin_amdgcn_mfma_f32_16x16x32_bf16
#define AS1(p) ((const __attribute__((address_space(1))) void*)(p))
#define AS3(p) ((__attribute__((address_space(3))) void*)(p))

// Problem constants
#define BB   8
#define NN   2048
#define DIM  512
#define HID  2048
#define DQK  128
#define GRP  256
#define NG   8
#define KW   17
#define BK   32
#define NHQ  2176   // merged N for h(2048) + qk(128) buffers (stride)

// ---------------- LayerNorm: fp32 input, token-shift, float2-vectorized (all batches) ----
template<int D, int SHIFT_HALF>
__global__ __launch_bounds__(256) void ln_kernel_f(const float* __restrict__ in,
                                                   bf16* __restrict__ out)
{
    int row = blockIdx.x;
    int t = row % NN;
    int tid = threadIdx.x;
    int c0 = tid * 2;                      // D = 512, 2 floats/thread
    float2v v2 = {0.f, 0.f};
    if (SHIFT_HALF && c0 < D / 2) {
        if (t > 0) v2 = *(const float2v*)(in + ((long)row - 1) * D + c0);
    } else {
        v2 = *(const float2v*)(in + (long)row * D + c0);
    }
    float s = v2[0] + v2[1];
    float ss = v2[0] * v2[0] + v2[1] * v2[1];
    for (int o = 32; o > 0; o >>= 1) { s += __shfl_down(s, o); ss += __shfl_down(ss, o); }
    __shared__ float sm[4], sm2[4];
    int wid = tid >> 6, lane = tid & 63;
    if (lane == 0) { sm[wid] = s; sm2[wid] = ss; }
    __syncthreads();
    if (tid == 0) {
        float a = 0.f, q = 0.f;
        for (int w = 0; w < 4; w++) { a += sm[w]; q += sm2[w]; }
        sm[0] = a; sm2[0] = q;
    }
    __syncthreads();
    float mean = sm[0] / D;
    float var  = fmaxf(sm2[0] / D - mean * mean, 0.f);
    float rs = rsqrtf(var + 1e-5f);
    union { short2v v; bf16 h[2]; } o2;
    o2.h[0] = f2b((v2[0] - mean) * rs);
    o2.h[1] = f2b((v2[1] - mean) * rs);
    *(short2v*)(out + (long)row * D + c0) = o2.v;
}

// vectorized bf16 LN: D=1024, each thread owns 4 contiguous cols (8B loads/stores)
template<int D>
__global__ __launch_bounds__(256) void ln_kernel_bf(const bf16* __restrict__ in,
                                                    bf16* __restrict__ out)
{
    int row = blockIdx.x;
    int tid = threadIdx.x;
    int c0 = tid * 4;
    union { short4v v; bf16 h[4]; } u;
    u.v = *(const short4v*)(in + (long)row * D + c0);
    float vals[4];
    float s = 0.f, ss = 0.f;
    #pragma unroll
    for (int i = 0; i < 4; i++) {
        float v = b2f(u.h[i]);
        vals[i] = v; s += v; ss += v * v;
    }
    for (int o = 32; o > 0; o >>= 1) { s += __shfl_down(s, o); ss += __shfl_down(ss, o); }
    __shared__ float sm[4], sm2[4];
    int wid = tid >> 6, lane = tid & 63;
    if (lane == 0) { sm[wid] = s; sm2[wid] = ss; }
    __syncthreads();
    if (tid == 0) {
        float a = 0.f, q = 0.f;
        for (int w = 0; w < 4; w++) { a += sm[w]; q += sm2[w]; }
        sm[0] = a; sm2[0] = q;
    }
    __syncthreads();
    float mean = sm[0] / D;
    float var  = fmaxf(sm2[0] / D - mean * mean, 0.f);
    float rs = rsqrtf(var + 1e-5f);
    union { short4v v; bf16 h[4]; } o4;
    #pragma unroll
    for (int i = 0; i < 4; i++) o4.h[i] = f2b((vals[i] - mean) * rs);
    *(short4v*)(out + (long)row * D + c0) = o4.v;
}

// ---------------- merged weight prep: all 3 WT in one launch -----------------------------
__global__ __launch_bounds__(256) void prep_all(
    const float* __restrict__ W_h,  const float* __restrict__ g_h,  bf16* __restrict__ WT_h,
    const float* __restrict__ W_qk, const float* __restrict__ g_qk, bf16* __restrict__ WT_qk,
    const float* __restrict__ W_o,  const float* __restrict__ g_o,  bf16* __restrict__ WT_o)
{
    int i = blockIdx.x;
    const float *W, *g; bf16* WT; int K, N, k0, n0;
    if (i < 1024) {                 // W_h: K=512 (16 kb), N=2048 (64 nb)
        W = W_h; g = g_h; WT = WT_h; K = DIM; N = HID;
        k0 = (i & 15) * 32; n0 = (i >> 4) * 32;
    } else if (i < 1088) {          // W_qk: K=512 (16 kb), N=128 (4 nb)
        int j = i - 1024;
        W = W_qk; g = g_qk; WT = WT_qk; K = DIM; N = DQK;
        k0 = (j & 15) * 32; n0 = (j >> 4) * 32;
    } else {                        // W_o: K=1024 (32 kb), N=512 (16 nb)
        int j = i - 1088;
        W = W_o; g = g_o; WT = WT_o; K = 1024; N = DIM;
        k0 = (j & 31) * 32; n0 = (j >> 5) * 32;
    }
    __shared__ float Ws[32][33];
    int tid = threadIdx.x;
    for (int l = 0; l < 4; l++) {
        int e = tid + 256 * l;
        int kk = e >> 5, nn = e & 31;
        Ws[kk][nn] = g[k0 + kk] * W[(size_t)(k0 + kk) * N + n0 + nn];
    }
    __syncthreads();
    for (int l = 0; l < 4; l++) {
        int e = tid + 256 * l;
        int nn = e >> 5, kk = e & 31;
        WT[(size_t)(n0 + nn) * K + k0 + kk] = f2b(Ws[kk][nn]);
    }
}

// ---------------- merged bias init --------------------------------------------------------
__global__ __launch_bounds__(256) void bias_init3(
    const float* __restrict__ b_h, const float* __restrict__ b_qk,
    const float* __restrict__ b_o, float* __restrict__ bias_hq,
    float* __restrict__ bias_o)
{
    int n = blockIdx.x * 256 + threadIdx.x;
    if (n < HID)                 bias_hq[n] = b_h[n];
    else if (n < NHQ)            bias_hq[n] = b_qk[n - HID];
    else if (n < NHQ + DIM)      bias_o[n - NHQ] = b_o[n - NHQ];
}

// ---------------- merged bias reduce (parallel over K, atomics — r5-proven) --------------
#define BKC 64
__global__ __launch_bounds__(256) void bias_reduce3(
    const float* __restrict__ W_h,  const float* __restrict__ lnb_h,
    const float* __restrict__ W_qk, const float* __restrict__ lnb_qk,
    const float* __restrict__ W_o,  const float* __restrict__ lnb_o,
    float* __restrict__ bias_hq, float* __restrict__ bias_o)
{
    int i = blockIdx.x;
    const float *W, *lnb; float* out; int N, n, k0;
    if (i < 64) {                   // W_h: N=2048 (8 nb), K=512 (8 kb)
        W = W_h; lnb = lnb_h; out = bias_hq; N = HID;
        n = (i & 7) * 256 + threadIdx.x; k0 = (i >> 3) * BKC;
    } else if (i < 72) {            // W_qk: N=128 (1 nb), K=512 (8 kb)
        int j = i - 64;
        W = W_qk; lnb = lnb_qk; out = bias_hq + HID; N = DQK;
        n = threadIdx.x; k0 = j * BKC;
    } else {                        // W_o: N=512 (2 nb), K=1024 (16 kb)
        int j = i - 72;
        W = W_o; lnb = lnb_o; out = bias_o; N = DIM;
        n = (j & 1) * 256 + threadIdx.x; k0 = (j >> 1) * BKC;
    }
    if (n >= N) return;
    float s = 0.f;
    #pragma unroll 8
    for (int k = k0; k < k0 + BKC; k++) s += lnb[k] * W[(size_t)k * N + n];
    atomicAdd(&out[n], s);
}

// ---------------- staging helper: 128 rows x 32 cols bf16 tile via global_load_lds -------
__device__ __forceinline__ void stage_tile(const bf16* base, size_t ld, bf16* dst,
                                           int wave, int lane)
{
    int lrow = lane >> 2, lcol = lane & 3;
    for (int cc = 0; cc < 2; cc++) {
        int c = wave * 2 + cc;
        int row = c * 16 + lrow;
        const bf16* g = base + (size_t)row * ld + lcol * 8;
        __builtin_amdgcn_global_load_lds(AS1(g), AS3(dst + c * 512), 16, 0, 0);
    }
}

// ============ shared 3-slot pipelined 128x128 GEMM core (T3/T4/T5, proven in r2) =========
#define PIPE_SLOT 8192   // As(128x32) + Bs(128x32) bf16 = 16 KiB

__device__ __forceinline__ void pipe_core(
    const bf16* __restrict__ Abase, size_t ldA,
    const bf16* __restrict__ Bbase, size_t ldB,
    int nit, bf16* lds, int wave, int lane, float4v acc[4][4])
{
    auto stage = [&](int it, int slot) {
        bf16* As = lds + slot * PIPE_SLOT;
        stage_tile(Abase + (size_t)it * 32, ldA, As, wave, lane);
        stage_tile(Bbase + (size_t)it * 32, ldB, As + 4096, wave, lane);
    };
    stage(0, 0);
    stage(1, 1);
    asm volatile("s_waitcnt vmcnt(4)" ::: "memory");
    __builtin_amdgcn_s_barrier();
    __builtin_amdgcn_sched_barrier(0);

    int wm = wave & 1, wn = wave >> 1;
    int col = lane & 15, quad = lane >> 4;
    int slot = 0;
    for (int it = 0; it < nit; it++) {
        const bf16* As = lds + slot * PIPE_SLOT;
        const bf16* Bs = As + 4096;
        short8 a[4], b[4];
        #pragma unroll
        for (int t = 0; t < 4; t++) {
            a[t] = *(const short8*)(As + (wm * 64 + t * 16 + col) * 32 + quad * 8);
            b[t] = *(const short8*)(Bs + (wn * 64 + t * 16 + col) * 32 + quad * 8);
        }
        int nslot = slot + 1; if (nslot == 3) nslot = 0;
        int pslot = nslot + 1; if (pslot == 3) pslot = 0;   // (slot+2)%3
        if (it + 2 < nit) stage(it + 2, pslot);
        asm volatile("s_waitcnt lgkmcnt(0)" ::: "memory");
        __builtin_amdgcn_sched_barrier(0);
        __builtin_amdgcn_s_setprio(1);
        #pragma unroll
        for (int i = 0; i < 4; i++)
            #pragma unroll
            for (int j = 0; j < 4; j++)
                acc[i][j] = MFMA(a[i], b[j], acc[i][j], 0, 0, 0);
        __builtin_amdgcn_s_setprio(0);
        __builtin_amdgcn_sched_barrier(0);
        if (it + 2 < nit) { asm volatile("s_waitcnt vmcnt(4)" ::: "memory"); }
        else              { asm volatile("s_waitcnt vmcnt(0)" ::: "memory"); }
        __builtin_amdgcn_s_barrier();
        __builtin_amdgcn_sched_barrier(0);
        slot = nslot;
    }
}

// ---------------- pipelined MFMA GEMM: C = silu(A@B^T + bias); XCD-affine m-blocks -------
__global__ __launch_bounds__(256) void gemm_pipe(
    const bf16* __restrict__ A, const bf16* __restrict__ BT,
    const float* __restrict__ bias, bf16* __restrict__ C,
    int M, int N, int K, int ldC)
{
    __shared__ __align__(16) bf16 lds[3 * PIPE_SLOT];
    int nb = N >> 7;
    int i = blockIdx.x;
    int xcd = i & 7, r = i >> 3;
    int m0 = (xcd + 8 * (r / nb)) << 7;   // same-A-panel blocks share an XCD
    int n0 = (r % nb) << 7;
    int tid = threadIdx.x, wave = tid >> 6, lane = tid & 63;
    float4v acc[4][4] = {};
    pipe_core(A + (size_t)m0 * K, K, BT + (size_t)n0 * K, K, K / 32,
              lds, wave, lane, acc);
    int wm = wave & 1, wn = wave >> 1;
    int col = lane & 15, quad = lane >> 4;
    for (int i2 = 0; i2 < 4; i2++) {
        for (int j = 0; j < 4; j++) {
            int n = n0 + wn * 64 + j * 16 + col;
            float bs = bias[n];
            for (int r2 = 0; r2 < 4; r2++) {
                int m = m0 + wm * 64 + i2 * 16 + quad * 4 + r2;
                float v = acc[i2][j][r2] + bs;
                v = v / (1.f + __expf(-v));
                C[(size_t)m * ldC + n] = f2b(v);
            }
        }
    }
}

// ============== 256x256 8-wave BK=64 multi-phase GEMM (T1+T2+T3/T4+T5) ==================
__device__ __forceinline__ void stage_half256(const bf16* __restrict__ g0, int ld,
                                              bf16* dst, int tid)
{
    int wb = tid & ~63;   // wave*64
    #pragma unroll
    for (int l = 0; l < 2; l++) {
        int idx = l * 512 + tid;
        int row = idx >> 3;
        int c8  = (idx & 7) ^ (row & 7);
        const bf16* g = g0 + (size_t)row * ld + c8 * 8;
        __builtin_amdgcn_global_load_lds(AS1(g), AS3(dst + (size_t)(l * 512 + wb) * 8), 16, 0, 0);
    }
}

__device__ __forceinline__ short8 ldsfrag(const bf16* h, int row, int g)
{
    return *(const short8*)(h + row * 64 + ((g ^ (row & 7)) << 3));
}

__global__ __launch_bounds__(512, 2) void gemm256(
    const bf16* __restrict__ A, const bf16* __restrict__ BT,
    const float* __restrict__ bias, bf16* __restrict__ C,
    int N, int K, int ldC)
{
    __shared__ __align__(16) bf16 As[2][2][128][64];
    __shared__ __align__(16) bf16 Bs[2][2][128][64];
    int nbx = N >> 8;
    int nwg = gridDim.x;
    int cpx = nwg >> 3;               // grid is always a multiple of 8 -> bijective
    int bid = blockIdx.x;
    int swz = (bid & 7) * cpx + (bid >> 3);
    int bx = swz % nbx, by = swz / nbx;
    int m0 = by << 8, n0 = bx << 8;
    int tid = threadIdx.x, wave = tid >> 6, lane = tid & 63;
    int wm = wave >> 2, wn = wave & 3;      // 2 (M) x 4 (N) waves
    int col = lane & 15, quad = lane >> 4;
    int nkt = K >> 6;
    float4v acc[8][4] = {};

    const bf16* Ag = A  + (size_t)m0 * K;
    const bf16* Bg = BT + (size_t)n0 * K;

    // prologue: stage K-tile 0 fully into buf0
    #pragma unroll
    for (int h = 0; h < 2; h++) {
        stage_half256(Ag + (size_t)h * 128 * K, K, &As[0][h][0][0], tid);
        stage_half256(Bg + (size_t)h * 128 * K, K, &Bs[0][h][0][0], tid);
    }
    asm volatile("s_waitcnt vmcnt(0)" ::: "memory");
    __builtin_amdgcn_s_barrier();

    for (int kt = 0; kt < nkt; kt++) {
        int buf = kt & 1;
        const bf16* Ah = &As[buf][wm][0][0];
        const bf16* Bh = &Bs[buf][wn >> 1][0][0];
        int brb = (wn & 1) * 64;
        short8 ar[2][4], br[2][2], br2[2][2];
        bool pf = (kt + 1 < nkt);

        // ---------------- P1: read a(qi=0), b(qj=0); stage A+B halves of kt+1 -----------
        #pragma unroll
        for (int i = 0; i < 4; i++)
            #pragma unroll
            for (int ks = 0; ks < 2; ks++)
                ar[ks][i] = ldsfrag(Ah, i * 16 + col, ks * 4 + quad);
        #pragma unroll
        for (int j = 0; j < 2; j++)
            #pragma unroll
            for (int ks = 0; ks < 2; ks++)
                br[ks][j] = ldsfrag(Bh, brb + j * 16 + col, ks * 4 + quad);
        if (pf) {
            #pragma unroll
            for (int h = 0; h < 2; h++) {
                stage_half256(Ag + (size_t)h * 128 * K + (kt + 1) * 64, K,
                              &As[buf ^ 1][h][0][0], tid);
                stage_half256(Bg + (size_t)h * 128 * K + (kt + 1) * 64, K,
                              &Bs[buf ^ 1][h][0][0], tid);
            }
        }
        __builtin_amdgcn_s_barrier();
        __builtin_amdgcn_s_setprio(1);
        #pragma unroll
        for (int i = 0; i < 4; i++)
            #pragma unroll
            for (int j = 0; j < 2; j++) {
                acc[i][j] = MFMA(ar[0][i], br[0][j], acc[i][j], 0, 0, 0);
                acc[i][j] = MFMA(ar[1][i], br[1][j], acc[i][j], 0, 0, 0);
            }
        __builtin_amdgcn_s_setprio(0);
        __builtin_amdgcn_s_barrier();

        // ---------------- P2: read b(qj=1) ----------------------------------------------
        #pragma unroll
        for (int j = 0; j < 2; j++)
            #pragma unroll
            for (int ks = 0; ks < 2; ks++)
                br2[ks][j] = ldsfrag(Bh, brb + (j + 2) * 16 + col, ks * 4 + quad);
        __builtin_amdgcn_s_barrier();
        __builtin_amdgcn_s_setprio(1);
        #pragma unroll
        for (int i = 0; i < 4; i++)
            #pragma unroll
            for (int j = 0; j < 2; j++) {
                acc[i][j + 2] = MFMA(ar[0][i], br2[0][j], acc[i][j + 2], 0, 0, 0);
                acc[i][j + 2] = MFMA(ar[1][i], br2[1][j], acc[i][j + 2], 0, 0, 0);
            }
        __builtin_amdgcn_s_setprio(0);
        __builtin_amdgcn_s_barrier();

        // ---------------- P3: read a(qi=1) ----------------------------------------------
        #pragma unroll
        for (int i = 0; i < 4; i++)
            #pragma unroll
            for (int ks = 0; ks < 2; ks++)
                ar[ks][i] = ldsfrag(Ah, (i + 4) * 16 + col, ks * 4 + quad);
        __builtin_amdgcn_s_barrier();
        __builtin_amdgcn_s_setprio(1);
        #pragma unroll
        for (int i = 0; i < 4; i++)
            #pragma unroll
            for (int j = 0; j < 2; j++) {
                acc[i + 4][j + 2] = MFMA(ar[0][i], br2[0][j], acc[i + 4][j + 2], 0, 0, 0);
                acc[i + 4][j + 2] = MFMA(ar[1][i], br2[1][j], acc[i + 4][j + 2], 0, 0, 0);
            }
        __builtin_amdgcn_s_setprio(0);
        __builtin_amdgcn_s_barrier();

        // ---------------- P4: read b(qj=0) again ----------------------------------------
        #pragma unroll
        for (int j = 0; j < 2; j++)
            #pragma unroll
            for (int ks = 0; ks < 2; ks++)
                br[ks][j] = ldsfrag(Bh, brb + j * 16 + col, ks * 4 + quad);
        __builtin_amdgcn_s_barrier();
        __builtin_amdgcn_s_setprio(1);
        #pragma unroll
        for (int i = 0; i < 4; i++)
            #pragma unroll
            for (int j = 0; j < 2; j++) {
                acc[i + 4][j] = MFMA(ar[0][i], br[0][j], acc[i + 4][j], 0, 0, 0);
                acc[i + 4][j] = MFMA(ar[1][i], br[1][j], acc[i + 4][j], 0, 0, 0);
            }
        __builtin_amdgcn_s_setprio(0);
        __builtin_amdgcn_sched_barrier(0);
        asm volatile("s_waitcnt vmcnt(0)" ::: "memory");
        __builtin_amdgcn_s_barrier();
    }

    // epilogue: bias + silu + store
    #pragma unroll
    for (int i = 0; i < 8; i++) {
        #pragma unroll
        for (int j = 0; j < 4; j++) {
            int n = n0 + wn * 64 + j * 16 + col;
            float bs = bias[n];
            #pragma unroll
            for (int r = 0; r < 4; r++) {
                int m = m0 + wm * 128 + i * 16 + quad * 4 + r;
                float v = acc[i][j][r] + bs;
                v = v / (1.f + __expf(-v));
                C[(size_t)m * ldC + n] = f2b(v);
            }
        }
    }
}

// ======== merged attn_score + linkv (one launch; both pipe_core; XCD-affine) =============
__global__ __launch_bounds__(256) void score_linkv(
    const bf16* __restrict__ quadq, const bf16* __restrict__ quadk,
    bf16* __restrict__ P,
    const bf16* __restrict__ hidT, const bf16* __restrict__ linkT,
    float* __restrict__ linkvT, int rowsC, int nScore)
{
    __shared__ __align__(16) bf16 lds[3 * PIPE_SLOT];
    int tid = threadIdx.x, wave = tid >> 6, lane = tid & 63;
    if ((int)blockIdx.x < nScore) {
        // ---- attn scores: P = relu(QK^T/256)^2, causal ----
        int i = blockIdx.x;
        int xcd = i & 7, r = i >> 3;
        int g = xcd + 8 * (r >> 2);
        int t = r & 3, bi = t >> 1, bj = t & 1;
        bf16* Pg = P + (size_t)g * GRP * GRP;
        if (bj > bi) {   // fully masked tile: write zeros
            short8 z = {};
            int rr = tid >> 1, half = tid & 1;
            short* dst = (short*)Pg + (size_t)(bi * 128 + rr) * GRP + bj * 128 + half * 64;
            for (int q = 0; q < 8; q++) ((short8*)dst)[q] = z;
            return;
        }
        float4v acc[4][4] = {};
        const bf16* Ab = quadq + (size_t)(g * GRP + bi * 128) * DQK;
        const bf16* Bb = quadk + (size_t)(g * GRP + bj * 128) * DQK;
        pipe_core(Ab, DQK, Bb, DQK, DQK / 32, lds, wave, lane, acc);
        int wm = wave & 1, wn = wave >> 1;
        int col = lane & 15, quad = lane >> 4;
        for (int i2 = 0; i2 < 4; i2++) {
            for (int j = 0; j < 4; j++) {
                int jj = bj * 128 + wn * 64 + j * 16 + col;
                for (int r2 = 0; r2 < 4; r2++) {
                    int ii = bi * 128 + wm * 64 + i2 * 16 + quad * 4 + r2;
                    float s = acc[i2][j][r2] * (1.f / GRP);
                    s = fmaxf(s, 0.f); s = s * s;
                    if (jj > ii) s = 0.f;
                    Pg[(size_t)ii * GRP + jj] = f2b(s);
                }
            }
        }
    } else {
        // ---- linkv: linkvT[g][e][d] = (hidT_g @ linkT_g^T)/256 ----
        int i = blockIdx.x - nScore;       // nScore % 8 == 0 -> XCD parity preserved
        int xcd = i & 7, r = i >> 3;
        int g = xcd + 8 * (r >> 4);
        int eb = r & 15;
        int e0 = eb * 128;
        float4v acc[4][4] = {};
        pipe_core(hidT + (size_t)e0 * rowsC + g * GRP, rowsC,
                  linkT + g * GRP, rowsC, GRP / 32, lds, wave, lane, acc);
        float* out = linkvT + (size_t)g * (HID * DQK);
        int wm = wave & 1, wn = wave >> 1;
        int col = lane & 15, quad = lane >> 4;
        for (int i2 = 0; i2 < 4; i2++) {
            for (int j = 0; j < 4; j++) {
                int d = wn * 64 + j * 16 + col;
                for (int r2 = 0; r2 < 4; r2++) {
                    int e = e0 + wm * 64 + i2 * 16 + quad * 4 + r2;
                    out[(size_t)e * DQK + d] = acc[i2][j][r2] * (1.f / GRP);
                }
            }
        }
    }
}

// ---------------- exclusive cumsum over group axis, fp32 in -> bf16 out (x4 vec) ---------
__global__ void cumsum_bf(const float* __restrict__ in, bf16* __restrict__ out)
{
    long idx4 = (long)blockIdx.x * blockDim.x + threadIdx.x;   // 4 elems per thread
    int b = (int)(idx4 / (DQK * HID / 4));
    long off = (idx4 % (DQK * HID / 4)) * 4;
    const float* pi = in + (long)b * NG * DQK * HID + off;
    bf16* po = out + (long)b * NG * DQK * HID + off;
    float4v run = {0.f, 0.f, 0.f, 0.f};
    for (int gi = 0; gi < NG; gi++) {
        short4v o4;
        union { short s; bf16 h; } cv;
        #pragma unroll
        for (int k = 0; k < 4; k++) { cv.h = f2b(run[k]); o4[k] = cv.s; }
        *(short4v*)(po + (long)gi * DQK * HID) = o4;
        run += *(const float4v*)(pi + (long)gi * DQK * HID);
    }
}

// ---------------- fused attn apply MFMA + gating — 3-slot pipelined, XCD-affine ----------
// gating reads hidT (ch-major) — row-major `hid` buffer eliminated entirely
#define AP_SLOT (256 * BK + 128 * BK)   // 12288 bf16 = 24 KiB per slot

__global__ __launch_bounds__(256) void attn_apply_mfma(
    const bf16* __restrict__ P, const bf16* __restrict__ hidT,
    const bf16* __restrict__ linq, const bf16* __restrict__ linkvb,
    bf16* __restrict__ outg, int rowsC)
{
    int ib = blockIdx.x;
    int xcd = ib & 7, rb = ib >> 3;
    int g = xcd + 8 * (rb >> 4);          // all 16 e-blocks of a group share an XCD
    int e0 = (rb & 15) * 64;
    __shared__ __align__(16) bf16 lds[3 * AP_SLOT];
    int tid = threadIdx.x, wave = tid >> 6, lane = tid & 63;
    int lrow = lane >> 2, lcol = lane & 3;
    const bf16* Pg = P + (size_t)g * GRP * GRP;
    const bf16* Lg = linkvb + (size_t)g * (HID * DQK);

    // stage iteration 'it' (0..7: quad j0=it*32; 8..11: lin d0=(it-8)*32) into 'slot'
    auto stage = [&](int it, int slot) {
        bf16* As = lds + slot * AP_SLOT;
        bf16* Bs = As + 256 * BK;
        if (it < 8) {
            int j0 = it * 32;
            for (int cc = 0; cc < 4; cc++) {
                int c = wave * 4 + cc;
                int row = c * 16 + lrow;
                const bf16* ga = Pg + (size_t)row * GRP + j0 + lcol * 8;
                __builtin_amdgcn_global_load_lds(AS1(ga), AS3(As + c * 512), 16, 0, 0);
            }
            for (int cc = 0; cc < 2; cc++) {
                int c = wave * 2 + cc;
                int row = c * 16 + lrow;
                int er = (row < 64) ? (e0 + row) : (1024 + e0 + (row - 64));
                const bf16* gb = hidT + (size_t)er * rowsC + g * GRP + j0 + lcol * 8;
                __builtin_amdgcn_global_load_lds(AS1(gb), AS3(Bs + c * 512), 16, 0, 0);
            }
        } else {
            int d0 = (it - 8) * 32;
            for (int cc = 0; cc < 4; cc++) {
                int c = wave * 4 + cc;
                int row = c * 16 + lrow;
                const bf16* ga = linq + (size_t)(g * GRP + row) * DQK + d0 + lcol * 8;
                __builtin_amdgcn_global_load_lds(AS1(ga), AS3(As + c * 512), 16, 0, 0);
            }
            for (int cc = 0; cc < 2; cc++) {
                int c = wave * 2 + cc;
                int row = c * 16 + lrow;
                int er = (row < 64) ? (e0 + row) : (1024 + e0 + (row - 64));
                const bf16* gb = Lg + (size_t)er * DQK + d0 + lcol * 8;
                __builtin_amdgcn_global_load_lds(AS1(gb), AS3(Bs + c * 512), 16, 0, 0);
            }
        }
    };

    // prologue: slots 0 and 1 in flight; wait for slot 0 (6 loads of slot1 may remain)
    stage(0, 0);
    stage(1, 1);
    asm volatile("s_waitcnt vmcnt(6)" ::: "memory");
    __builtin_amdgcn_s_barrier();
    __builtin_amdgcn_sched_barrier(0);

    float4v acc[4][8] = {};
    int col = lane & 15, quad = lane >> 4;
    int slot = 0;
    for (int it = 0; it < 12; it++) {
        const bf16* As = lds + slot * AP_SLOT;
        const bf16* Bs = As + 256 * BK;
        short8 a[4], b[8];
        #pragma unroll
        for (int t = 0; t < 4; t++)
            a[t] = *(const short8*)(As + (wave * 64 + t * 16 + col) * BK + quad * 8);
        #pragma unroll
        for (int t = 0; t < 8; t++)
            b[t] = *(const short8*)(Bs + (t * 16 + col) * BK + quad * 8);
        int nslot = slot + 1; if (nslot == 3) nslot = 0;
        int pslot = nslot + 1; if (pslot == 3) pslot = 0;   // (slot+2)%3
        if (it + 2 < 12) stage(it + 2, pslot);
        asm volatile("s_waitcnt lgkmcnt(0)" ::: "memory");
        __builtin_amdgcn_sched_barrier(0);
        __builtin_amdgcn_s_setprio(1);
        #pragma unroll
        for (int i = 0; i < 4; i++)
            #pragma unroll
            for (int j = 0; j < 8; j++)
                acc[i][j] = MFMA(a[i], b[j], acc[i][j], 0, 0, 0);
        __builtin_amdgcn_s_setprio(0);
        __builtin_amdgcn_sched_barrier(0);
        if (it + 2 < 12) { asm volatile("s_waitcnt vmcnt(6)" ::: "memory"); }
        else             { asm volatile("s_waitcnt vmcnt(0)" ::: "memory"); }
        __builtin_amdgcn_s_barrier();
        __builtin_amdgcn_sched_barrier(0);
        slot = nslot;
    }

    // epilogue with gating (v,u read from hidT: row e contiguous in token)
    for (int mt = 0; mt < 4; mt++) {
        for (int nt = 0; nt < 4; nt++) {
            for (int r = 0; r < 4; r++) {
                int tokg = g * GRP + wave * 64 + mt * 16 + quad * 4 + r;
                int e = e0 + nt * 16 + col;
                float av = acc[mt][nt][r];
                float au = acc[mt][nt + 4][r];
                float v = b2f(hidT[(size_t)e * rowsC + tokg]);
                float u = b2f(hidT[(size_t)(1024 + e) * rowsC + tokg]);
                float gate = 1.f / (1.f + __expf(-av * u));
                outg[(size_t)tokg * 1024 + e] = f2b(au * v * gate);
            }
        }
    }
}

// ======== merged dwconv: h-path (hidT only) + qk-path (affine split), one launch =========
__global__ __launch_bounds__(256) void dwconv_both(
    const bf16* __restrict__ hq, const float* __restrict__ dw_h,
    bf16* __restrict__ hidT,
    const float* __restrict__ dw_qk,
    const float* __restrict__ gamma, const float* __restrict__ beta,
    bf16* __restrict__ quadq, bf16* __restrict__ quadk,
    bf16* __restrict__ linq, bf16* __restrict__ linkT,
    int rowsC, int nDual)
{
    __shared__ float s[80][64];
    __shared__ bf16 o[64][72];   // [ch][tok], row stride 144 B (16B-aligned)
    int tid = threadIdx.x;
    if ((int)blockIdx.x < nDual) {
        // ---- h path: hidT = h + dwconv(h), transposed write only ----
        int i = blockIdx.x;
        int c0 = (i & 31) * 64;            // HID/64 = 32
        int t0 = ((i >> 5) & 31) * 64;     // NN/64 = 32
        int b  = i >> 10;
        const bf16* base = hq + (size_t)b * NN * NHQ + c0;
        {
            int ch8 = (tid & 7) * 8, rw = tid >> 3;
            #pragma unroll
            for (int ps = 0; ps < 3; ps++) {
                int tt = rw + ps * 32;
                if (tt < 80) {
                    int t = t0 + tt - 8;
                    union { short8 v; bf16 h[8]; } u; u.v = short8{};
                    if (t >= 0 && t < NN)
                        u.v = *(const short8*)(base + (size_t)t * NHQ + ch8);
                    float* sp = &s[tt][ch8];
                    #pragma unroll
                    for (int k = 0; k < 8; k++) sp[k] = b2f(u.h[k]);
                }
            }
        }
        __syncthreads();
        int c = tid & 63, rp = tid >> 6;
        float w[KW];
        for (int k = 0; k < KW; k++) w[k] = dw_h[k * HID + c0 + c];
        for (int l = 0; l < 16; l++) {
            int r = rp + l * 4;
            float acc = s[r + 8][c];
            for (int k = 0; k < KW; k++) acc += s[r + k][c] * w[k];
            o[c][r] = f2b(acc);
        }
        __syncthreads();
        // write hidT (ch-major [ch][rowsC]) as short8
        {
            int t8 = (tid & 7) * 8, ch = tid >> 3;
            #pragma unroll
            for (int ps = 0; ps < 2; ps++) {
                int cc = ch + ps * 32;
                short8 v = *(const short8*)(&o[cc][t8]);
                *(short8*)(hidT + (size_t)(c0 + cc) * rowsC + b * NN + t0 + t8) = v;
            }
        }
    } else {
        // ---- qk path: conv + 4-way affine -> quadq/quadk/linq/linkT ----
        int i = blockIdx.x - nDual;
        int c0 = (i & 1) * 64;             // DQK/64 = 2
        int t0 = ((i >> 1) & 31) * 64;
        int b  = i >> 6;
        const bf16* base = hq + HID + (size_t)b * NN * NHQ + c0;
        {
            int ch8 = (tid & 7) * 8, rw = tid >> 3;
            #pragma unroll
            for (int ps = 0; ps < 3; ps++) {
                int tt = rw + ps * 32;
                if (tt < 80) {
                    int t = t0 + tt - 8;
                    union { short8 v; bf16 h[8]; } u; u.v = short8{};
                    if (t >= 0 && t < NN)
                        u.v = *(const short8*)(base + (size_t)t * NHQ + ch8);
                    float* sp = &s[tt][ch8];
                    #pragma unroll
                    for (int k = 0; k < 8; k++) sp[k] = b2f(u.h[k]);
                }
            }
        }
        __syncthreads();
        int c = tid & 63, rp = tid >> 6;
        float w[KW];
        for (int k = 0; k < KW; k++) w[k] = dw_qk[k * DQK + c0 + c];
        float ga0 = gamma[0 * DQK + c0 + c], be0 = beta[0 * DQK + c0 + c];
        float ga1 = gamma[1 * DQK + c0 + c], be1 = beta[1 * DQK + c0 + c];
        float ga2 = gamma[2 * DQK + c0 + c], be2 = beta[2 * DQK + c0 + c];
        float ga3 = gamma[3 * DQK + c0 + c], be3 = beta[3 * DQK + c0 + c];
        for (int l = 0; l < 16; l++) {
            int r = rp + l * 4;
            float acc = s[r + 8][c];
            for (int k = 0; k < KW; k++) acc += s[r + k][c] * w[k];
            size_t tok = (size_t)b * NN + t0 + r;
            quadq[tok * DQK + c0 + c] = f2b(acc * ga0 + be0);
            linq [tok * DQK + c0 + c] = f2b(acc * ga1 + be1);
            quadk[tok * DQK + c0 + c] = f2b(acc * ga2 + be2);
            o[c][r] = f2b(acc * ga3 + be3);
        }
        __syncthreads();
        // transposed write of linkT rows c0..c0+63
        int t8 = (tid & 7) * 8, ch = tid >> 3;
        #pragma unroll
        for (int ps = 0; ps < 2; ps++) {
            int cc = ch + ps * 32;
            short8 v = *(const short8*)(&o[cc][t8]);
            *(short8*)(linkT + (size_t)(c0 + cc) * rowsC + b * NN + t0 + t8) = v;
        }
    }
}

// ---------------- dwconv (generic, vectorized staging) -----------------------------------
template<typename TO>
__global__ __launch_bounds__(256) void dwconv_res(
    const bf16* __restrict__ src, const float* __restrict__ dw,
    const float* __restrict__ xres, TO* __restrict__ dst, int C, int ldS)
{
    int c0 = blockIdx.x * 64;
    int t0 = blockIdx.y * 64;
    int b  = blockIdx.z;
    __shared__ float s[80][64];
    int tid = threadIdx.x;
    int c = tid & 63;
    int rp = tid >> 6;
    const bf16* base = src + (size_t)b * NN * ldS + c0;
    {
        int ch8 = (tid & 7) * 8, rw = tid >> 3;
        #pragma unroll
        for (int ps = 0; ps < 3; ps++) {
            int tt = rw + ps * 32;
            if (tt < 80) {
                int t = t0 + tt - 8;
                union { short8 v; bf16 h[8]; } u; u.v = short8{};
                if (t >= 0 && t < NN)
                    u.v = *(const short8*)(base + (size_t)t * ldS + ch8);
                float* sp = &s[tt][ch8];
                #pragma unroll
                for (int k = 0; k < 8; k++) sp[k] = b2f(u.h[k]);
            }
        }
    }
    __syncthreads();
    float w[KW];
    for (int k = 0; k < KW; k++) w[k] = dw[k * C + c0 + c];
    for (int l = 0; l < 16; l++) {
        int r = rp + l * 4;
        float acc = s[r + 8][c];
        for (int k = 0; k < KW; k++) acc += s[r + k][c] * w[k];
        long gidx = ((long)b * NN + t0 + r) * C + c0 + c;
        if (xres) acc += xres[gidx];
        stv(dst, gidx, acc);
    }
}

extern "C" void kernel_launch(void* const* d_in, const int* in_sizes, int n_in,
                              void* d_out, int out_size, void* d_ws, size_t ws_size,
                              hipStream_t stream)
{
    const float* x      = (const float*)d_in[0];
    const float* ln_h_g = (const float*)d_in[1];
    const float* ln_h_b = (const float*)d_in[2];
    const float* W_h    = (const float*)d_in[3];
    const float* b_h    = (const float*)d_in[4];
    const float* dw_h   = (const float*)d_in[5];
    const float* ln_qk_g= (const float*)d_in[6];
    const float* ln_qk_b= (const float*)d_in[7];
    const float* W_qk   = (const float*)d_in[8];
    const float* b_qk   = (const float*)d_in[9];
    const float* dw_qk  = (const float*)d_in[10];
    const float* gamma  = (const float*)d_in[11];
    const float* beta   = (const float*)d_in[12];
    const float* ln_o_g = (const float*)d_in[13];
    const float* ln_o_b = (const float*)d_in[14];
    const float* W_o    = (const float*)d_in[15];
    const float* b_o    = (const float*)d_in[16];
    const float* dw_o   = (const float*)d_in[17];
    float* outp = (float*)d_out;

    // ---- fixed region ----
    char* p = (char*)d_ws;
    bf16* WT_hq = (bf16*)p;  p += (size_t)NHQ * DIM * 2;
    bf16* WT_o  = (bf16*)p;  p += (size_t)DIM * 1024 * 2;
    float* bias_hq = (float*)p; p += NHQ * 4;
    float* bias_o  = (float*)p; p += DIM * 4;
    bf16* hat1_all = (bf16*)p;  p += (size_t)BB * NN * DIM * 2;  // LN(x) for all batches
    p = (char*)(((uintptr_t)p + 255) & ~(uintptr_t)255);
    size_t fixed = (size_t)(p - (char*)d_ws);
    bf16* WT_h  = WT_hq;
    bf16* WT_qk = WT_hq + (size_t)HID * DIM;
    float* bias_h  = bias_hq;

    auto bytes_for = [fixed](int cb) -> size_t {
        size_t rows = (size_t)cb * NN;
        return fixed
             + rows * NHQ * 2           // s1 hq / linkvT / fin_pre
             + rows * 1024 * 2          // s2 hat2
             + rows * HID * 2           // s3 hidT
             + rows * 1024 * 2          // s4 outg
             + (size_t)cb * NG * GRP * GRP * 2   // s5 P
             + 4 * rows * DQK * 2       // s6 linkT + quadq/quadk/linq
             + rows * 1024 * 2          // s11 linkvb
             + 4096;
    };
    int CB = 1;
    if (bytes_for(4) <= ws_size) CB = 4;
    else if (bytes_for(2) <= ws_size) CB = 2;
    const int rowsC = CB * NN;
    const size_t rows = (size_t)rowsC;

    char* s1 = p;               p += rows * NHQ * 2;   // hq -> linkvT -> fin_pre
    char* s2 = p;               p += rows * 1024 * 2;  // hat2
    char* s3 = p;               p += rows * HID * 2;   // hidT
    char* s4 = p;               p += rows * 1024 * 2;  // outg
    char* s5 = p;               p += (size_t)CB * NG * GRP * GRP * 2;  // P
    char* s6 = p;               p += rows * DQK * 2;   // linkT
    char* s8 = p;               p += rows * DQK * 2;   // quadq
    char* s9 = p;               p += rows * DQK * 2;   // quadk
    char* s10 = p;              p += rows * DQK * 2;   // linq
    char* s11 = p;              p += rows * 1024 * 2;  // linkvb (bf16 cumsum out)

    bf16*  hq      = (bf16*)s1;
    float* linkvT  = (float*)s1;
    bf16*  fin_pre = (bf16*)s1;
    bf16*  hat2    = (bf16*)s2;
    bf16*  hidT    = (bf16*)s3;
    bf16*  outg    = (bf16*)s4;
    bf16*  P       = (bf16*)s5;
    bf16*  linkT   = (bf16*)s6;
    bf16*  quadq   = (bf16*)s8;
    bf16*  quadk   = (bf16*)s9;
    bf16*  linq    = (bf16*)s10;
    bf16*  linkvb  = (bf16*)s11;

    // ---- weight prep (3 launches) + LN of all batches (1 launch) ----
    prep_all<<<1600, 256, 0, stream>>>(W_h, ln_h_g, WT_h,
                                       W_qk, ln_qk_g, WT_qk,
                                       W_o, ln_o_g, WT_o);
    bias_init3<<<(NHQ + DIM + 255) / 256, 256, 0, stream>>>(b_h, b_qk, b_o, bias_hq, bias_o);
    bias_reduce3<<<104, 256, 0, stream>>>(W_h, ln_h_b, W_qk, ln_qk_b, W_o, ln_o_b,
                                          bias_hq, bias_o);
    ln_kernel_f<DIM, 1><<<BB * NN, 256, 0, stream>>>(x, hat1_all);

    const int G = CB * NG;   // groups per chunk
    for (int b0 = 0; b0 < BB; b0 += CB) {
        const float* xc = x    + (size_t)b0 * NN * DIM;
        float* outc     = outp + (size_t)b0 * NN * DIM;
        const bf16* hat1 = hat1_all + (size_t)b0 * NN * DIM;
        int R = rowsC;

        // 2a) h-part (N=2048) on the 256x256 kernel — grid exactly 256 = 1 wave @ 1 blk/CU
        gemm256<<<dim3((R / 256) * (HID / 256)), 512, 0, stream>>>(
            hat1, WT_h, bias_h, hq, HID, DIM, NHQ);
        // 2b) qk-part (N=128) on the pipelined 128x128 kernel
        gemm_pipe<<<dim3(R / 128), 256, 0, stream>>>(
            hat1, WT_qk, bias_hq + HID, hq + HID, R, 128, DIM, NHQ);
        // 3+4+5) merged dwconv: h transposed-write + qk conv+affine
        {
            int nDual = (HID / 64) * (NN / 64) * CB;
            int nQk   = (DQK / 64) * (NN / 64) * CB;
            dwconv_both<<<nDual + nQk, 256, 0, stream>>>(
                hq, dw_h, hidT, dw_qk, gamma, beta,
                quadq, quadk, linq, linkT, rowsC, nDual);
        }
        // 6+7) merged scores + linkv (both depend only on dwconv outputs)
        score_linkv<<<4 * G + 16 * G, 256, 0, stream>>>(
            quadq, quadk, P, hidT, linkT, linkvT, rowsC, 4 * G);
        // 8) exclusive cumsum over groups -> linkvb bf16
        cumsum_bf<<<(CB * DQK * HID) / (256 * 4), 256, 0, stream>>>(linkvT, linkvb);
        // 9) fused apply + gating -> outg (v,u from hidT), XCD-affine per group
        attn_apply_mfma<<<dim3(16 * G), 256, 0, stream>>>(P, hidT, linq, linkvb, outg, rowsC);
        // 10) LN(outg) -> hat2
        ln_kernel_bf<1024><<<R, 256, 0, stream>>>(outg, hat2);
        // 11) fin_pre = silu(hat2 @ W_o' + bias_o')
        gemm_pipe<<<dim3((DIM / 128) * (R / 128)), 256, 0, stream>>>(
            hat2, WT_o, bias_o, fin_pre, R, DIM, 1024, DIM);
        // 12) d_out(fp32) = x + fin_pre + dwconv(fin_pre)
        dwconv_res<float><<<dim3(DIM / 64, NN / 64, CB), 256, 0, stream>>>(
            fin_pre, dw_o, xc, outc, DIM, DIM);
    }
}

// Round 9
// 393.591 us; speedup vs baseline: 1.1702x; 1.0949x over previous
//
#include <hip/hip_runtime.h>
#include <hip/hip_bf16.h>

typedef __hip_bfloat16 bf16;
typedef __attribute__((ext_vector_type(8))) short short8;
typedef __attribute__((ext_vector_type(4))) short short4v;
typedef __attribute__((ext_vector_type(2))) short short2v;
typedef __attribute__((ext_vector_type(4))) float float4v;
typedef __attribute__((ext_vector_type(2))) float float2v;
__device__ __forceinline__ float b2f(bf16 v){ return __bfloat162float(v); }
__device__ __forceinline__ bf16 f2b(float v){ return __float2bfloat16(v); }
__device__ __forceinline__ void stv(float* p, long i, float v){ p[i] = v; }
__device__ __forceinline__ void stv(bf16*  p, long i, float v){ p[i] = f2b(v); }

#define MFMA __builtin_amdgcn_mfma_f32_16x16x32_bf16
#define AS1(p) ((const __attribute__((address_space(1))) void*)(p))
#define AS3(p) ((__attribute__((address_space(3))) void*)(p))

// Problem constants
#define BB   8
#define NN   2048
#define DIM  512
#define HID  2048
#define DQK  128
#define GRP  256
#define NG   8
#define KW   17
#define BK   32
#define NHQ  2176   // merged N for h(2048) + qk(128) buffers (stride)

// ---------------- LayerNorm: fp32 input, token-shift, float2-vectorized ------------------
template<int D, int SHIFT_HALF>
__global__ __launch_bounds__(256) void ln_kernel_f(const float* __restrict__ in,
                                                   bf16* __restrict__ out)
{
    int row = blockIdx.x;
    int t = row % NN;
    int tid = threadIdx.x;
    int c0 = tid * 2;                      // D = 512, 2 floats/thread
    float2v v2 = {0.f, 0.f};
    if (SHIFT_HALF && c0 < D / 2) {
        if (t > 0) v2 = *(const float2v*)(in + ((long)row - 1) * D + c0);
    } else {
        v2 = *(const float2v*)(in + (long)row * D + c0);
    }
    float s = v2[0] + v2[1];
    float ss = v2[0] * v2[0] + v2[1] * v2[1];
    for (int o = 32; o > 0; o >>= 1) { s += __shfl_down(s, o); ss += __shfl_down(ss, o); }
    __shared__ float sm[4], sm2[4];
    int wid = tid >> 6, lane = tid & 63;
    if (lane == 0) { sm[wid] = s; sm2[wid] = ss; }
    __syncthreads();
    if (tid == 0) {
        float a = 0.f, q = 0.f;
        for (int w = 0; w < 4; w++) { a += sm[w]; q += sm2[w]; }
        sm[0] = a; sm2[0] = q;
    }
    __syncthreads();
    float mean = sm[0] / D;
    float var  = fmaxf(sm2[0] / D - mean * mean, 0.f);
    float rs = rsqrtf(var + 1e-5f);
    union { short2v v; bf16 h[2]; } o2;
    o2.h[0] = f2b((v2[0] - mean) * rs);
    o2.h[1] = f2b((v2[1] - mean) * rs);
    *(short2v*)(out + (long)row * D + c0) = o2.v;
}

// vectorized bf16 LN: D=1024, each thread owns 4 contiguous cols (8B loads/stores)
template<int D>
__global__ __launch_bounds__(256) void ln_kernel_bf(const bf16* __restrict__ in,
                                                    bf16* __restrict__ out)
{
    int row = blockIdx.x;
    int tid = threadIdx.x;
    int c0 = tid * 4;
    union { short4v v; bf16 h[4]; } u;
    u.v = *(const short4v*)(in + (long)row * D + c0);
    float vals[4];
    float s = 0.f, ss = 0.f;
    #pragma unroll
    for (int i = 0; i < 4; i++) {
        float v = b2f(u.h[i]);
        vals[i] = v; s += v; ss += v * v;
    }
    for (int o = 32; o > 0; o >>= 1) { s += __shfl_down(s, o); ss += __shfl_down(ss, o); }
    __shared__ float sm[4], sm2[4];
    int wid = tid >> 6, lane = tid & 63;
    if (lane == 0) { sm[wid] = s; sm2[wid] = ss; }
    __syncthreads();
    if (tid == 0) {
        float a = 0.f, q = 0.f;
        for (int w = 0; w < 4; w++) { a += sm[w]; q += sm2[w]; }
        sm[0] = a; sm2[0] = q;
    }
    __syncthreads();
    float mean = sm[0] / D;
    float var  = fmaxf(sm2[0] / D - mean * mean, 0.f);
    float rs = rsqrtf(var + 1e-5f);
    union { short4v v; bf16 h[4]; } o4;
    #pragma unroll
    for (int i = 0; i < 4; i++) o4.h[i] = f2b((vals[i] - mean) * rs);
    *(short4v*)(out + (long)row * D + c0) = o4.v;
}

// ---------------- merged weight prep: all 3 WT in one launch -----------------------------
__global__ __launch_bounds__(256) void prep_all(
    const float* __restrict__ W_h,  const float* __restrict__ g_h,  bf16* __restrict__ WT_h,
    const float* __restrict__ W_qk, const float* __restrict__ g_qk, bf16* __restrict__ WT_qk,
    const float* __restrict__ W_o,  const float* __restrict__ g_o,  bf16* __restrict__ WT_o)
{
    int i = blockIdx.x;
    const float *W, *g; bf16* WT; int K, N, k0, n0;
    if (i < 1024) {                 // W_h: K=512 (16 kb), N=2048 (64 nb)
        W = W_h; g = g_h; WT = WT_h; K = DIM; N = HID;
        k0 = (i & 15) * 32; n0 = (i >> 4) * 32;
    } else if (i < 1088) {          // W_qk: K=512 (16 kb), N=128 (4 nb)
        int j = i - 1024;
        W = W_qk; g = g_qk; WT = WT_qk; K = DIM; N = DQK;
        k0 = (j & 15) * 32; n0 = (j >> 4) * 32;
    } else {                        // W_o: K=1024 (32 kb), N=512 (16 nb)
        int j = i - 1088;
        W = W_o; g = g_o; WT = WT_o; K = 1024; N = DIM;
        k0 = (j & 31) * 32; n0 = (j >> 5) * 32;
    }
    __shared__ float Ws[32][33];
    int tid = threadIdx.x;
    for (int l = 0; l < 4; l++) {
        int e = tid + 256 * l;
        int kk = e >> 5, nn = e & 31;
        Ws[kk][nn] = g[k0 + kk] * W[(size_t)(k0 + kk) * N + n0 + nn];
    }
    __syncthreads();
    for (int l = 0; l < 4; l++) {
        int e = tid + 256 * l;
        int nn = e >> 5, kk = e & 31;
        WT[(size_t)(n0 + nn) * K + k0 + kk] = f2b(Ws[kk][nn]);
    }
}

// ---------------- merged bias init --------------------------------------------------------
__global__ __launch_bounds__(256) void bias_init3(
    const float* __restrict__ b_h, const float* __restrict__ b_qk,
    const float* __restrict__ b_o, float* __restrict__ bias_hq,
    float* __restrict__ bias_o)
{
    int n = blockIdx.x * 256 + threadIdx.x;
    if (n < HID)                 bias_hq[n] = b_h[n];
    else if (n < NHQ)            bias_hq[n] = b_qk[n - HID];
    else if (n < NHQ + DIM)      bias_o[n - NHQ] = b_o[n - NHQ];
}

// ---------------- merged bias reduce (parallel over K, atomics — r5-proven) --------------
#define BKC 64
__global__ __launch_bounds__(256) void bias_reduce3(
    const float* __restrict__ W_h,  const float* __restrict__ lnb_h,
    const float* __restrict__ W_qk, const float* __restrict__ lnb_qk,
    const float* __restrict__ W_o,  const float* __restrict__ lnb_o,
    float* __restrict__ bias_hq, float* __restrict__ bias_o)
{
    int i = blockIdx.x;
    const float *W, *lnb; float* out; int N, n, k0;
    if (i < 64) {                   // W_h: N=2048 (8 nb), K=512 (8 kb)
        W = W_h; lnb = lnb_h; out = bias_hq; N = HID;
        n = (i & 7) * 256 + threadIdx.x; k0 = (i >> 3) * BKC;
    } else if (i < 72) {            // W_qk: N=128 (1 nb), K=512 (8 kb)
        int j = i - 64;
        W = W_qk; lnb = lnb_qk; out = bias_hq + HID; N = DQK;
        n = threadIdx.x; k0 = j * BKC;
    } else {                        // W_o: N=512 (2 nb), K=1024 (16 kb)
        int j = i - 72;
        W = W_o; lnb = lnb_o; out = bias_o; N = DIM;
        n = (j & 1) * 256 + threadIdx.x; k0 = (j >> 1) * BKC;
    }
    if (n >= N) return;
    float s = 0.f;
    #pragma unroll 8
    for (int k = k0; k < k0 + BKC; k++) s += lnb[k] * W[(size_t)k * N + n];
    atomicAdd(&out[n], s);
}

// ---------------- staging helper: 128 rows x 32 cols bf16 tile via global_load_lds -------
__device__ __forceinline__ void stage_tile(const bf16* base, size_t ld, bf16* dst,
                                           int wave, int lane)
{
    int lrow = lane >> 2, lcol = lane & 3;
    for (int cc = 0; cc < 2; cc++) {
        int c = wave * 2 + cc;
        int row = c * 16 + lrow;
        const bf16* g = base + (size_t)row * ld + lcol * 8;
        __builtin_amdgcn_global_load_lds(AS1(g), AS3(dst + c * 512), 16, 0, 0);
    }
}

// ============ shared 3-slot pipelined 128x128 GEMM core (T3/T4/T5, proven in r2) =========
#define PIPE_SLOT 8192   // As(128x32) + Bs(128x32) bf16 = 16 KiB

__device__ __forceinline__ void pipe_core(
    const bf16* __restrict__ Abase, size_t ldA,
    const bf16* __restrict__ Bbase, size_t ldB,
    int nit, bf16* lds, int wave, int lane, float4v acc[4][4])
{
    auto stage = [&](int it, int slot) {
        bf16* As = lds + slot * PIPE_SLOT;
        stage_tile(Abase + (size_t)it * 32, ldA, As, wave, lane);
        stage_tile(Bbase + (size_t)it * 32, ldB, As + 4096, wave, lane);
    };
    stage(0, 0);
    stage(1, 1);
    asm volatile("s_waitcnt vmcnt(4)" ::: "memory");
    __builtin_amdgcn_s_barrier();
    __builtin_amdgcn_sched_barrier(0);

    int wm = wave & 1, wn = wave >> 1;
    int col = lane & 15, quad = lane >> 4;
    int slot = 0;
    for (int it = 0; it < nit; it++) {
        const bf16* As = lds + slot * PIPE_SLOT;
        const bf16* Bs = As + 4096;
        short8 a[4], b[4];
        #pragma unroll
        for (int t = 0; t < 4; t++) {
            a[t] = *(const short8*)(As + (wm * 64 + t * 16 + col) * 32 + quad * 8);
            b[t] = *(const short8*)(Bs + (wn * 64 + t * 16 + col) * 32 + quad * 8);
        }
        int nslot = slot + 1; if (nslot == 3) nslot = 0;
        int pslot = nslot + 1; if (pslot == 3) pslot = 0;   // (slot+2)%3
        if (it + 2 < nit) stage(it + 2, pslot);
        asm volatile("s_waitcnt lgkmcnt(0)" ::: "memory");
        __builtin_amdgcn_sched_barrier(0);
        __builtin_amdgcn_s_setprio(1);
        #pragma unroll
        for (int i = 0; i < 4; i++)
            #pragma unroll
            for (int j = 0; j < 4; j++)
                acc[i][j] = MFMA(a[i], b[j], acc[i][j], 0, 0, 0);
        __builtin_amdgcn_s_setprio(0);
        __builtin_amdgcn_sched_barrier(0);
        if (it + 2 < nit) { asm volatile("s_waitcnt vmcnt(4)" ::: "memory"); }
        else              { asm volatile("s_waitcnt vmcnt(0)" ::: "memory"); }
        __builtin_amdgcn_s_barrier();
        __builtin_amdgcn_sched_barrier(0);
        slot = nslot;
    }
}

// ---------------- pipelined MFMA GEMM: C = silu(A@B^T + bias); XCD-affine m-blocks -------
__global__ __launch_bounds__(256) void gemm_pipe(
    const bf16* __restrict__ A, const bf16* __restrict__ BT,
    const float* __restrict__ bias, bf16* __restrict__ C,
    int M, int N, int K, int ldC)
{
    __shared__ __align__(16) bf16 lds[3 * PIPE_SLOT];
    int nb = N >> 7;
    int i = blockIdx.x;
    int xcd = i & 7, r = i >> 3;
    int m0 = (xcd + 8 * (r / nb)) << 7;   // same-A-panel blocks share an XCD
    int n0 = (r % nb) << 7;
    int tid = threadIdx.x, wave = tid >> 6, lane = tid & 63;
    float4v acc[4][4] = {};
    pipe_core(A + (size_t)m0 * K, K, BT + (size_t)n0 * K, K, K / 32,
              lds, wave, lane, acc);
    int wm = wave & 1, wn = wave >> 1;
    int col = lane & 15, quad = lane >> 4;
    for (int i2 = 0; i2 < 4; i2++) {
        for (int j = 0; j < 4; j++) {
            int n = n0 + wn * 64 + j * 16 + col;
            float bs = bias[n];
            for (int r2 = 0; r2 < 4; r2++) {
                int m = m0 + wm * 64 + i2 * 16 + quad * 4 + r2;
                float v = acc[i2][j][r2] + bs;
                v = v / (1.f + __expf(-v));
                C[(size_t)m * ldC + n] = f2b(v);
            }
        }
    }
}

// ============== 256x256 8-wave BK=64 multi-phase GEMM (T1+T2+T3/T4+T5) ==================
__device__ __forceinline__ void stage_half256(const bf16* __restrict__ g0, int ld,
                                              bf16* dst, int tid)
{
    int wb = tid & ~63;   // wave*64
    #pragma unroll
    for (int l = 0; l < 2; l++) {
        int idx = l * 512 + tid;
        int row = idx >> 3;
        int c8  = (idx & 7) ^ (row & 7);
        const bf16* g = g0 + (size_t)row * ld + c8 * 8;
        __builtin_amdgcn_global_load_lds(AS1(g), AS3(dst + (size_t)(l * 512 + wb) * 8), 16, 0, 0);
    }
}

__device__ __forceinline__ short8 ldsfrag(const bf16* h, int row, int g)
{
    return *(const short8*)(h + row * 64 + ((g ^ (row & 7)) << 3));
}

__global__ __launch_bounds__(512, 2) void gemm256(
    const bf16* __restrict__ A, const bf16* __restrict__ BT,
    const float* __restrict__ bias, bf16* __restrict__ C,
    int N, int K, int ldC)
{
    __shared__ __align__(16) bf16 As[2][2][128][64];
    __shared__ __align__(16) bf16 Bs[2][2][128][64];
    int nbx = N >> 8;
    int nwg = gridDim.x;
    int cpx = nwg >> 3;               // grid is always a multiple of 8 -> bijective
    int bid = blockIdx.x;
    int swz = (bid & 7) * cpx + (bid >> 3);
    int bx = swz % nbx, by = swz / nbx;
    int m0 = by << 8, n0 = bx << 8;
    int tid = threadIdx.x, wave = tid >> 6, lane = tid & 63;
    int wm = wave >> 2, wn = wave & 3;      // 2 (M) x 4 (N) waves
    int col = lane & 15, quad = lane >> 4;
    int nkt = K >> 6;
    float4v acc[8][4] = {};

    const bf16* Ag = A  + (size_t)m0 * K;
    const bf16* Bg = BT + (size_t)n0 * K;

    // prologue: stage K-tile 0 fully into buf0
    #pragma unroll
    for (int h = 0; h < 2; h++) {
        stage_half256(Ag + (size_t)h * 128 * K, K, &As[0][h][0][0], tid);
        stage_half256(Bg + (size_t)h * 128 * K, K, &Bs[0][h][0][0], tid);
    }
    asm volatile("s_waitcnt vmcnt(0)" ::: "memory");
    __builtin_amdgcn_s_barrier();

    for (int kt = 0; kt < nkt; kt++) {
        int buf = kt & 1;
        const bf16* Ah = &As[buf][wm][0][0];
        const bf16* Bh = &Bs[buf][wn >> 1][0][0];
        int brb = (wn & 1) * 64;
        short8 ar[2][4], br[2][2], br2[2][2];
        bool pf = (kt + 1 < nkt);

        // ---------------- P1: read a(qi=0), b(qj=0); stage A+B halves of kt+1 -----------
        #pragma unroll
        for (int i = 0; i < 4; i++)
            #pragma unroll
            for (int ks = 0; ks < 2; ks++)
                ar[ks][i] = ldsfrag(Ah, i * 16 + col, ks * 4 + quad);
        #pragma unroll
        for (int j = 0; j < 2; j++)
            #pragma unroll
            for (int ks = 0; ks < 2; ks++)
                br[ks][j] = ldsfrag(Bh, brb + j * 16 + col, ks * 4 + quad);
        if (pf) {
            #pragma unroll
            for (int h = 0; h < 2; h++) {
                stage_half256(Ag + (size_t)h * 128 * K + (kt + 1) * 64, K,
                              &As[buf ^ 1][h][0][0], tid);
                stage_half256(Bg + (size_t)h * 128 * K + (kt + 1) * 64, K,
                              &Bs[buf ^ 1][h][0][0], tid);
            }
        }
        __builtin_amdgcn_s_barrier();
        __builtin_amdgcn_s_setprio(1);
        #pragma unroll
        for (int i = 0; i < 4; i++)
            #pragma unroll
            for (int j = 0; j < 2; j++) {
                acc[i][j] = MFMA(ar[0][i], br[0][j], acc[i][j], 0, 0, 0);
                acc[i][j] = MFMA(ar[1][i], br[1][j], acc[i][j], 0, 0, 0);
            }
        __builtin_amdgcn_s_setprio(0);
        __builtin_amdgcn_s_barrier();

        // ---------------- P2: read b(qj=1) ----------------------------------------------
        #pragma unroll
        for (int j = 0; j < 2; j++)
            #pragma unroll
            for (int ks = 0; ks < 2; ks++)
                br2[ks][j] = ldsfrag(Bh, brb + (j + 2) * 16 + col, ks * 4 + quad);
        __builtin_amdgcn_s_barrier();
        __builtin_amdgcn_s_setprio(1);
        #pragma unroll
        for (int i = 0; i < 4; i++)
            #pragma unroll
            for (int j = 0; j < 2; j++) {
                acc[i][j + 2] = MFMA(ar[0][i], br2[0][j], acc[i][j + 2], 0, 0, 0);
                acc[i][j + 2] = MFMA(ar[1][i], br2[1][j], acc[i][j + 2], 0, 0, 0);
            }
        __builtin_amdgcn_s_setprio(0);
        __builtin_amdgcn_s_barrier();

        // ---------------- P3: read a(qi=1) ----------------------------------------------
        #pragma unroll
        for (int i = 0; i < 4; i++)
            #pragma unroll
            for (int ks = 0; ks < 2; ks++)
                ar[ks][i] = ldsfrag(Ah, (i + 4) * 16 + col, ks * 4 + quad);
        __builtin_amdgcn_s_barrier();
        __builtin_amdgcn_s_setprio(1);
        #pragma unroll
        for (int i = 0; i < 4; i++)
            #pragma unroll
            for (int j = 0; j < 2; j++) {
                acc[i + 4][j + 2] = MFMA(ar[0][i], br2[0][j], acc[i + 4][j + 2], 0, 0, 0);
                acc[i + 4][j + 2] = MFMA(ar[1][i], br2[1][j], acc[i + 4][j + 2], 0, 0, 0);
            }
        __builtin_amdgcn_s_setprio(0);
        __builtin_amdgcn_s_barrier();

        // ---------------- P4: read b(qj=0) again ----------------------------------------
        #pragma unroll
        for (int j = 0; j < 2; j++)
            #pragma unroll
            for (int ks = 0; ks < 2; ks++)
                br[ks][j] = ldsfrag(Bh, brb + j * 16 + col, ks * 4 + quad);
        __builtin_amdgcn_s_barrier();
        __builtin_amdgcn_s_setprio(1);
        #pragma unroll
        for (int i = 0; i < 4; i++)
            #pragma unroll
            for (int j = 0; j < 2; j++) {
                acc[i + 4][j] = MFMA(ar[0][i], br[0][j], acc[i + 4][j], 0, 0, 0);
                acc[i + 4][j] = MFMA(ar[1][i], br[1][j], acc[i + 4][j], 0, 0, 0);
            }
        __builtin_amdgcn_s_setprio(0);
        __builtin_amdgcn_sched_barrier(0);
        asm volatile("s_waitcnt vmcnt(0)" ::: "memory");
        __builtin_amdgcn_s_barrier();
    }

    // epilogue: bias + silu + store
    #pragma unroll
    for (int i = 0; i < 8; i++) {
        #pragma unroll
        for (int j = 0; j < 4; j++) {
            int n = n0 + wn * 64 + j * 16 + col;
            float bs = bias[n];
            #pragma unroll
            for (int r = 0; r < 4; r++) {
                int m = m0 + wm * 128 + i * 16 + quad * 4 + r;
                float v = acc[i][j][r] + bs;
                v = v / (1.f + __expf(-v));
                C[(size_t)m * ldC + n] = f2b(v);
            }
        }
    }
}

// ======== merged attn_score + linkv (one launch; both pipe_core; XCD-affine) =============
__global__ __launch_bounds__(256) void score_linkv(
    const bf16* __restrict__ quadq, const bf16* __restrict__ quadk,
    bf16* __restrict__ P,
    const bf16* __restrict__ hidT, const bf16* __restrict__ linkT,
    float* __restrict__ linkvT, int rowsC, int nScore)
{
    __shared__ __align__(16) bf16 lds[3 * PIPE_SLOT];
    int tid = threadIdx.x, wave = tid >> 6, lane = tid & 63;
    if ((int)blockIdx.x < nScore) {
        // ---- attn scores: P = relu(QK^T/256)^2, causal ----
        int i = blockIdx.x;
        int xcd = i & 7, r = i >> 3;
        int g = xcd + 8 * (r >> 2);
        int t = r & 3, bi = t >> 1, bj = t & 1;
        bf16* Pg = P + (size_t)g * GRP * GRP;
        if (bj > bi) {   // fully masked tile: write zeros
            short8 z = {};
            int rr = tid >> 1, half = tid & 1;
            short* dst = (short*)Pg + (size_t)(bi * 128 + rr) * GRP + bj * 128 + half * 64;
            for (int q = 0; q < 8; q++) ((short8*)dst)[q] = z;
            return;
        }
        float4v acc[4][4] = {};
        const bf16* Ab = quadq + (size_t)(g * GRP + bi * 128) * DQK;
        const bf16* Bb = quadk + (size_t)(g * GRP + bj * 128) * DQK;
        pipe_core(Ab, DQK, Bb, DQK, DQK / 32, lds, wave, lane, acc);
        int wm = wave & 1, wn = wave >> 1;
        int col = lane & 15, quad = lane >> 4;
        for (int i2 = 0; i2 < 4; i2++) {
            for (int j = 0; j < 4; j++) {
                int jj = bj * 128 + wn * 64 + j * 16 + col;
                for (int r2 = 0; r2 < 4; r2++) {
                    int ii = bi * 128 + wm * 64 + i2 * 16 + quad * 4 + r2;
                    float s = acc[i2][j][r2] * (1.f / GRP);
                    s = fmaxf(s, 0.f); s = s * s;
                    if (jj > ii) s = 0.f;
                    Pg[(size_t)ii * GRP + jj] = f2b(s);
                }
            }
        }
    } else {
        // ---- linkv: linkvT[g][e][d] = (hidT_g @ linkT_g^T)/256 ----
        int i = blockIdx.x - nScore;       // nScore % 8 == 0 -> XCD parity preserved
        int xcd = i & 7, r = i >> 3;
        int g = xcd + 8 * (r >> 4);
        int eb = r & 15;
        int e0 = eb * 128;
        float4v acc[4][4] = {};
        pipe_core(hidT + (size_t)e0 * rowsC + g * GRP, rowsC,
                  linkT + g * GRP, rowsC, GRP / 32, lds, wave, lane, acc);
        float* out = linkvT + (size_t)g * (HID * DQK);
        int wm = wave & 1, wn = wave >> 1;
        int col = lane & 15, quad = lane >> 4;
        for (int i2 = 0; i2 < 4; i2++) {
            for (int j = 0; j < 4; j++) {
                int d = wn * 64 + j * 16 + col;
                for (int r2 = 0; r2 < 4; r2++) {
                    int e = e0 + wm * 64 + i2 * 16 + quad * 4 + r2;
                    out[(size_t)e * DQK + d] = acc[i2][j][r2] * (1.f / GRP);
                }
            }
        }
    }
}

// ---------------- exclusive cumsum over group axis, fp32 in -> bf16 out (x4 vec) ---------
__global__ void cumsum_bf(const float* __restrict__ in, bf16* __restrict__ out)
{
    long idx4 = (long)blockIdx.x * blockDim.x + threadIdx.x;   // 4 elems per thread
    int b = (int)(idx4 / (DQK * HID / 4));
    long off = (idx4 % (DQK * HID / 4)) * 4;
    const float* pi = in + (long)b * NG * DQK * HID + off;
    bf16* po = out + (long)b * NG * DQK * HID + off;
    float4v run = {0.f, 0.f, 0.f, 0.f};
    for (int gi = 0; gi < NG; gi++) {
        short4v o4;
        union { short s; bf16 h; } cv;
        #pragma unroll
        for (int k = 0; k < 4; k++) { cv.h = f2b(run[k]); o4[k] = cv.s; }
        *(short4v*)(po + (long)gi * DQK * HID) = o4;
        run += *(const float4v*)(pi + (long)gi * DQK * HID);
    }
}

// ---------------- fused attn apply MFMA + gating — 3-slot pipelined, XCD-affine ----------
// gating reads hidT (ch-major) via short4 over the 4 consecutive tokens of each quad
#define AP_SLOT (256 * BK + 128 * BK)   // 12288 bf16 = 24 KiB per slot

__global__ __launch_bounds__(256) void attn_apply_mfma(
    const bf16* __restrict__ P, const bf16* __restrict__ hidT,
    const bf16* __restrict__ linq, const bf16* __restrict__ linkvb,
    bf16* __restrict__ outg, int rowsC)
{
    int ib = blockIdx.x;
    int xcd = ib & 7, rb = ib >> 3;
    int g = xcd + 8 * (rb >> 4);          // all 16 e-blocks of a group share an XCD
    int e0 = (rb & 15) * 64;
    __shared__ __align__(16) bf16 lds[3 * AP_SLOT];
    int tid = threadIdx.x, wave = tid >> 6, lane = tid & 63;
    int lrow = lane >> 2, lcol = lane & 3;
    const bf16* Pg = P + (size_t)g * GRP * GRP;
    const bf16* Lg = linkvb + (size_t)g * (HID * DQK);

    // stage iteration 'it' (0..7: quad j0=it*32; 8..11: lin d0=(it-8)*32) into 'slot'
    auto stage = [&](int it, int slot) {
        bf16* As = lds + slot * AP_SLOT;
        bf16* Bs = As + 256 * BK;
        if (it < 8) {
            int j0 = it * 32;
            for (int cc = 0; cc < 4; cc++) {
                int c = wave * 4 + cc;
                int row = c * 16 + lrow;
                const bf16* ga = Pg + (size_t)row * GRP + j0 + lcol * 8;
                __builtin_amdgcn_global_load_lds(AS1(ga), AS3(As + c * 512), 16, 0, 0);
            }
            for (int cc = 0; cc < 2; cc++) {
                int c = wave * 2 + cc;
                int row = c * 16 + lrow;
                int er = (row < 64) ? (e0 + row) : (1024 + e0 + (row - 64));
                const bf16* gb = hidT + (size_t)er * rowsC + g * GRP + j0 + lcol * 8;
                __builtin_amdgcn_global_load_lds(AS1(gb), AS3(Bs + c * 512), 16, 0, 0);
            }
        } else {
            int d0 = (it - 8) * 32;
            for (int cc = 0; cc < 4; cc++) {
                int c = wave * 4 + cc;
                int row = c * 16 + lrow;
                const bf16* ga = linq + (size_t)(g * GRP + row) * DQK + d0 + lcol * 8;
                __builtin_amdgcn_global_load_lds(AS1(ga), AS3(As + c * 512), 16, 0, 0);
            }
            for (int cc = 0; cc < 2; cc++) {
                int c = wave * 2 + cc;
                int row = c * 16 + lrow;
                int er = (row < 64) ? (e0 + row) : (1024 + e0 + (row - 64));
                const bf16* gb = Lg + (size_t)er * DQK + d0 + lcol * 8;
                __builtin_amdgcn_global_load_lds(AS1(gb), AS3(Bs + c * 512), 16, 0, 0);
            }
        }
    };

    // prologue: slots 0 and 1 in flight; wait for slot 0 (6 loads of slot1 may remain)
    stage(0, 0);
    stage(1, 1);
    asm volatile("s_waitcnt vmcnt(6)" ::: "memory");
    __builtin_amdgcn_s_barrier();
    __builtin_amdgcn_sched_barrier(0);

    float4v acc[4][8] = {};
    int col = lane & 15, quad = lane >> 4;
    int slot = 0;
    for (int it = 0; it < 12; it++) {
        const bf16* As = lds + slot * AP_SLOT;
        const bf16* Bs = As + 256 * BK;
        short8 a[4], b[8];
        #pragma unroll
        for (int t = 0; t < 4; t++)
            a[t] = *(const short8*)(As + (wave * 64 + t * 16 + col) * BK + quad * 8);
        #pragma unroll
        for (int t = 0; t < 8; t++)
            b[t] = *(const short8*)(Bs + (t * 16 + col) * BK + quad * 8);
        int nslot = slot + 1; if (nslot == 3) nslot = 0;
        int pslot = nslot + 1; if (pslot == 3) pslot = 0;   // (slot+2)%3
        if (it + 2 < 12) stage(it + 2, pslot);
        asm volatile("s_waitcnt lgkmcnt(0)" ::: "memory");
        __builtin_amdgcn_sched_barrier(0);
        __builtin_amdgcn_s_setprio(1);
        #pragma unroll
        for (int i = 0; i < 4; i++)
            #pragma unroll
            for (int j = 0; j < 8; j++)
                acc[i][j] = MFMA(a[i], b[j], acc[i][j], 0, 0, 0);
        __builtin_amdgcn_s_setprio(0);
        __builtin_amdgcn_sched_barrier(0);
        if (it + 2 < 12) { asm volatile("s_waitcnt vmcnt(6)" ::: "memory"); }
        else             { asm volatile("s_waitcnt vmcnt(0)" ::: "memory"); }
        __builtin_amdgcn_s_barrier();
        __builtin_amdgcn_sched_barrier(0);
        slot = nslot;
    }

    // epilogue with gating: v,u loaded as short4 over the 4 consecutive tokens (r dim)
    for (int mt = 0; mt < 4; mt++) {
        int tokg0 = g * GRP + wave * 64 + mt * 16 + quad * 4;
        for (int nt = 0; nt < 4; nt++) {
            int e = e0 + nt * 16 + col;
            union { short4v v; bf16 h[4]; } v4, u4;
            v4.v = *(const short4v*)(hidT + (size_t)e * rowsC + tokg0);
            u4.v = *(const short4v*)(hidT + (size_t)(1024 + e) * rowsC + tokg0);
            #pragma unroll
            for (int r = 0; r < 4; r++) {
                float av = acc[mt][nt][r];
                float au = acc[mt][nt + 4][r];
                float v = b2f(v4.h[r]);
                float u = b2f(u4.h[r]);
                float gate = 1.f / (1.f + __expf(-av * u));
                outg[(size_t)(tokg0 + r) * 1024 + e] = f2b(au * v * gate);
            }
        }
    }
}

// ======== merged dwconv: h-path (hidT only) + qk-path (affine split), one launch =========
__global__ __launch_bounds__(256) void dwconv_both(
    const bf16* __restrict__ hq, const float* __restrict__ dw_h,
    bf16* __restrict__ hidT,
    const float* __restrict__ dw_qk,
    const float* __restrict__ gamma, const float* __restrict__ beta,
    bf16* __restrict__ quadq, bf16* __restrict__ quadk,
    bf16* __restrict__ linq, bf16* __restrict__ linkT,
    int rowsC, int nDual)
{
    __shared__ float s[80][64];
    __shared__ bf16 o[64][72];   // [ch][tok], row stride 144 B (16B-aligned)
    int tid = threadIdx.x;
    if ((int)blockIdx.x < nDual) {
        // ---- h path: hidT = h + dwconv(h), transposed write only ----
        int i = blockIdx.x;
        int c0 = (i & 31) * 64;            // HID/64 = 32
        int t0 = ((i >> 5) & 31) * 64;     // NN/64 = 32
        int b  = i >> 10;
        const bf16* base = hq + (size_t)b * NN * NHQ + c0;
        {
            int ch8 = (tid & 7) * 8, rw = tid >> 3;
            #pragma unroll
            for (int ps = 0; ps < 3; ps++) {
                int tt = rw + ps * 32;
                if (tt < 80) {
                    int t = t0 + tt - 8;
                    union { short8 v; bf16 h[8]; } u; u.v = short8{};
                    if (t >= 0 && t < NN)
                        u.v = *(const short8*)(base + (size_t)t * NHQ + ch8);
                    float* sp = &s[tt][ch8];
                    #pragma unroll
                    for (int k = 0; k < 8; k++) sp[k] = b2f(u.h[k]);
                }
            }
        }
        __syncthreads();
        int c = tid & 63, rp = tid >> 6;
        float w[KW];
        for (int k = 0; k < KW; k++) w[k] = dw_h[k * HID + c0 + c];
        for (int l = 0; l < 16; l++) {
            int r = rp + l * 4;
            float acc = s[r + 8][c];
            for (int k = 0; k < KW; k++) acc += s[r + k][c] * w[k];
            o[c][r] = f2b(acc);
        }
        __syncthreads();
        // write hidT (ch-major [ch][rowsC]) as short8
        {
            int t8 = (tid & 7) * 8, ch = tid >> 3;
            #pragma unroll
            for (int ps = 0; ps < 2; ps++) {
                int cc = ch + ps * 32;
                short8 v = *(const short8*)(&o[cc][t8]);
                *(short8*)(hidT + (size_t)(c0 + cc) * rowsC + b * NN + t0 + t8) = v;
            }
        }
    } else {
        // ---- qk path: conv + 4-way affine -> quadq/quadk/linq/linkT ----
        int i = blockIdx.x - nDual;
        int c0 = (i & 1) * 64;             // DQK/64 = 2
        int t0 = ((i >> 1) & 31) * 64;
        int b  = i >> 6;
        const bf16* base = hq + HID + (size_t)b * NN * NHQ + c0;
        {
            int ch8 = (tid & 7) * 8, rw = tid >> 3;
            #pragma unroll
            for (int ps = 0; ps < 3; ps++) {
                int tt = rw + ps * 32;
                if (tt < 80) {
                    int t = t0 + tt - 8;
                    union { short8 v; bf16 h[8]; } u; u.v = short8{};
                    if (t >= 0 && t < NN)
                        u.v = *(const short8*)(base + (size_t)t * NHQ + ch8);
                    float* sp = &s[tt][ch8];
                    #pragma unroll
                    for (int k = 0; k < 8; k++) sp[k] = b2f(u.h[k]);
                }
            }
        }
        __syncthreads();
        int c = tid & 63, rp = tid >> 6;
        float w[KW];
        for (int k = 0; k < KW; k++) w[k] = dw_qk[k * DQK + c0 + c];
        float ga0 = gamma[0 * DQK + c0 + c], be0 = beta[0 * DQK + c0 + c];
        float ga1 = gamma[1 * DQK + c0 + c], be1 = beta[1 * DQK + c0 + c];
        float ga2 = gamma[2 * DQK + c0 + c], be2 = beta[2 * DQK + c0 + c];
        float ga3 = gamma[3 * DQK + c0 + c], be3 = beta[3 * DQK + c0 + c];
        for (int l = 0; l < 16; l++) {
            int r = rp + l * 4;
            float acc = s[r + 8][c];
            for (int k = 0; k < KW; k++) acc += s[r + k][c] * w[k];
            size_t tok = (size_t)b * NN + t0 + r;
            quadq[tok * DQK + c0 + c] = f2b(acc * ga0 + be0);
            linq [tok * DQK + c0 + c] = f2b(acc * ga1 + be1);
            quadk[tok * DQK + c0 + c] = f2b(acc * ga2 + be2);
            o[c][r] = f2b(acc * ga3 + be3);
        }
        __syncthreads();
        // transposed write of linkT rows c0..c0+63
        int t8 = (tid & 7) * 8, ch = tid >> 3;
        #pragma unroll
        for (int ps = 0; ps < 2; ps++) {
            int cc = ch + ps * 32;
            short8 v = *(const short8*)(&o[cc][t8]);
            *(short8*)(linkT + (size_t)(c0 + cc) * rowsC + b * NN + t0 + t8) = v;
        }
    }
}

// ---------------- dwconv (generic, vectorized staging) -----------------------------------
template<typename TO>
__global__ __launch_bounds__(256) void dwconv_res(
    const bf16* __restrict__ src, const float* __restrict__ dw,
    const float* __restrict__ xres, TO* __restrict__ dst, int C, int ldS)
{
    int c0 = blockIdx.x * 64;
    int t0 = blockIdx.y * 64;
    int b  = blockIdx.z;
    __shared__ float s[80][64];
    int tid = threadIdx.x;
    int c = tid & 63;
    int rp = tid >> 6;
    const bf16* base = src + (size_t)b * NN * ldS + c0;
    {
        int ch8 = (tid & 7) * 8, rw = tid >> 3;
        #pragma unroll
        for (int ps = 0; ps < 3; ps++) {
            int tt = rw + ps * 32;
            if (tt < 80) {
                int t = t0 + tt - 8;
                union { short8 v; bf16 h[8]; } u; u.v = short8{};
                if (t >= 0 && t < NN)
                    u.v = *(const short8*)(base + (size_t)t * ldS + ch8);
                float* sp = &s[tt][ch8];
                #pragma unroll
                for (int k = 0; k < 8; k++) sp[k] = b2f(u.h[k]);
            }
        }
    }
    __syncthreads();
    float w[KW];
    for (int k = 0; k < KW; k++) w[k] = dw[k * C + c0 + c];
    for (int l = 0; l < 16; l++) {
        int r = rp + l * 4;
        float acc = s[r + 8][c];
        for (int k = 0; k < KW; k++) acc += s[r + k][c] * w[k];
        long gidx = ((long)b * NN + t0 + r) * C + c0 + c;
        if (xres) acc += xres[gidx];
        stv(dst, gidx, acc);
    }
}

extern "C" void kernel_launch(void* const* d_in, const int* in_sizes, int n_in,
                              void* d_out, int out_size, void* d_ws, size_t ws_size,
                              hipStream_t stream)
{
    const float* x      = (const float*)d_in[0];
    const float* ln_h_g = (const float*)d_in[1];
    const float* ln_h_b = (const float*)d_in[2];
    const float* W_h    = (const float*)d_in[3];
    const float* b_h    = (const float*)d_in[4];
    const float* dw_h   = (const float*)d_in[5];
    const float* ln_qk_g= (const float*)d_in[6];
    const float* ln_qk_b= (const float*)d_in[7];
    const float* W_qk   = (const float*)d_in[8];
    const float* b_qk   = (const float*)d_in[9];
    const float* dw_qk  = (const float*)d_in[10];
    const float* gamma  = (const float*)d_in[11];
    const float* beta   = (const float*)d_in[12];
    const float* ln_o_g = (const float*)d_in[13];
    const float* ln_o_b = (const float*)d_in[14];
    const float* W_o    = (const float*)d_in[15];
    const float* b_o    = (const float*)d_in[16];
    const float* dw_o   = (const float*)d_in[17];
    float* outp = (float*)d_out;

    // ---- fixed region (hat1 now aliased into the per-chunk hat2 slot, not here) ----
    char* p = (char*)d_ws;
    bf16* WT_hq = (bf16*)p;  p += (size_t)NHQ * DIM * 2;
    bf16* WT_o  = (bf16*)p;  p += (size_t)DIM * 1024 * 2;
    float* bias_hq = (float*)p; p += NHQ * 4;
    float* bias_o  = (float*)p; p += DIM * 4;
    p = (char*)(((uintptr_t)p + 255) & ~(uintptr_t)255);
    size_t fixed = (size_t)(p - (char*)d_ws);
    bf16* WT_h  = WT_hq;
    bf16* WT_qk = WT_hq + (size_t)HID * DIM;
    float* bias_h  = bias_hq;

    auto bytes_for = [fixed](int cb) -> size_t {
        size_t rows = (size_t)cb * NN;
        return fixed
             + rows * NHQ * 2           // s1 hq / linkvT / fin_pre
             + rows * 1024 * 2          // s2 hat1 -> hat2
             + rows * HID * 2           // s3 hidT
             + rows * 1024 * 2          // s4 outg
             + (size_t)cb * NG * GRP * GRP * 2   // s5 P
             + 4 * rows * DQK * 2       // s6 linkT + quadq/quadk/linq
             + rows * 1024 * 2          // s11 linkvb
             + 4096;
    };
    int CB = 1;
    if (bytes_for(8) <= ws_size) CB = 8;
    else if (bytes_for(4) <= ws_size) CB = 4;
    else if (bytes_for(2) <= ws_size) CB = 2;
    const int rowsC = CB * NN;
    const size_t rows = (size_t)rowsC;

    char* s1 = p;               p += rows * NHQ * 2;   // hq -> linkvT -> fin_pre
    char* s2 = p;               p += rows * 1024 * 2;  // hat1 (512-wide) -> hat2 (1024-wide)
    char* s3 = p;               p += rows * HID * 2;   // hidT
    char* s4 = p;               p += rows * 1024 * 2;  // outg
    char* s5 = p;               p += (size_t)CB * NG * GRP * GRP * 2;  // P
    char* s6 = p;               p += rows * DQK * 2;   // linkT
    char* s8 = p;               p += rows * DQK * 2;   // quadq
    char* s9 = p;               p += rows * DQK * 2;   // quadk
    char* s10 = p;              p += rows * DQK * 2;   // linq
    char* s11 = p;              p += rows * 1024 * 2;  // linkvb (bf16 cumsum out)

    bf16*  hq      = (bf16*)s1;
    float* linkvT  = (float*)s1;
    bf16*  fin_pre = (bf16*)s1;
    bf16*  hat1    = (bf16*)s2;   // dead after step 2; hat2 overwrites at step 10
    bf16*  hat2    = (bf16*)s2;
    bf16*  hidT    = (bf16*)s3;
    bf16*  outg    = (bf16*)s4;
    bf16*  P       = (bf16*)s5;
    bf16*  linkT   = (bf16*)s6;
    bf16*  quadq   = (bf16*)s8;
    bf16*  quadk   = (bf16*)s9;
    bf16*  linq    = (bf16*)s10;
    bf16*  linkvb  = (bf16*)s11;

    // ---- weight prep: 3 launches total ----
    prep_all<<<1600, 256, 0, stream>>>(W_h, ln_h_g, WT_h,
                                       W_qk, ln_qk_g, WT_qk,
                                       W_o, ln_o_g, WT_o);
    bias_init3<<<(NHQ + DIM + 255) / 256, 256, 0, stream>>>(b_h, b_qk, b_o, bias_hq, bias_o);
    bias_reduce3<<<104, 256, 0, stream>>>(W_h, ln_h_b, W_qk, ln_qk_b, W_o, ln_o_b,
                                          bias_hq, bias_o);

    const int G = CB * NG;   // groups per chunk
    for (int b0 = 0; b0 < BB; b0 += CB) {
        const float* xc = x    + (size_t)b0 * NN * DIM;
        float* outc     = outp + (size_t)b0 * NN * DIM;
        int R = rowsC;

        // 1) LN of token-shifted x -> hat1 (s2)
        ln_kernel_f<DIM, 1><<<R, 256, 0, stream>>>(xc, hat1);
        // 2a) h-part (N=2048) on the 256x256 kernel — grid multiple of 256 (1 blk/CU waves)
        gemm256<<<dim3((R / 256) * (HID / 256)), 512, 0, stream>>>(
            hat1, WT_h, bias_h, hq, HID, DIM, NHQ);
        // 2b) qk-part (N=128) on the pipelined 128x128 kernel
        gemm_pipe<<<dim3(R / 128), 256, 0, stream>>>(
            hat1, WT_qk, bias_hq + HID, hq + HID, R, 128, DIM, NHQ);
        // 3+4+5) merged dwconv: h transposed-write + qk conv+affine
        {
            int nDual = (HID / 64) * (NN / 64) * CB;
            int nQk   = (DQK / 64) * (NN / 64) * CB;
            dwconv_both<<<nDual + nQk, 256, 0, stream>>>(
                hq, dw_h, hidT, dw_qk, gamma, beta,
                quadq, quadk, linq, linkT, rowsC, nDual);
        }
        // 6+7) merged scores + linkv (both depend only on dwconv outputs)
        score_linkv<<<4 * G + 16 * G, 256, 0, stream>>>(
            quadq, quadk, P, hidT, linkT, linkvT, rowsC, 4 * G);
        // 8) exclusive cumsum over groups -> linkvb bf16
        cumsum_bf<<<(CB * DQK * HID) / (256 * 4), 256, 0, stream>>>(linkvT, linkvb);
        // 9) fused apply + gating -> outg (v,u from hidT), XCD-affine per group
        attn_apply_mfma<<<dim3(16 * G), 256, 0, stream>>>(P, hidT, linq, linkvb, outg, rowsC);
        // 10) LN(outg) -> hat2 (overwrites hat1, which is dead)
        ln_kernel_bf<1024><<<R, 256, 0, stream>>>(outg, hat2);
        // 11) fin_pre = silu(hat2 @ W_o' + bias_o')
        gemm_pipe<<<dim3((DIM / 128) * (R / 128)), 256, 0, stream>>>(
            hat2, WT_o, bias_o, fin_pre, R, DIM, 1024, DIM);
        // 12) d_out(fp32) = x + fin_pre + dwconv(fin_pre)
        dwconv_res<float><<<dim3(DIM / 64, NN / 64, CB), 256, 0, stream>>>(
            fin_pre, dw_o, xc, outc, DIM, DIM);
    }
}

// Round 10
// 390.160 us; speedup vs baseline: 1.1805x; 1.0088x over previous
//
#include <hip/hip_runtime.h>
#include <hip/hip_bf16.h>

typedef __hip_bfloat16 bf16;
typedef __attribute__((ext_vector_type(8))) short short8;
typedef __attribute__((ext_vector_type(4))) short short4v;
typedef __attribute__((ext_vector_type(2))) short short2v;
typedef __attribute__((ext_vector_type(4))) float float4v;
typedef __attribute__((ext_vector_type(2))) float float2v;
__device__ __forceinline__ float b2f(bf16 v){ return __bfloat162float(v); }
__device__ __forceinline__ bf16 f2b(float v){ return __float2bfloat16(v); }
__device__ __forceinline__ void stv(float* p, long i, float v){ p[i] = v; }
__device__ __forceinline__ void stv(bf16*  p, long i, float v){ p[i] = f2b(v); }

#define MFMA __builtin_amdgcn_mfma_f32_16x16x32_bf16
#define AS1(p) ((const __attribute__((address_space(1))) void*)(p))
#define AS3(p) ((__attribute__((address_space(3))) void*)(p))

// Problem constants
#define BB   8
#define NN   2048
#define DIM  512
#define HID  2048
#define DQK  128
#define GRP  256
#define NG   8
#define KW   17
#define BK   32
#define NHQ  2176   // merged N for h(2048) + qk(128) buffers (stride)

// ---------------- LayerNorm: fp32 input, token-shift, float2-vectorized ------------------
template<int D, int SHIFT_HALF>
__global__ __launch_bounds__(256) void ln_kernel_f(const float* __restrict__ in,
                                                   bf16* __restrict__ out)
{
    int row = blockIdx.x;
    int t = row % NN;
    int tid = threadIdx.x;
    int c0 = tid * 2;                      // D = 512, 2 floats/thread
    float2v v2 = {0.f, 0.f};
    if (SHIFT_HALF && c0 < D / 2) {
        if (t > 0) v2 = *(const float2v*)(in + ((long)row - 1) * D + c0);
    } else {
        v2 = *(const float2v*)(in + (long)row * D + c0);
    }
    float s = v2[0] + v2[1];
    float ss = v2[0] * v2[0] + v2[1] * v2[1];
    for (int o = 32; o > 0; o >>= 1) { s += __shfl_down(s, o); ss += __shfl_down(ss, o); }
    __shared__ float sm[4], sm2[4];
    int wid = tid >> 6, lane = tid & 63;
    if (lane == 0) { sm[wid] = s; sm2[wid] = ss; }
    __syncthreads();
    if (tid == 0) {
        float a = 0.f, q = 0.f;
        for (int w = 0; w < 4; w++) { a += sm[w]; q += sm2[w]; }
        sm[0] = a; sm2[0] = q;
    }
    __syncthreads();
    float mean = sm[0] / D;
    float var  = fmaxf(sm2[0] / D - mean * mean, 0.f);
    float rs = rsqrtf(var + 1e-5f);
    union { short2v v; bf16 h[2]; } o2;
    o2.h[0] = f2b((v2[0] - mean) * rs);
    o2.h[1] = f2b((v2[1] - mean) * rs);
    *(short2v*)(out + (long)row * D + c0) = o2.v;
}

// vectorized bf16 LN: D=1024, each thread owns 4 contiguous cols (8B loads/stores)
template<int D>
__global__ __launch_bounds__(256) void ln_kernel_bf(const bf16* __restrict__ in,
                                                    bf16* __restrict__ out)
{
    int row = blockIdx.x;
    int tid = threadIdx.x;
    int c0 = tid * 4;
    union { short4v v; bf16 h[4]; } u;
    u.v = *(const short4v*)(in + (long)row * D + c0);
    float vals[4];
    float s = 0.f, ss = 0.f;
    #pragma unroll
    for (int i = 0; i < 4; i++) {
        float v = b2f(u.h[i]);
        vals[i] = v; s += v; ss += v * v;
    }
    for (int o = 32; o > 0; o >>= 1) { s += __shfl_down(s, o); ss += __shfl_down(ss, o); }
    __shared__ float sm[4], sm2[4];
    int wid = tid >> 6, lane = tid & 63;
    if (lane == 0) { sm[wid] = s; sm2[wid] = ss; }
    __syncthreads();
    if (tid == 0) {
        float a = 0.f, q = 0.f;
        for (int w = 0; w < 4; w++) { a += sm[w]; q += sm2[w]; }
        sm[0] = a; sm2[0] = q;
    }
    __syncthreads();
    float mean = sm[0] / D;
    float var  = fmaxf(sm2[0] / D - mean * mean, 0.f);
    float rs = rsqrtf(var + 1e-5f);
    union { short4v v; bf16 h[4]; } o4;
    #pragma unroll
    for (int i = 0; i < 4; i++) o4.h[i] = f2b((vals[i] - mean) * rs);
    *(short4v*)(out + (long)row * D + c0) = o4.v;
}

// ---------------- merged weight prep: all 3 WT in one launch -----------------------------
__global__ __launch_bounds__(256) void prep_all(
    const float* __restrict__ W_h,  const float* __restrict__ g_h,  bf16* __restrict__ WT_h,
    const float* __restrict__ W_qk, const float* __restrict__ g_qk, bf16* __restrict__ WT_qk,
    const float* __restrict__ W_o,  const float* __restrict__ g_o,  bf16* __restrict__ WT_o)
{
    int i = blockIdx.x;
    const float *W, *g; bf16* WT; int K, N, k0, n0;
    if (i < 1024) {                 // W_h: K=512 (16 kb), N=2048 (64 nb)
        W = W_h; g = g_h; WT = WT_h; K = DIM; N = HID;
        k0 = (i & 15) * 32; n0 = (i >> 4) * 32;
    } else if (i < 1088) {          // W_qk: K=512 (16 kb), N=128 (4 nb)
        int j = i - 1024;
        W = W_qk; g = g_qk; WT = WT_qk; K = DIM; N = DQK;
        k0 = (j & 15) * 32; n0 = (j >> 4) * 32;
    } else {                        // W_o: K=1024 (32 kb), N=512 (16 nb)
        int j = i - 1088;
        W = W_o; g = g_o; WT = WT_o; K = 1024; N = DIM;
        k0 = (j & 31) * 32; n0 = (j >> 5) * 32;
    }
    __shared__ float Ws[32][33];
    int tid = threadIdx.x;
    for (int l = 0; l < 4; l++) {
        int e = tid + 256 * l;
        int kk = e >> 5, nn = e & 31;
        Ws[kk][nn] = g[k0 + kk] * W[(size_t)(k0 + kk) * N + n0 + nn];
    }
    __syncthreads();
    for (int l = 0; l < 4; l++) {
        int e = tid + 256 * l;
        int nn = e >> 5, kk = e & 31;
        WT[(size_t)(n0 + nn) * K + k0 + kk] = f2b(Ws[kk][nn]);
    }
}

// ---------------- merged bias init --------------------------------------------------------
__global__ __launch_bounds__(256) void bias_init3(
    const float* __restrict__ b_h, const float* __restrict__ b_qk,
    const float* __restrict__ b_o, float* __restrict__ bias_hq,
    float* __restrict__ bias_o)
{
    int n = blockIdx.x * 256 + threadIdx.x;
    if (n < HID)                 bias_hq[n] = b_h[n];
    else if (n < NHQ)            bias_hq[n] = b_qk[n - HID];
    else if (n < NHQ + DIM)      bias_o[n - NHQ] = b_o[n - NHQ];
}

// ---------------- merged bias reduce (parallel over K, atomics — r5-proven) --------------
#define BKC 64
__global__ __launch_bounds__(256) void bias_reduce3(
    const float* __restrict__ W_h,  const float* __restrict__ lnb_h,
    const float* __restrict__ W_qk, const float* __restrict__ lnb_qk,
    const float* __restrict__ W_o,  const float* __restrict__ lnb_o,
    float* __restrict__ bias_hq, float* __restrict__ bias_o)
{
    int i = blockIdx.x;
    const float *W, *lnb; float* out; int N, n, k0;
    if (i < 64) {                   // W_h: N=2048 (8 nb), K=512 (8 kb)
        W = W_h; lnb = lnb_h; out = bias_hq; N = HID;
        n = (i & 7) * 256 + threadIdx.x; k0 = (i >> 3) * BKC;
    } else if (i < 72) {            // W_qk: N=128 (1 nb), K=512 (8 kb)
        int j = i - 64;
        W = W_qk; lnb = lnb_qk; out = bias_hq + HID; N = DQK;
        n = threadIdx.x; k0 = j * BKC;
    } else {                        // W_o: N=512 (2 nb), K=1024 (16 kb)
        int j = i - 72;
        W = W_o; lnb = lnb_o; out = bias_o; N = DIM;
        n = (j & 1) * 256 + threadIdx.x; k0 = (j >> 1) * BKC;
    }
    if (n >= N) return;
    float s = 0.f;
    #pragma unroll 8
    for (int k = k0; k < k0 + BKC; k++) s += lnb[k] * W[(size_t)k * N + n];
    atomicAdd(&out[n], s);
}

// ---------------- staging helper: 128 rows x 32 cols bf16 tile via global_load_lds -------
__device__ __forceinline__ void stage_tile(const bf16* base, size_t ld, bf16* dst,
                                           int wave, int lane)
{
    int lrow = lane >> 2, lcol = lane & 3;
    for (int cc = 0; cc < 2; cc++) {
        int c = wave * 2 + cc;
        int row = c * 16 + lrow;
        const bf16* g = base + (size_t)row * ld + lcol * 8;
        __builtin_amdgcn_global_load_lds(AS1(g), AS3(dst + c * 512), 16, 0, 0);
    }
}

// ============ shared 3-slot pipelined 128x128 GEMM core (T3/T4/T5, proven in r2) =========
#define PIPE_SLOT 8192   // As(128x32) + Bs(128x32) bf16 = 16 KiB

__device__ __forceinline__ void pipe_core(
    const bf16* __restrict__ Abase, size_t ldA,
    const bf16* __restrict__ Bbase, size_t ldB,
    int nit, bf16* lds, int wave, int lane, float4v acc[4][4])
{
    auto stage = [&](int it, int slot) {
        bf16* As = lds + slot * PIPE_SLOT;
        stage_tile(Abase + (size_t)it * 32, ldA, As, wave, lane);
        stage_tile(Bbase + (size_t)it * 32, ldB, As + 4096, wave, lane);
    };
    stage(0, 0);
    stage(1, 1);
    asm volatile("s_waitcnt vmcnt(4)" ::: "memory");
    __builtin_amdgcn_s_barrier();
    __builtin_amdgcn_sched_barrier(0);

    int wm = wave & 1, wn = wave >> 1;
    int col = lane & 15, quad = lane >> 4;
    int slot = 0;
    for (int it = 0; it < nit; it++) {
        const bf16* As = lds + slot * PIPE_SLOT;
        const bf16* Bs = As + 4096;
        short8 a[4], b[4];
        #pragma unroll
        for (int t = 0; t < 4; t++) {
            a[t] = *(const short8*)(As + (wm * 64 + t * 16 + col) * 32 + quad * 8);
            b[t] = *(const short8*)(Bs + (wn * 64 + t * 16 + col) * 32 + quad * 8);
        }
        int nslot = slot + 1; if (nslot == 3) nslot = 0;
        int pslot = nslot + 1; if (pslot == 3) pslot = 0;   // (slot+2)%3
        if (it + 2 < nit) stage(it + 2, pslot);
        asm volatile("s_waitcnt lgkmcnt(0)" ::: "memory");
        __builtin_amdgcn_sched_barrier(0);
        __builtin_amdgcn_s_setprio(1);
        #pragma unroll
        for (int i = 0; i < 4; i++)
            #pragma unroll
            for (int j = 0; j < 4; j++)
                acc[i][j] = MFMA(a[i], b[j], acc[i][j], 0, 0, 0);
        __builtin_amdgcn_s_setprio(0);
        __builtin_amdgcn_sched_barrier(0);
        if (it + 2 < nit) { asm volatile("s_waitcnt vmcnt(4)" ::: "memory"); }
        else              { asm volatile("s_waitcnt vmcnt(0)" ::: "memory"); }
        __builtin_amdgcn_s_barrier();
        __builtin_amdgcn_sched_barrier(0);
        slot = nslot;
    }
}

// ---------------- pipelined MFMA GEMM: C = silu(A@B^T + bias); XCD-affine m-blocks -------
__global__ __launch_bounds__(256) void gemm_pipe(
    const bf16* __restrict__ A, const bf16* __restrict__ BT,
    const float* __restrict__ bias, bf16* __restrict__ C,
    int M, int N, int K, int ldC)
{
    __shared__ __align__(16) bf16 lds[3 * PIPE_SLOT];
    int nb = N >> 7;
    int i = blockIdx.x;
    int xcd = i & 7, r = i >> 3;
    int m0 = (xcd + 8 * (r / nb)) << 7;   // same-A-panel blocks share an XCD
    int n0 = (r % nb) << 7;
    int tid = threadIdx.x, wave = tid >> 6, lane = tid & 63;
    float4v acc[4][4] = {};
    pipe_core(A + (size_t)m0 * K, K, BT + (size_t)n0 * K, K, K / 32,
              lds, wave, lane, acc);
    int wm = wave & 1, wn = wave >> 1;
    int col = lane & 15, quad = lane >> 4;
    for (int i2 = 0; i2 < 4; i2++) {
        for (int j = 0; j < 4; j++) {
            int n = n0 + wn * 64 + j * 16 + col;
            float bs = bias[n];
            for (int r2 = 0; r2 < 4; r2++) {
                int m = m0 + wm * 64 + i2 * 16 + quad * 4 + r2;
                float v = acc[i2][j][r2] + bs;
                v = v / (1.f + __expf(-v));
                C[(size_t)m * ldC + n] = f2b(v);
            }
        }
    }
}

// ============== 256x256 8-wave BK=64 2-phase GEMM (T3-minimum + T1/T2/T5) ===============
__device__ __forceinline__ void stage_half256(const bf16* __restrict__ g0, int ld,
                                              bf16* dst, int tid)
{
    int wb = tid & ~63;   // wave*64
    #pragma unroll
    for (int l = 0; l < 2; l++) {
        int idx = l * 512 + tid;
        int row = idx >> 3;
        int c8  = (idx & 7) ^ (row & 7);
        const bf16* g = g0 + (size_t)row * ld + c8 * 8;
        __builtin_amdgcn_global_load_lds(AS1(g), AS3(dst + (size_t)(l * 512 + wb) * 8), 16, 0, 0);
    }
}

__device__ __forceinline__ short8 ldsfrag(const bf16* h, int row, int g)
{
    return *(const short8*)(h + row * 64 + ((g ^ (row & 7)) << 3));
}

__global__ __launch_bounds__(512, 2) void gemm256(
    const bf16* __restrict__ A, const bf16* __restrict__ BT,
    const float* __restrict__ bias, bf16* __restrict__ C,
    int N, int K, int ldC)
{
    __shared__ __align__(16) bf16 As[2][2][128][64];
    __shared__ __align__(16) bf16 Bs[2][2][128][64];
    int nbx = N >> 8;
    int nwg = gridDim.x;
    int cpx = nwg >> 3;               // grid is always a multiple of 8 -> bijective
    int bid = blockIdx.x;
    int swz = (bid & 7) * cpx + (bid >> 3);
    int bx = swz % nbx, by = swz / nbx;
    int m0 = by << 8, n0 = bx << 8;
    int tid = threadIdx.x, wave = tid >> 6, lane = tid & 63;
    int wm = wave >> 2, wn = wave & 3;      // 2 (M) x 4 (N) waves
    int col = lane & 15, quad = lane >> 4;
    int nkt = K >> 6;
    float4v acc[8][4] = {};

    const bf16* Ag = A  + (size_t)m0 * K;
    const bf16* Bg = BT + (size_t)n0 * K;

    // prologue: stage K-tile 0 fully into buf0
    #pragma unroll
    for (int h = 0; h < 2; h++) {
        stage_half256(Ag + (size_t)h * 128 * K, K, &As[0][h][0][0], tid);
        stage_half256(Bg + (size_t)h * 128 * K, K, &Bs[0][h][0][0], tid);
    }
    asm volatile("s_waitcnt vmcnt(0)" ::: "memory");
    __builtin_amdgcn_s_barrier();

    // canonical 2-phase K-loop: stage(kt+1) issued FIRST (in flight under ds_read+MFMA),
    // all 24 unique frags read once, one 64-MFMA run, single vmcnt(0)+barrier per tile.
    for (int kt = 0; kt < nkt; kt++) {
        int buf = kt & 1;
        const bf16* Ah = &As[buf][wm][0][0];
        const bf16* Bh = &Bs[buf][wn >> 1][0][0];
        int brb = (wn & 1) * 64;
        bool pf = (kt + 1 < nkt);

        if (pf) {
            #pragma unroll
            for (int h = 0; h < 2; h++) {
                stage_half256(Ag + (size_t)h * 128 * K + (kt + 1) * 64, K,
                              &As[buf ^ 1][h][0][0], tid);
                stage_half256(Bg + (size_t)h * 128 * K + (kt + 1) * 64, K,
                              &Bs[buf ^ 1][h][0][0], tid);
            }
        }
        short8 ar[2][8], br[2][4];
        #pragma unroll
        for (int f = 0; f < 8; f++)
            #pragma unroll
            for (int ks = 0; ks < 2; ks++)
                ar[ks][f] = ldsfrag(Ah, f * 16 + col, ks * 4 + quad);
        #pragma unroll
        for (int j = 0; j < 4; j++)
            #pragma unroll
            for (int ks = 0; ks < 2; ks++)
                br[ks][j] = ldsfrag(Bh, brb + j * 16 + col, ks * 4 + quad);
        asm volatile("s_waitcnt lgkmcnt(0)" ::: "memory");
        __builtin_amdgcn_sched_barrier(0);
        __builtin_amdgcn_s_setprio(1);
        #pragma unroll
        for (int f = 0; f < 8; f++)
            #pragma unroll
            for (int j = 0; j < 4; j++) {
                acc[f][j] = MFMA(ar[0][f], br[0][j], acc[f][j], 0, 0, 0);
                acc[f][j] = MFMA(ar[1][f], br[1][j], acc[f][j], 0, 0, 0);
            }
        __builtin_amdgcn_s_setprio(0);
        __builtin_amdgcn_sched_barrier(0);
        asm volatile("s_waitcnt vmcnt(0)" ::: "memory");
        __builtin_amdgcn_s_barrier();
        __builtin_amdgcn_sched_barrier(0);
    }

    // epilogue: bias + silu + store
    #pragma unroll
    for (int i = 0; i < 8; i++) {
        #pragma unroll
        for (int j = 0; j < 4; j++) {
            int n = n0 + wn * 64 + j * 16 + col;
            float bs = bias[n];
            #pragma unroll
            for (int r = 0; r < 4; r++) {
                int m = m0 + wm * 128 + i * 16 + quad * 4 + r;
                float v = acc[i][j][r] + bs;
                v = v / (1.f + __expf(-v));
                C[(size_t)m * ldC + n] = f2b(v);
            }
        }
    }
}

// ======== merged attn_score + linkv (one launch; both pipe_core; XCD-affine) =============
__global__ __launch_bounds__(256) void score_linkv(
    const bf16* __restrict__ quadq, const bf16* __restrict__ quadk,
    bf16* __restrict__ P,
    const bf16* __restrict__ hidT, const bf16* __restrict__ linkT,
    float* __restrict__ linkvT, int rowsC, int nScore)
{
    __shared__ __align__(16) bf16 lds[3 * PIPE_SLOT];
    int tid = threadIdx.x, wave = tid >> 6, lane = tid & 63;
    if ((int)blockIdx.x < nScore) {
        // ---- attn scores: P = relu(QK^T/256)^2, causal ----
        int i = blockIdx.x;
        int xcd = i & 7, r = i >> 3;
        int g = xcd + 8 * (r >> 2);
        int t = r & 3, bi = t >> 1, bj = t & 1;
        bf16* Pg = P + (size_t)g * GRP * GRP;
        if (bj > bi) {   // fully masked tile: write zeros
            short8 z = {};
            int rr = tid >> 1, half = tid & 1;
            short* dst = (short*)Pg + (size_t)(bi * 128 + rr) * GRP + bj * 128 + half * 64;
            for (int q = 0; q < 8; q++) ((short8*)dst)[q] = z;
            return;
        }
        float4v acc[4][4] = {};
        const bf16* Ab = quadq + (size_t)(g * GRP + bi * 128) * DQK;
        const bf16* Bb = quadk + (size_t)(g * GRP + bj * 128) * DQK;
        pipe_core(Ab, DQK, Bb, DQK, DQK / 32, lds, wave, lane, acc);
        int wm = wave & 1, wn = wave >> 1;
        int col = lane & 15, quad = lane >> 4;
        for (int i2 = 0; i2 < 4; i2++) {
            for (int j = 0; j < 4; j++) {
                int jj = bj * 128 + wn * 64 + j * 16 + col;
                for (int r2 = 0; r2 < 4; r2++) {
                    int ii = bi * 128 + wm * 64 + i2 * 16 + quad * 4 + r2;
                    float s = acc[i2][j][r2] * (1.f / GRP);
                    s = fmaxf(s, 0.f); s = s * s;
                    if (jj > ii) s = 0.f;
                    Pg[(size_t)ii * GRP + jj] = f2b(s);
                }
            }
        }
    } else {
        // ---- linkv: linkvT[g][e][d] = (hidT_g @ linkT_g^T)/256 ----
        int i = blockIdx.x - nScore;       // nScore % 8 == 0 -> XCD parity preserved
        int xcd = i & 7, r = i >> 3;
        int g = xcd + 8 * (r >> 4);
        int eb = r & 15;
        int e0 = eb * 128;
        float4v acc[4][4] = {};
        pipe_core(hidT + (size_t)e0 * rowsC + g * GRP, rowsC,
                  linkT + g * GRP, rowsC, GRP / 32, lds, wave, lane, acc);
        float* out = linkvT + (size_t)g * (HID * DQK);
        int wm = wave & 1, wn = wave >> 1;
        int col = lane & 15, quad = lane >> 4;
        for (int i2 = 0; i2 < 4; i2++) {
            for (int j = 0; j < 4; j++) {
                int d = wn * 64 + j * 16 + col;
                for (int r2 = 0; r2 < 4; r2++) {
                    int e = e0 + wm * 64 + i2 * 16 + quad * 4 + r2;
                    out[(size_t)e * DQK + d] = acc[i2][j][r2] * (1.f / GRP);
                }
            }
        }
    }
}

// ---------------- exclusive cumsum over group axis, fp32 in -> bf16 out (x4 vec) ---------
__global__ void cumsum_bf(const float* __restrict__ in, bf16* __restrict__ out)
{
    long idx4 = (long)blockIdx.x * blockDim.x + threadIdx.x;   // 4 elems per thread
    int b = (int)(idx4 / (DQK * HID / 4));
    long off = (idx4 % (DQK * HID / 4)) * 4;
    const float* pi = in + (long)b * NG * DQK * HID + off;
    bf16* po = out + (long)b * NG * DQK * HID + off;
    float4v run = {0.f, 0.f, 0.f, 0.f};
    for (int gi = 0; gi < NG; gi++) {
        short4v o4;
        union { short s; bf16 h; } cv;
        #pragma unroll
        for (int k = 0; k < 4; k++) { cv.h = f2b(run[k]); o4[k] = cv.s; }
        *(short4v*)(po + (long)gi * DQK * HID) = o4;
        run += *(const float4v*)(pi + (long)gi * DQK * HID);
    }
}

// ---------------- fused attn apply MFMA + gating — 3-slot pipelined, XCD-affine ----------
// gating reads hidT (ch-major) via short4 over the 4 consecutive tokens of each quad
#define AP_SLOT (256 * BK + 128 * BK)   // 12288 bf16 = 24 KiB per slot

__global__ __launch_bounds__(256) void attn_apply_mfma(
    const bf16* __restrict__ P, const bf16* __restrict__ hidT,
    const bf16* __restrict__ linq, const bf16* __restrict__ linkvb,
    bf16* __restrict__ outg, int rowsC)
{
    int ib = blockIdx.x;
    int xcd = ib & 7, rb = ib >> 3;
    int g = xcd + 8 * (rb >> 4);          // all 16 e-blocks of a group share an XCD
    int e0 = (rb & 15) * 64;
    __shared__ __align__(16) bf16 lds[3 * AP_SLOT];
    int tid = threadIdx.x, wave = tid >> 6, lane = tid & 63;
    int lrow = lane >> 2, lcol = lane & 3;
    const bf16* Pg = P + (size_t)g * GRP * GRP;
    const bf16* Lg = linkvb + (size_t)g * (HID * DQK);

    // stage iteration 'it' (0..7: quad j0=it*32; 8..11: lin d0=(it-8)*32) into 'slot'
    auto stage = [&](int it, int slot) {
        bf16* As = lds + slot * AP_SLOT;
        bf16* Bs = As + 256 * BK;
        if (it < 8) {
            int j0 = it * 32;
            for (int cc = 0; cc < 4; cc++) {
                int c = wave * 4 + cc;
                int row = c * 16 + lrow;
                const bf16* ga = Pg + (size_t)row * GRP + j0 + lcol * 8;
                __builtin_amdgcn_global_load_lds(AS1(ga), AS3(As + c * 512), 16, 0, 0);
            }
            for (int cc = 0; cc < 2; cc++) {
                int c = wave * 2 + cc;
                int row = c * 16 + lrow;
                int er = (row < 64) ? (e0 + row) : (1024 + e0 + (row - 64));
                const bf16* gb = hidT + (size_t)er * rowsC + g * GRP + j0 + lcol * 8;
                __builtin_amdgcn_global_load_lds(AS1(gb), AS3(Bs + c * 512), 16, 0, 0);
            }
        } else {
            int d0 = (it - 8) * 32;
            for (int cc = 0; cc < 4; cc++) {
                int c = wave * 4 + cc;
                int row = c * 16 + lrow;
                const bf16* ga = linq + (size_t)(g * GRP + row) * DQK + d0 + lcol * 8;
                __builtin_amdgcn_global_load_lds(AS1(ga), AS3(As + c * 512), 16, 0, 0);
            }
            for (int cc = 0; cc < 2; cc++) {
                int c = wave * 2 + cc;
                int row = c * 16 + lrow;
                int er = (row < 64) ? (e0 + row) : (1024 + e0 + (row - 64));
                const bf16* gb = Lg + (size_t)er * DQK + d0 + lcol * 8;
                __builtin_amdgcn_global_load_lds(AS1(gb), AS3(Bs + c * 512), 16, 0, 0);
            }
        }
    };

    // prologue: slots 0 and 1 in flight; wait for slot 0 (6 loads of slot1 may remain)
    stage(0, 0);
    stage(1, 1);
    asm volatile("s_waitcnt vmcnt(6)" ::: "memory");
    __builtin_amdgcn_s_barrier();
    __builtin_amdgcn_sched_barrier(0);

    float4v acc[4][8] = {};
    int col = lane & 15, quad = lane >> 4;
    int slot = 0;
    for (int it = 0; it < 12; it++) {
        const bf16* As = lds + slot * AP_SLOT;
        const bf16* Bs = As + 256 * BK;
        short8 a[4], b[8];
        #pragma unroll
        for (int t = 0; t < 4; t++)
            a[t] = *(const short8*)(As + (wave * 64 + t * 16 + col) * BK + quad * 8);
        #pragma unroll
        for (int t = 0; t < 8; t++)
            b[t] = *(const short8*)(Bs + (t * 16 + col) * BK + quad * 8);
        int nslot = slot + 1; if (nslot == 3) nslot = 0;
        int pslot = nslot + 1; if (pslot == 3) pslot = 0;   // (slot+2)%3
        if (it + 2 < 12) stage(it + 2, pslot);
        asm volatile("s_waitcnt lgkmcnt(0)" ::: "memory");
        __builtin_amdgcn_sched_barrier(0);
        __builtin_amdgcn_s_setprio(1);
        #pragma unroll
        for (int i = 0; i < 4; i++)
            #pragma unroll
            for (int j = 0; j < 8; j++)
                acc[i][j] = MFMA(a[i], b[j], acc[i][j], 0, 0, 0);
        __builtin_amdgcn_s_setprio(0);
        __builtin_amdgcn_sched_barrier(0);
        if (it + 2 < 12) { asm volatile("s_waitcnt vmcnt(6)" ::: "memory"); }
        else             { asm volatile("s_waitcnt vmcnt(0)" ::: "memory"); }
        __builtin_amdgcn_s_barrier();
        __builtin_amdgcn_sched_barrier(0);
        slot = nslot;
    }

    // epilogue with gating: v,u loaded as short4 over the 4 consecutive tokens (r dim)
    for (int mt = 0; mt < 4; mt++) {
        int tokg0 = g * GRP + wave * 64 + mt * 16 + quad * 4;
        for (int nt = 0; nt < 4; nt++) {
            int e = e0 + nt * 16 + col;
            union { short4v v; bf16 h[4]; } v4, u4;
            v4.v = *(const short4v*)(hidT + (size_t)e * rowsC + tokg0);
            u4.v = *(const short4v*)(hidT + (size_t)(1024 + e) * rowsC + tokg0);
            #pragma unroll
            for (int r = 0; r < 4; r++) {
                float av = acc[mt][nt][r];
                float au = acc[mt][nt + 4][r];
                float v = b2f(v4.h[r]);
                float u = b2f(u4.h[r]);
                float gate = 1.f / (1.f + __expf(-av * u));
                outg[(size_t)(tokg0 + r) * 1024 + e] = f2b(au * v * gate);
            }
        }
    }
}

// ======== merged dwconv: h-path (hidT only) + qk-path (affine split), one launch =========
__global__ __launch_bounds__(256) void dwconv_both(
    const bf16* __restrict__ hq, const float* __restrict__ dw_h,
    bf16* __restrict__ hidT,
    const float* __restrict__ dw_qk,
    const float* __restrict__ gamma, const float* __restrict__ beta,
    bf16* __restrict__ quadq, bf16* __restrict__ quadk,
    bf16* __restrict__ linq, bf16* __restrict__ linkT,
    int rowsC, int nDual)
{
    __shared__ float s[80][64];
    __shared__ bf16 o[64][72];   // [ch][tok], row stride 144 B (16B-aligned)
    int tid = threadIdx.x;
    if ((int)blockIdx.x < nDual) {
        // ---- h path: hidT = h + dwconv(h), transposed write only ----
        int i = blockIdx.x;
        int c0 = (i & 31) * 64;            // HID/64 = 32
        int t0 = ((i >> 5) & 31) * 64;     // NN/64 = 32
        int b  = i >> 10;
        const bf16* base = hq + (size_t)b * NN * NHQ + c0;
        {
            int ch8 = (tid & 7) * 8, rw = tid >> 3;
            #pragma unroll
            for (int ps = 0; ps < 3; ps++) {
                int tt = rw + ps * 32;
                if (tt < 80) {
                    int t = t0 + tt - 8;
                    union { short8 v; bf16 h[8]; } u; u.v = short8{};
                    if (t >= 0 && t < NN)
                        u.v = *(const short8*)(base + (size_t)t * NHQ + ch8);
                    float* sp = &s[tt][ch8];
                    #pragma unroll
                    for (int k = 0; k < 8; k++) sp[k] = b2f(u.h[k]);
                }
            }
        }
        __syncthreads();
        int c = tid & 63, rp = tid >> 6;
        float w[KW];
        for (int k = 0; k < KW; k++) w[k] = dw_h[k * HID + c0 + c];
        for (int l = 0; l < 16; l++) {
            int r = rp + l * 4;
            float acc = s[r + 8][c];
            for (int k = 0; k < KW; k++) acc += s[r + k][c] * w[k];
            o[c][r] = f2b(acc);
        }
        __syncthreads();
        // write hidT (ch-major [ch][rowsC]) as short8
        {
            int t8 = (tid & 7) * 8, ch = tid >> 3;
            #pragma unroll
            for (int ps = 0; ps < 2; ps++) {
                int cc = ch + ps * 32;
                short8 v = *(const short8*)(&o[cc][t8]);
                *(short8*)(hidT + (size_t)(c0 + cc) * rowsC + b * NN + t0 + t8) = v;
            }
        }
    } else {
        // ---- qk path: conv + 4-way affine -> quadq/quadk/linq/linkT ----
        int i = blockIdx.x - nDual;
        int c0 = (i & 1) * 64;             // DQK/64 = 2
        int t0 = ((i >> 1) & 31) * 64;
        int b  = i >> 6;
        const bf16* base = hq + HID + (size_t)b * NN * NHQ + c0;
        {
            int ch8 = (tid & 7) * 8, rw = tid >> 3;
            #pragma unroll
            for (int ps = 0; ps < 3; ps++) {
                int tt = rw + ps * 32;
                if (tt < 80) {
                    int t = t0 + tt - 8;
                    union { short8 v; bf16 h[8]; } u; u.v = short8{};
                    if (t >= 0 && t < NN)
                        u.v = *(const short8*)(base + (size_t)t * NHQ + ch8);
                    float* sp = &s[tt][ch8];
                    #pragma unroll
                    for (int k = 0; k < 8; k++) sp[k] = b2f(u.h[k]);
                }
            }
        }
        __syncthreads();
        int c = tid & 63, rp = tid >> 6;
        float w[KW];
        for (int k = 0; k < KW; k++) w[k] = dw_qk[k * DQK + c0 + c];
        float ga0 = gamma[0 * DQK + c0 + c], be0 = beta[0 * DQK + c0 + c];
        float ga1 = gamma[1 * DQK + c0 + c], be1 = beta[1 * DQK + c0 + c];
        float ga2 = gamma[2 * DQK + c0 + c], be2 = beta[2 * DQK + c0 + c];
        float ga3 = gamma[3 * DQK + c0 + c], be3 = beta[3 * DQK + c0 + c];
        for (int l = 0; l < 16; l++) {
            int r = rp + l * 4;
            float acc = s[r + 8][c];
            for (int k = 0; k < KW; k++) acc += s[r + k][c] * w[k];
            size_t tok = (size_t)b * NN + t0 + r;
            quadq[tok * DQK + c0 + c] = f2b(acc * ga0 + be0);
            linq [tok * DQK + c0 + c] = f2b(acc * ga1 + be1);
            quadk[tok * DQK + c0 + c] = f2b(acc * ga2 + be2);
            o[c][r] = f2b(acc * ga3 + be3);
        }
        __syncthreads();
        // transposed write of linkT rows c0..c0+63
        int t8 = (tid & 7) * 8, ch = tid >> 3;
        #pragma unroll
        for (int ps = 0; ps < 2; ps++) {
            int cc = ch + ps * 32;
            short8 v = *(const short8*)(&o[cc][t8]);
            *(short8*)(linkT + (size_t)(c0 + cc) * rowsC + b * NN + t0 + t8) = v;
        }
    }
}

// ---------------- dwconv (generic, vectorized staging) -----------------------------------
template<typename TO>
__global__ __launch_bounds__(256) void dwconv_res(
    const bf16* __restrict__ src, const float* __restrict__ dw,
    const float* __restrict__ xres, TO* __restrict__ dst, int C, int ldS)
{
    int c0 = blockIdx.x * 64;
    int t0 = blockIdx.y * 64;
    int b  = blockIdx.z;
    __shared__ float s[80][64];
    int tid = threadIdx.x;
    int c = tid & 63;
    int rp = tid >> 6;
    const bf16* base = src + (size_t)b * NN * ldS + c0;
    {
        int ch8 = (tid & 7) * 8, rw = tid >> 3;
        #pragma unroll
        for (int ps = 0; ps < 3; ps++) {
            int tt = rw + ps * 32;
            if (tt < 80) {
                int t = t0 + tt - 8;
                union { short8 v; bf16 h[8]; } u; u.v = short8{};
                if (t >= 0 && t < NN)
                    u.v = *(const short8*)(base + (size_t)t * ldS + ch8);
                float* sp = &s[tt][ch8];
                #pragma unroll
                for (int k = 0; k < 8; k++) sp[k] = b2f(u.h[k]);
            }
        }
    }
    __syncthreads();
    float w[KW];
    for (int k = 0; k < KW; k++) w[k] = dw[k * C + c0 + c];
    for (int l = 0; l < 16; l++) {
        int r = rp + l * 4;
        float acc = s[r + 8][c];
        for (int k = 0; k < KW; k++) acc += s[r + k][c] * w[k];
        long gidx = ((long)b * NN + t0 + r) * C + c0 + c;
        if (xres) acc += xres[gidx];
        stv(dst, gidx, acc);
    }
}

extern "C" void kernel_launch(void* const* d_in, const int* in_sizes, int n_in,
                              void* d_out, int out_size, void* d_ws, size_t ws_size,
                              hipStream_t stream)
{
    const float* x      = (const float*)d_in[0];
    const float* ln_h_g = (const float*)d_in[1];
    const float* ln_h_b = (const float*)d_in[2];
    const float* W_h    = (const float*)d_in[3];
    const float* b_h    = (const float*)d_in[4];
    const float* dw_h   = (const float*)d_in[5];
    const float* ln_qk_g= (const float*)d_in[6];
    const float* ln_qk_b= (const float*)d_in[7];
    const float* W_qk   = (const float*)d_in[8];
    const float* b_qk   = (const float*)d_in[9];
    const float* dw_qk  = (const float*)d_in[10];
    const float* gamma  = (const float*)d_in[11];
    const float* beta   = (const float*)d_in[12];
    const float* ln_o_g = (const float*)d_in[13];
    const float* ln_o_b = (const float*)d_in[14];
    const float* W_o    = (const float*)d_in[15];
    const float* b_o    = (const float*)d_in[16];
    const float* dw_o   = (const float*)d_in[17];
    float* outp = (float*)d_out;

    // ---- fixed region ----
    char* p = (char*)d_ws;
    bf16* WT_hq = (bf16*)p;  p += (size_t)NHQ * DIM * 2;
    bf16* WT_o  = (bf16*)p;  p += (size_t)DIM * 1024 * 2;
    float* bias_hq = (float*)p; p += NHQ * 4;
    float* bias_o  = (float*)p; p += DIM * 4;
    p = (char*)(((uintptr_t)p + 255) & ~(uintptr_t)255);
    size_t fixed = (size_t)(p - (char*)d_ws);
    bf16* WT_h  = WT_hq;
    bf16* WT_qk = WT_hq + (size_t)HID * DIM;
    float* bias_h  = bias_hq;

    auto bytes_for = [fixed](int cb) -> size_t {
        size_t rows = (size_t)cb * NN;
        return fixed
             + rows * NHQ * 2           // s1 hq / linkvT / fin_pre
             + rows * 1024 * 2          // s2 hat1 -> hat2
             + rows * HID * 2           // s3 hidT
             + rows * 1024 * 2          // s4 outg
             + (size_t)cb * NG * GRP * GRP * 2   // s5 P
             + 4 * rows * DQK * 2       // s6 linkT + quadq/quadk/linq
             + rows * 1024 * 2          // s11 linkvb
             + 4096;
    };
    int CB = 1;
    if (bytes_for(8) <= ws_size) CB = 8;
    else if (bytes_for(4) <= ws_size) CB = 4;
    else if (bytes_for(2) <= ws_size) CB = 2;
    const int rowsC = CB * NN;
    const size_t rows = (size_t)rowsC;

    char* s1 = p;               p += rows * NHQ * 2;   // hq -> linkvT -> fin_pre
    char* s2 = p;               p += rows * 1024 * 2;  // hat1 (512-wide) -> hat2 (1024-wide)
    char* s3 = p;               p += rows * HID * 2;   // hidT
    char* s4 = p;               p += rows * 1024 * 2;  // outg
    char* s5 = p;               p += (size_t)CB * NG * GRP * GRP * 2;  // P
    char* s6 = p;               p += rows * DQK * 2;   // linkT
    char* s8 = p;               p += rows * DQK * 2;   // quadq
    char* s9 = p;               p += rows * DQK * 2;   // quadk
    char* s10 = p;              p += rows * DQK * 2;   // linq
    char* s11 = p;              p += rows * 1024 * 2;  // linkvb (bf16 cumsum out)

    bf16*  hq      = (bf16*)s1;
    float* linkvT  = (float*)s1;
    bf16*  fin_pre = (bf16*)s1;
    bf16*  hat1    = (bf16*)s2;   // dead after step 2; hat2 overwrites at step 10
    bf16*  hat2    = (bf16*)s2;
    bf16*  hidT    = (bf16*)s3;
    bf16*  outg    = (bf16*)s4;
    bf16*  P       = (bf16*)s5;
    bf16*  linkT   = (bf16*)s6;
    bf16*  quadq   = (bf16*)s8;
    bf16*  quadk   = (bf16*)s9;
    bf16*  linq    = (bf16*)s10;
    bf16*  linkvb  = (bf16*)s11;

    // ---- weight prep: 3 launches total ----
    prep_all<<<1600, 256, 0, stream>>>(W_h, ln_h_g, WT_h,
                                       W_qk, ln_qk_g, WT_qk,
                                       W_o, ln_o_g, WT_o);
    bias_init3<<<(NHQ + DIM + 255) / 256, 256, 0, stream>>>(b_h, b_qk, b_o, bias_hq, bias_o);
    bias_reduce3<<<104, 256, 0, stream>>>(W_h, ln_h_b, W_qk, ln_qk_b, W_o, ln_o_b,
                                          bias_hq, bias_o);

    const int G = CB * NG;   // groups per chunk
    for (int b0 = 0; b0 < BB; b0 += CB) {
        const float* xc = x    + (size_t)b0 * NN * DIM;
        float* outc     = outp + (size_t)b0 * NN * DIM;
        int R = rowsC;

        // 1) LN of token-shifted x -> hat1 (s2)
        ln_kernel_f<DIM, 1><<<R, 256, 0, stream>>>(xc, hat1);
        // 2a) h-part (N=2048) on the 256x256 kernel — grid multiple of 256 (1 blk/CU waves)
        gemm256<<<dim3((R / 256) * (HID / 256)), 512, 0, stream>>>(
            hat1, WT_h, bias_h, hq, HID, DIM, NHQ);
        // 2b) qk-part (N=128) on the pipelined 128x128 kernel
        gemm_pipe<<<dim3(R / 128), 256, 0, stream>>>(
            hat1, WT_qk, bias_hq + HID, hq + HID, R, 128, DIM, NHQ);
        // 3+4+5) merged dwconv: h transposed-write + qk conv+affine
        {
            int nDual = (HID / 64) * (NN / 64) * CB;
            int nQk   = (DQK / 64) * (NN / 64) * CB;
            dwconv_both<<<nDual + nQk, 256, 0, stream>>>(
                hq, dw_h, hidT, dw_qk, gamma, beta,
                quadq, quadk, linq, linkT, rowsC, nDual);
        }
        // 6+7) merged scores + linkv (both depend only on dwconv outputs)
        score_linkv<<<4 * G + 16 * G, 256, 0, stream>>>(
            quadq, quadk, P, hidT, linkT, linkvT, rowsC, 4 * G);
        // 8) exclusive cumsum over groups -> linkvb bf16
        cumsum_bf<<<(CB * DQK * HID) / (256 * 4), 256, 0, stream>>>(linkvT, linkvb);
        // 9) fused apply + gating -> outg (v,u from hidT), XCD-affine per group
        attn_apply_mfma<<<dim3(16 * G), 256, 0, stream>>>(P, hidT, linq, linkvb, outg, rowsC);
        // 10) LN(outg) -> hat2 (overwrites hat1, which is dead)
        ln_kernel_bf<1024><<<R, 256, 0, stream>>>(outg, hat2);
        // 11) fin_pre = silu(hat2 @ W_o' + bias_o')
        gemm_pipe<<<dim3((DIM / 128) * (R / 128)), 256, 0, stream>>>(
            hat2, WT_o, bias_o, fin_pre, R, DIM, 1024, DIM);
        // 12) d_out(fp32) = x + fin_pre + dwconv(fin_pre)
        dwconv_res<float><<<dim3(DIM / 64, NN / 64, CB), 256, 0, stream>>>(
            fin_pre, dw_o, xc, outc, DIM, DIM);
    }
}

// Round 11
// 386.523 us; speedup vs baseline: 1.1916x; 1.0094x over previous
//
#include <hip/hip_runtime.h>
#include <hip/hip_bf16.h>

typedef __hip_bfloat16 bf16;
typedef __attribute__((ext_vector_type(8))) short short8;
typedef __attribute__((ext_vector_type(4))) short short4v;
typedef __attribute__((ext_vector_type(2))) short short2v;
typedef __attribute__((ext_vector_type(4))) float float4v;
typedef __attribute__((ext_vector_type(2))) float float2v;
__device__ __forceinline__ float b2f(bf16 v){ return __bfloat162float(v); }
__device__ __forceinline__ bf16 f2b(float v){ return __float2bfloat16(v); }
__device__ __forceinline__ void stv(float* p, long i, float v){ p[i] = v; }
__device__ __forceinline__ void stv(bf16*  p, long i, float v){ p[i] = f2b(v); }

#define MFMA __builtin_amdgcn_mfma_f32_16x16x32_bf16
#define AS1(p) ((const __attribute__((address_space(1))) void*)(p))
#define AS3(p) ((__attribute__((address_space(3))) void*)(p))

// Problem constants
#define BB   8
#define NN   2048
#define DIM  512
#define HID  2048
#define DQK  128
#define GRP  256
#define NG   8
#define KW   17
#define BK   32
#define NHQ  2176   // merged N for h(2048) + qk(128) buffers (stride); 17 blocks of 128

// ---------------- LayerNorm: fp32 input, token-shift, float2-vectorized ------------------
template<int D, int SHIFT_HALF>
__global__ __launch_bounds__(256) void ln_kernel_f(const float* __restrict__ in,
                                                   bf16* __restrict__ out)
{
    int row = blockIdx.x;
    int t = row % NN;
    int tid = threadIdx.x;
    int c0 = tid * 2;                      // D = 512, 2 floats/thread
    float2v v2 = {0.f, 0.f};
    if (SHIFT_HALF && c0 < D / 2) {
        if (t > 0) v2 = *(const float2v*)(in + ((long)row - 1) * D + c0);
    } else {
        v2 = *(const float2v*)(in + (long)row * D + c0);
    }
    float s = v2[0] + v2[1];
    float ss = v2[0] * v2[0] + v2[1] * v2[1];
    for (int o = 32; o > 0; o >>= 1) { s += __shfl_down(s, o); ss += __shfl_down(ss, o); }
    __shared__ float sm[4], sm2[4];
    int wid = tid >> 6, lane = tid & 63;
    if (lane == 0) { sm[wid] = s; sm2[wid] = ss; }
    __syncthreads();
    if (tid == 0) {
        float a = 0.f, q = 0.f;
        for (int w = 0; w < 4; w++) { a += sm[w]; q += sm2[w]; }
        sm[0] = a; sm2[0] = q;
    }
    __syncthreads();
    float mean = sm[0] / D;
    float var  = fmaxf(sm2[0] / D - mean * mean, 0.f);
    float rs = rsqrtf(var + 1e-5f);
    union { short2v v; bf16 h[2]; } o2;
    o2.h[0] = f2b((v2[0] - mean) * rs);
    o2.h[1] = f2b((v2[1] - mean) * rs);
    *(short2v*)(out + (long)row * D + c0) = o2.v;
}

// vectorized bf16 LN: D=1024, each thread owns 4 contiguous cols (8B loads/stores)
template<int D>
__global__ __launch_bounds__(256) void ln_kernel_bf(const bf16* __restrict__ in,
                                                    bf16* __restrict__ out)
{
    int row = blockIdx.x;
    int tid = threadIdx.x;
    int c0 = tid * 4;
    union { short4v v; bf16 h[4]; } u;
    u.v = *(const short4v*)(in + (long)row * D + c0);
    float vals[4];
    float s = 0.f, ss = 0.f;
    #pragma unroll
    for (int i = 0; i < 4; i++) {
        float v = b2f(u.h[i]);
        vals[i] = v; s += v; ss += v * v;
    }
    for (int o = 32; o > 0; o >>= 1) { s += __shfl_down(s, o); ss += __shfl_down(ss, o); }
    __shared__ float sm[4], sm2[4];
    int wid = tid >> 6, lane = tid & 63;
    if (lane == 0) { sm[wid] = s; sm2[wid] = ss; }
    __syncthreads();
    if (tid == 0) {
        float a = 0.f, q = 0.f;
        for (int w = 0; w < 4; w++) { a += sm[w]; q += sm2[w]; }
        sm[0] = a; sm2[0] = q;
    }
    __syncthreads();
    float mean = sm[0] / D;
    float var  = fmaxf(sm2[0] / D - mean * mean, 0.f);
    float rs = rsqrtf(var + 1e-5f);
    union { short4v v; bf16 h[4]; } o4;
    #pragma unroll
    for (int i = 0; i < 4; i++) o4.h[i] = f2b((vals[i] - mean) * rs);
    *(short4v*)(out + (long)row * D + c0) = o4.v;
}

// ---------------- merged weight prep: all 3 WT in one launch -----------------------------
__global__ __launch_bounds__(256) void prep_all(
    const float* __restrict__ W_h,  const float* __restrict__ g_h,  bf16* __restrict__ WT_h,
    const float* __restrict__ W_qk, const float* __restrict__ g_qk, bf16* __restrict__ WT_qk,
    const float* __restrict__ W_o,  const float* __restrict__ g_o,  bf16* __restrict__ WT_o)
{
    int i = blockIdx.x;
    const float *W, *g; bf16* WT; int K, N, k0, n0;
    if (i < 1024) {                 // W_h: K=512 (16 kb), N=2048 (64 nb)
        W = W_h; g = g_h; WT = WT_h; K = DIM; N = HID;
        k0 = (i & 15) * 32; n0 = (i >> 4) * 32;
    } else if (i < 1088) {          // W_qk: K=512 (16 kb), N=128 (4 nb)
        int j = i - 1024;
        W = W_qk; g = g_qk; WT = WT_qk; K = DIM; N = DQK;
        k0 = (j & 15) * 32; n0 = (j >> 4) * 32;
    } else {                        // W_o: K=1024 (32 kb), N=512 (16 nb)
        int j = i - 1088;
        W = W_o; g = g_o; WT = WT_o; K = 1024; N = DIM;
        k0 = (j & 31) * 32; n0 = (j >> 5) * 32;
    }
    __shared__ float Ws[32][33];
    int tid = threadIdx.x;
    for (int l = 0; l < 4; l++) {
        int e = tid + 256 * l;
        int kk = e >> 5, nn = e & 31;
        Ws[kk][nn] = g[k0 + kk] * W[(size_t)(k0 + kk) * N + n0 + nn];
    }
    __syncthreads();
    for (int l = 0; l < 4; l++) {
        int e = tid + 256 * l;
        int nn = e >> 5, kk = e & 31;
        WT[(size_t)(n0 + nn) * K + k0 + kk] = f2b(Ws[kk][nn]);
    }
}

// ---------------- merged bias init --------------------------------------------------------
__global__ __launch_bounds__(256) void bias_init3(
    const float* __restrict__ b_h, const float* __restrict__ b_qk,
    const float* __restrict__ b_o, float* __restrict__ bias_hq,
    float* __restrict__ bias_o)
{
    int n = blockIdx.x * 256 + threadIdx.x;
    if (n < HID)                 bias_hq[n] = b_h[n];
    else if (n < NHQ)            bias_hq[n] = b_qk[n - HID];
    else if (n < NHQ + DIM)      bias_o[n - NHQ] = b_o[n - NHQ];
}

// ---------------- merged bias reduce (parallel over K, atomics — r5-proven) --------------
#define BKC 64
__global__ __launch_bounds__(256) void bias_reduce3(
    const float* __restrict__ W_h,  const float* __restrict__ lnb_h,
    const float* __restrict__ W_qk, const float* __restrict__ lnb_qk,
    const float* __restrict__ W_o,  const float* __restrict__ lnb_o,
    float* __restrict__ bias_hq, float* __restrict__ bias_o)
{
    int i = blockIdx.x;
    const float *W, *lnb; float* out; int N, n, k0;
    if (i < 64) {                   // W_h: N=2048 (8 nb), K=512 (8 kb)
        W = W_h; lnb = lnb_h; out = bias_hq; N = HID;
        n = (i & 7) * 256 + threadIdx.x; k0 = (i >> 3) * BKC;
    } else if (i < 72) {            // W_qk: N=128 (1 nb), K=512 (8 kb)
        int j = i - 64;
        W = W_qk; lnb = lnb_qk; out = bias_hq + HID; N = DQK;
        n = threadIdx.x; k0 = j * BKC;
    } else {                        // W_o: N=512 (2 nb), K=1024 (16 kb)
        int j = i - 72;
        W = W_o; lnb = lnb_o; out = bias_o; N = DIM;
        n = (j & 1) * 256 + threadIdx.x; k0 = (j >> 1) * BKC;
    }
    if (n >= N) return;
    float s = 0.f;
    #pragma unroll 8
    for (int k = k0; k < k0 + BKC; k++) s += lnb[k] * W[(size_t)k * N + n];
    atomicAdd(&out[n], s);
}

// ---------------- staging helper: 128 rows x 32 cols bf16 tile via global_load_lds -------
__device__ __forceinline__ void stage_tile(const bf16* base, size_t ld, bf16* dst,
                                           int wave, int lane)
{
    int lrow = lane >> 2, lcol = lane & 3;
    for (int cc = 0; cc < 2; cc++) {
        int c = wave * 2 + cc;
        int row = c * 16 + lrow;
        const bf16* g = base + (size_t)row * ld + lcol * 8;
        __builtin_amdgcn_global_load_lds(AS1(g), AS3(dst + c * 512), 16, 0, 0);
    }
}

// ============ shared 3-slot pipelined 128x128 GEMM core (T3/T4/T5, proven in r2) =========
#define PIPE_SLOT 8192   // As(128x32) + Bs(128x32) bf16 = 16 KiB; 3 slots = 48 KiB -> 3 blk/CU

__device__ __forceinline__ void pipe_core(
    const bf16* __restrict__ Abase, size_t ldA,
    const bf16* __restrict__ Bbase, size_t ldB,
    int nit, bf16* lds, int wave, int lane, float4v acc[4][4])
{
    auto stage = [&](int it, int slot) {
        bf16* As = lds + slot * PIPE_SLOT;
        stage_tile(Abase + (size_t)it * 32, ldA, As, wave, lane);
        stage_tile(Bbase + (size_t)it * 32, ldB, As + 4096, wave, lane);
    };
    stage(0, 0);
    stage(1, 1);
    asm volatile("s_waitcnt vmcnt(4)" ::: "memory");
    __builtin_amdgcn_s_barrier();
    __builtin_amdgcn_sched_barrier(0);

    int wm = wave & 1, wn = wave >> 1;
    int col = lane & 15, quad = lane >> 4;
    int slot = 0;
    for (int it = 0; it < nit; it++) {
        const bf16* As = lds + slot * PIPE_SLOT;
        const bf16* Bs = As + 4096;
        short8 a[4], b[4];
        #pragma unroll
        for (int t = 0; t < 4; t++) {
            a[t] = *(const short8*)(As + (wm * 64 + t * 16 + col) * 32 + quad * 8);
            b[t] = *(const short8*)(Bs + (wn * 64 + t * 16 + col) * 32 + quad * 8);
        }
        int nslot = slot + 1; if (nslot == 3) nslot = 0;
        int pslot = nslot + 1; if (pslot == 3) pslot = 0;   // (slot+2)%3
        if (it + 2 < nit) stage(it + 2, pslot);
        asm volatile("s_waitcnt lgkmcnt(0)" ::: "memory");
        __builtin_amdgcn_sched_barrier(0);
        __builtin_amdgcn_s_setprio(1);
        #pragma unroll
        for (int i = 0; i < 4; i++)
            #pragma unroll
            for (int j = 0; j < 4; j++)
                acc[i][j] = MFMA(a[i], b[j], acc[i][j], 0, 0, 0);
        __builtin_amdgcn_s_setprio(0);
        __builtin_amdgcn_sched_barrier(0);
        if (it + 2 < nit) { asm volatile("s_waitcnt vmcnt(4)" ::: "memory"); }
        else              { asm volatile("s_waitcnt vmcnt(0)" ::: "memory"); }
        __builtin_amdgcn_s_barrier();
        __builtin_amdgcn_sched_barrier(0);
        slot = nslot;
    }
}

// ---------------- pipelined MFMA GEMM: C = silu(A@B^T + bias); XCD-affine m-blocks -------
__global__ __launch_bounds__(256) void gemm_pipe(
    const bf16* __restrict__ A, const bf16* __restrict__ BT,
    const float* __restrict__ bias, bf16* __restrict__ C,
    int M, int N, int K, int ldC)
{
    __shared__ __align__(16) bf16 lds[3 * PIPE_SLOT];
    int nb = N >> 7;
    int i = blockIdx.x;
    int xcd = i & 7, r = i >> 3;
    int m0 = (xcd + 8 * (r / nb)) << 7;   // same-A-panel blocks share an XCD
    int n0 = (r % nb) << 7;
    int tid = threadIdx.x, wave = tid >> 6, lane = tid & 63;
    float4v acc[4][4] = {};
    pipe_core(A + (size_t)m0 * K, K, BT + (size_t)n0 * K, K, K / 32,
              lds, wave, lane, acc);
    int wm = wave & 1, wn = wave >> 1;
    int col = lane & 15, quad = lane >> 4;
    for (int i2 = 0; i2 < 4; i2++) {
        for (int j = 0; j < 4; j++) {
            int n = n0 + wn * 64 + j * 16 + col;
            float bs = bias[n];
            for (int r2 = 0; r2 < 4; r2++) {
                int m = m0 + wm * 64 + i2 * 16 + quad * 4 + r2;
                float v = acc[i2][j][r2] + bs;
                v = v / (1.f + __expf(-v));
                C[(size_t)m * ldC + n] = f2b(v);
            }
        }
    }
}

// ======== merged attn_score + linkv (one launch; both pipe_core; XCD-affine) =============
__global__ __launch_bounds__(256) void score_linkv(
    const bf16* __restrict__ quadq, const bf16* __restrict__ quadk,
    bf16* __restrict__ P,
    const bf16* __restrict__ hidT, const bf16* __restrict__ linkT,
    float* __restrict__ linkvT, int rowsC, int nScore)
{
    __shared__ __align__(16) bf16 lds[3 * PIPE_SLOT];
    int tid = threadIdx.x, wave = tid >> 6, lane = tid & 63;
    if ((int)blockIdx.x < nScore) {
        // ---- attn scores: P = relu(QK^T/256)^2, causal ----
        int i = blockIdx.x;
        int xcd = i & 7, r = i >> 3;
        int g = xcd + 8 * (r >> 2);
        int t = r & 3, bi = t >> 1, bj = t & 1;
        bf16* Pg = P + (size_t)g * GRP * GRP;
        if (bj > bi) {   // fully masked tile: write zeros
            short8 z = {};
            int rr = tid >> 1, half = tid & 1;
            short* dst = (short*)Pg + (size_t)(bi * 128 + rr) * GRP + bj * 128 + half * 64;
            for (int q = 0; q < 8; q++) ((short8*)dst)[q] = z;
            return;
        }
        float4v acc[4][4] = {};
        const bf16* Ab = quadq + (size_t)(g * GRP + bi * 128) * DQK;
        const bf16* Bb = quadk + (size_t)(g * GRP + bj * 128) * DQK;
        pipe_core(Ab, DQK, Bb, DQK, DQK / 32, lds, wave, lane, acc);
        int wm = wave & 1, wn = wave >> 1;
        int col = lane & 15, quad = lane >> 4;
        for (int i2 = 0; i2 < 4; i2++) {
            for (int j = 0; j < 4; j++) {
                int jj = bj * 128 + wn * 64 + j * 16 + col;
                for (int r2 = 0; r2 < 4; r2++) {
                    int ii = bi * 128 + wm * 64 + i2 * 16 + quad * 4 + r2;
                    float s = acc[i2][j][r2] * (1.f / GRP);
                    s = fmaxf(s, 0.f); s = s * s;
                    if (jj > ii) s = 0.f;
                    Pg[(size_t)ii * GRP + jj] = f2b(s);
                }
            }
        }
    } else {
        // ---- linkv: linkvT[g][e][d] = (hidT_g @ linkT_g^T)/256 ----
        int i = blockIdx.x - nScore;       // nScore % 8 == 0 -> XCD parity preserved
        int xcd = i & 7, r = i >> 3;
        int g = xcd + 8 * (r >> 4);
        int eb = r & 15;
        int e0 = eb * 128;
        float4v acc[4][4] = {};
        pipe_core(hidT + (size_t)e0 * rowsC + g * GRP, rowsC,
                  linkT + g * GRP, rowsC, GRP / 32, lds, wave, lane, acc);
        float* out = linkvT + (size_t)g * (HID * DQK);
        int wm = wave & 1, wn = wave >> 1;
        int col = lane & 15, quad = lane >> 4;
        for (int i2 = 0; i2 < 4; i2++) {
            for (int j = 0; j < 4; j++) {
                int d = wn * 64 + j * 16 + col;
                for (int r2 = 0; r2 < 4; r2++) {
                    int e = e0 + wm * 64 + i2 * 16 + quad * 4 + r2;
                    out[(size_t)e * DQK + d] = acc[i2][j][r2] * (1.f / GRP);
                }
            }
        }
    }
}

// ---------------- exclusive cumsum over group axis, fp32 in -> bf16 out (x4 vec) ---------
__global__ void cumsum_bf(const float* __restrict__ in, bf16* __restrict__ out)
{
    long idx4 = (long)blockIdx.x * blockDim.x + threadIdx.x;   // 4 elems per thread
    int b = (int)(idx4 / (DQK * HID / 4));
    long off = (idx4 % (DQK * HID / 4)) * 4;
    const float* pi = in + (long)b * NG * DQK * HID + off;
    bf16* po = out + (long)b * NG * DQK * HID + off;
    float4v run = {0.f, 0.f, 0.f, 0.f};
    for (int gi = 0; gi < NG; gi++) {
        short4v o4;
        union { short s; bf16 h; } cv;
        #pragma unroll
        for (int k = 0; k < 4; k++) { cv.h = f2b(run[k]); o4[k] = cv.s; }
        *(short4v*)(po + (long)gi * DQK * HID) = o4;
        run += *(const float4v*)(pi + (long)gi * DQK * HID);
    }
}

// ---------------- fused attn apply MFMA + gating — 3-slot pipelined, XCD-affine ----------
// gating reads hidT (ch-major) via short4 over the 4 consecutive tokens of each quad
#define AP_SLOT (256 * BK + 128 * BK)   // 12288 bf16 = 24 KiB per slot

__global__ __launch_bounds__(256) void attn_apply_mfma(
    const bf16* __restrict__ P, const bf16* __restrict__ hidT,
    const bf16* __restrict__ linq, const bf16* __restrict__ linkvb,
    bf16* __restrict__ outg, int rowsC)
{
    int ib = blockIdx.x;
    int xcd = ib & 7, rb = ib >> 3;
    int g = xcd + 8 * (rb >> 4);          // all 16 e-blocks of a group share an XCD
    int e0 = (rb & 15) * 64;
    __shared__ __align__(16) bf16 lds[3 * AP_SLOT];
    int tid = threadIdx.x, wave = tid >> 6, lane = tid & 63;
    int lrow = lane >> 2, lcol = lane & 3;
    const bf16* Pg = P + (size_t)g * GRP * GRP;
    const bf16* Lg = linkvb + (size_t)g * (HID * DQK);

    // stage iteration 'it' (0..7: quad j0=it*32; 8..11: lin d0=(it-8)*32) into 'slot'
    auto stage = [&](int it, int slot) {
        bf16* As = lds + slot * AP_SLOT;
        bf16* Bs = As + 256 * BK;
        if (it < 8) {
            int j0 = it * 32;
            for (int cc = 0; cc < 4; cc++) {
                int c = wave * 4 + cc;
                int row = c * 16 + lrow;
                const bf16* ga = Pg + (size_t)row * GRP + j0 + lcol * 8;
                __builtin_amdgcn_global_load_lds(AS1(ga), AS3(As + c * 512), 16, 0, 0);
            }
            for (int cc = 0; cc < 2; cc++) {
                int c = wave * 2 + cc;
                int row = c * 16 + lrow;
                int er = (row < 64) ? (e0 + row) : (1024 + e0 + (row - 64));
                const bf16* gb = hidT + (size_t)er * rowsC + g * GRP + j0 + lcol * 8;
                __builtin_amdgcn_global_load_lds(AS1(gb), AS3(Bs + c * 512), 16, 0, 0);
            }
        } else {
            int d0 = (it - 8) * 32;
            for (int cc = 0; cc < 4; cc++) {
                int c = wave * 4 + cc;
                int row = c * 16 + lrow;
                const bf16* ga = linq + (size_t)(g * GRP + row) * DQK + d0 + lcol * 8;
                __builtin_amdgcn_global_load_lds(AS1(ga), AS3(As + c * 512), 16, 0, 0);
            }
            for (int cc = 0; cc < 2; cc++) {
                int c = wave * 2 + cc;
                int row = c * 16 + lrow;
                int er = (row < 64) ? (e0 + row) : (1024 + e0 + (row - 64));
                const bf16* gb = Lg + (size_t)er * DQK + d0 + lcol * 8;
                __builtin_amdgcn_global_load_lds(AS1(gb), AS3(Bs + c * 512), 16, 0, 0);
            }
        }
    };

    // prologue: slots 0 and 1 in flight; wait for slot 0 (6 loads of slot1 may remain)
    stage(0, 0);
    stage(1, 1);
    asm volatile("s_waitcnt vmcnt(6)" ::: "memory");
    __builtin_amdgcn_s_barrier();
    __builtin_amdgcn_sched_barrier(0);

    float4v acc[4][8] = {};
    int col = lane & 15, quad = lane >> 4;
    int slot = 0;
    for (int it = 0; it < 12; it++) {
        const bf16* As = lds + slot * AP_SLOT;
        const bf16* Bs = As + 256 * BK;
        short8 a[4], b[8];
        #pragma unroll
        for (int t = 0; t < 4; t++)
            a[t] = *(const short8*)(As + (wave * 64 + t * 16 + col) * BK + quad * 8);
        #pragma unroll
        for (int t = 0; t < 8; t++)
            b[t] = *(const short8*)(Bs + (t * 16 + col) * BK + quad * 8);
        int nslot = slot + 1; if (nslot == 3) nslot = 0;
        int pslot = nslot + 1; if (pslot == 3) pslot = 0;   // (slot+2)%3
        if (it + 2 < 12) stage(it + 2, pslot);
        asm volatile("s_waitcnt lgkmcnt(0)" ::: "memory");
        __builtin_amdgcn_sched_barrier(0);
        __builtin_amdgcn_s_setprio(1);
        #pragma unroll
        for (int i = 0; i < 4; i++)
            #pragma unroll
            for (int j = 0; j < 8; j++)
                acc[i][j] = MFMA(a[i], b[j], acc[i][j], 0, 0, 0);
        __builtin_amdgcn_s_setprio(0);
        __builtin_amdgcn_sched_barrier(0);
        if (it + 2 < 12) { asm volatile("s_waitcnt vmcnt(6)" ::: "memory"); }
        else             { asm volatile("s_waitcnt vmcnt(0)" ::: "memory"); }
        __builtin_amdgcn_s_barrier();
        __builtin_amdgcn_sched_barrier(0);
        slot = nslot;
    }

    // epilogue with gating: v,u loaded as short4 over the 4 consecutive tokens (r dim)
    for (int mt = 0; mt < 4; mt++) {
        int tokg0 = g * GRP + wave * 64 + mt * 16 + quad * 4;
        for (int nt = 0; nt < 4; nt++) {
            int e = e0 + nt * 16 + col;
            union { short4v v; bf16 h[4]; } v4, u4;
            v4.v = *(const short4v*)(hidT + (size_t)e * rowsC + tokg0);
            u4.v = *(const short4v*)(hidT + (size_t)(1024 + e) * rowsC + tokg0);
            #pragma unroll
            for (int r = 0; r < 4; r++) {
                float av = acc[mt][nt][r];
                float au = acc[mt][nt + 4][r];
                float v = b2f(v4.h[r]);
                float u = b2f(u4.h[r]);
                float gate = 1.f / (1.f + __expf(-av * u));
                outg[(size_t)(tokg0 + r) * 1024 + e] = f2b(au * v * gate);
            }
        }
    }
}

// ======== merged dwconv: h-path (hidT only) + qk-path (affine split), one launch =========
__global__ __launch_bounds__(256) void dwconv_both(
    const bf16* __restrict__ hq, const float* __restrict__ dw_h,
    bf16* __restrict__ hidT,
    const float* __restrict__ dw_qk,
    const float* __restrict__ gamma, const float* __restrict__ beta,
    bf16* __restrict__ quadq, bf16* __restrict__ quadk,
    bf16* __restrict__ linq, bf16* __restrict__ linkT,
    int rowsC, int nDual)
{
    __shared__ float s[80][64];
    __shared__ bf16 o[64][72];   // [ch][tok], row stride 144 B (16B-aligned)
    int tid = threadIdx.x;
    if ((int)blockIdx.x < nDual) {
        // ---- h path: hidT = h + dwconv(h), transposed write only ----
        int i = blockIdx.x;
        int c0 = (i & 31) * 64;            // HID/64 = 32
        int t0 = ((i >> 5) & 31) * 64;     // NN/64 = 32
        int b  = i >> 10;
        const bf16* base = hq + (size_t)b * NN * NHQ + c0;
        {
            int ch8 = (tid & 7) * 8, rw = tid >> 3;
            #pragma unroll
            for (int ps = 0; ps < 3; ps++) {
                int tt = rw + ps * 32;
                if (tt < 80) {
                    int t = t0 + tt - 8;
                    union { short8 v; bf16 h[8]; } u; u.v = short8{};
                    if (t >= 0 && t < NN)
                        u.v = *(const short8*)(base + (size_t)t * NHQ + ch8);
                    float* sp = &s[tt][ch8];
                    #pragma unroll
                    for (int k = 0; k < 8; k++) sp[k] = b2f(u.h[k]);
                }
            }
        }
        __syncthreads();
        int c = tid & 63, rp = tid >> 6;
        float w[KW];
        for (int k = 0; k < KW; k++) w[k] = dw_h[k * HID + c0 + c];
        for (int l = 0; l < 16; l++) {
            int r = rp + l * 4;
            float acc = s[r + 8][c];
            for (int k = 0; k < KW; k++) acc += s[r + k][c] * w[k];
            o[c][r] = f2b(acc);
        }
        __syncthreads();
        // write hidT (ch-major [ch][rowsC]) as short8
        {
            int t8 = (tid & 7) * 8, ch = tid >> 3;
            #pragma unroll
            for (int ps = 0; ps < 2; ps++) {
                int cc = ch + ps * 32;
                short8 v = *(const short8*)(&o[cc][t8]);
                *(short8*)(hidT + (size_t)(c0 + cc) * rowsC + b * NN + t0 + t8) = v;
            }
        }
    } else {
        // ---- qk path: conv + 4-way affine -> quadq/quadk/linq/linkT ----
        int i = blockIdx.x - nDual;
        int c0 = (i & 1) * 64;             // DQK/64 = 2
        int t0 = ((i >> 1) & 31) * 64;
        int b  = i >> 6;
        const bf16* base = hq + HID + (size_t)b * NN * NHQ + c0;
        {
            int ch8 = (tid & 7) * 8, rw = tid >> 3;
            #pragma unroll
            for (int ps = 0; ps < 3; ps++) {
                int tt = rw + ps * 32;
                if (tt < 80) {
                    int t = t0 + tt - 8;
                    union { short8 v; bf16 h[8]; } u; u.v = short8{};
                    if (t >= 0 && t < NN)
                        u.v = *(const short8*)(base + (size_t)t * NHQ + ch8);
                    float* sp = &s[tt][ch8];
                    #pragma unroll
                    for (int k = 0; k < 8; k++) sp[k] = b2f(u.h[k]);
                }
            }
        }
        __syncthreads();
        int c = tid & 63, rp = tid >> 6;
        float w[KW];
        for (int k = 0; k < KW; k++) w[k] = dw_qk[k * DQK + c0 + c];
        float ga0 = gamma[0 * DQK + c0 + c], be0 = beta[0 * DQK + c0 + c];
        float ga1 = gamma[1 * DQK + c0 + c], be1 = beta[1 * DQK + c0 + c];
        float ga2 = gamma[2 * DQK + c0 + c], be2 = beta[2 * DQK + c0 + c];
        float ga3 = gamma[3 * DQK + c0 + c], be3 = beta[3 * DQK + c0 + c];
        for (int l = 0; l < 16; l++) {
            int r = rp + l * 4;
            float acc = s[r + 8][c];
            for (int k = 0; k < KW; k++) acc += s[r + k][c] * w[k];
            size_t tok = (size_t)b * NN + t0 + r;
            quadq[tok * DQK + c0 + c] = f2b(acc * ga0 + be0);
            linq [tok * DQK + c0 + c] = f2b(acc * ga1 + be1);
            quadk[tok * DQK + c0 + c] = f2b(acc * ga2 + be2);
            o[c][r] = f2b(acc * ga3 + be3);
        }
        __syncthreads();
        // transposed write of linkT rows c0..c0+63
        int t8 = (tid & 7) * 8, ch = tid >> 3;
        #pragma unroll
        for (int ps = 0; ps < 2; ps++) {
            int cc = ch + ps * 32;
            short8 v = *(const short8*)(&o[cc][t8]);
            *(short8*)(linkT + (size_t)(c0 + cc) * rowsC + b * NN + t0 + t8) = v;
        }
    }
}

// ---------------- dwconv (generic, vectorized staging) -----------------------------------
template<typename TO>
__global__ __launch_bounds__(256) void dwconv_res(
    const bf16* __restrict__ src, const float* __restrict__ dw,
    const float* __restrict__ xres, TO* __restrict__ dst, int C, int ldS)
{
    int c0 = blockIdx.x * 64;
    int t0 = blockIdx.y * 64;
    int b  = blockIdx.z;
    __shared__ float s[80][64];
    int tid = threadIdx.x;
    int c = tid & 63;
    int rp = tid >> 6;
    const bf16* base = src + (size_t)b * NN * ldS + c0;
    {
        int ch8 = (tid & 7) * 8, rw = tid >> 3;
        #pragma unroll
        for (int ps = 0; ps < 3; ps++) {
            int tt = rw + ps * 32;
            if (tt < 80) {
                int t = t0 + tt - 8;
                union { short8 v; bf16 h[8]; } u; u.v = short8{};
                if (t >= 0 && t < NN)
                    u.v = *(const short8*)(base + (size_t)t * ldS + ch8);
                float* sp = &s[tt][ch8];
                #pragma unroll
                for (int k = 0; k < 8; k++) sp[k] = b2f(u.h[k]);
            }
        }
    }
    __syncthreads();
    float w[KW];
    for (int k = 0; k < KW; k++) w[k] = dw[k * C + c0 + c];
    for (int l = 0; l < 16; l++) {
        int r = rp + l * 4;
        float acc = s[r + 8][c];
        for (int k = 0; k < KW; k++) acc += s[r + k][c] * w[k];
        long gidx = ((long)b * NN + t0 + r) * C + c0 + c;
        if (xres) acc += xres[gidx];
        stv(dst, gidx, acc);
    }
}

extern "C" void kernel_launch(void* const* d_in, const int* in_sizes, int n_in,
                              void* d_out, int out_size, void* d_ws, size_t ws_size,
                              hipStream_t stream)
{
    const float* x      = (const float*)d_in[0];
    const float* ln_h_g = (const float*)d_in[1];
    const float* ln_h_b = (const float*)d_in[2];
    const float* W_h    = (const float*)d_in[3];
    const float* b_h    = (const float*)d_in[4];
    const float* dw_h   = (const float*)d_in[5];
    const float* ln_qk_g= (const float*)d_in[6];
    const float* ln_qk_b= (const float*)d_in[7];
    const float* W_qk   = (const float*)d_in[8];
    const float* b_qk   = (const float*)d_in[9];
    const float* dw_qk  = (const float*)d_in[10];
    const float* gamma  = (const float*)d_in[11];
    const float* beta   = (const float*)d_in[12];
    const float* ln_o_g = (const float*)d_in[13];
    const float* ln_o_b = (const float*)d_in[14];
    const float* W_o    = (const float*)d_in[15];
    const float* b_o    = (const float*)d_in[16];
    const float* dw_o   = (const float*)d_in[17];
    float* outp = (float*)d_out;

    // ---- fixed region ----
    char* p = (char*)d_ws;
    bf16* WT_hq = (bf16*)p;  p += (size_t)NHQ * DIM * 2;
    bf16* WT_o  = (bf16*)p;  p += (size_t)DIM * 1024 * 2;
    float* bias_hq = (float*)p; p += NHQ * 4;
    float* bias_o  = (float*)p; p += DIM * 4;
    p = (char*)(((uintptr_t)p + 255) & ~(uintptr_t)255);
    size_t fixed = (size_t)(p - (char*)d_ws);
    bf16* WT_h  = WT_hq;
    bf16* WT_qk = WT_hq + (size_t)HID * DIM;

    auto bytes_for = [fixed](int cb) -> size_t {
        size_t rows = (size_t)cb * NN;
        return fixed
             + rows * NHQ * 2           // s1 hq / linkvT / fin_pre
             + rows * 1024 * 2          // s2 hat1 -> hat2
             + rows * HID * 2           // s3 hidT
             + rows * 1024 * 2          // s4 outg
             + (size_t)cb * NG * GRP * GRP * 2   // s5 P
             + 4 * rows * DQK * 2       // s6 linkT + quadq/quadk/linq
             + rows * 1024 * 2          // s11 linkvb
             + 4096;
    };
    int CB = 1;
    if (bytes_for(8) <= ws_size) CB = 8;
    else if (bytes_for(4) <= ws_size) CB = 4;
    else if (bytes_for(2) <= ws_size) CB = 2;
    const int rowsC = CB * NN;
    const size_t rows = (size_t)rowsC;

    char* s1 = p;               p += rows * NHQ * 2;   // hq -> linkvT -> fin_pre
    char* s2 = p;               p += rows * 1024 * 2;  // hat1 (512-wide) -> hat2 (1024-wide)
    char* s3 = p;               p += rows * HID * 2;   // hidT
    char* s4 = p;               p += rows * 1024 * 2;  // outg
    char* s5 = p;               p += (size_t)CB * NG * GRP * GRP * 2;  // P
    char* s6 = p;               p += rows * DQK * 2;   // linkT
    char* s8 = p;               p += rows * DQK * 2;   // quadq
    char* s9 = p;               p += rows * DQK * 2;   // quadk
    char* s10 = p;              p += rows * DQK * 2;   // linq
    char* s11 = p;              p += rows * 1024 * 2;  // linkvb (bf16 cumsum out)

    bf16*  hq      = (bf16*)s1;
    float* linkvT  = (float*)s1;
    bf16*  fin_pre = (bf16*)s1;
    bf16*  hat1    = (bf16*)s2;   // dead after step 2; hat2 overwrites at step 10
    bf16*  hat2    = (bf16*)s2;
    bf16*  hidT    = (bf16*)s3;
    bf16*  outg    = (bf16*)s4;
    bf16*  P       = (bf16*)s5;
    bf16*  linkT   = (bf16*)s6;
    bf16*  quadq   = (bf16*)s8;
    bf16*  quadk   = (bf16*)s9;
    bf16*  linq    = (bf16*)s10;
    bf16*  linkvb  = (bf16*)s11;

    // ---- weight prep: 3 launches total ----
    prep_all<<<1600, 256, 0, stream>>>(W_h, ln_h_g, WT_h,
                                       W_qk, ln_qk_g, WT_qk,
                                       W_o, ln_o_g, WT_o);
    bias_init3<<<(NHQ + DIM + 255) / 256, 256, 0, stream>>>(b_h, b_qk, b_o, bias_hq, bias_o);
    bias_reduce3<<<104, 256, 0, stream>>>(W_h, ln_h_b, W_qk, ln_qk_b, W_o, ln_o_b,
                                          bias_hq, bias_o);

    const int G = CB * NG;   // groups per chunk
    for (int b0 = 0; b0 < BB; b0 += CB) {
        const float* xc = x    + (size_t)b0 * NN * DIM;
        float* outc     = outp + (size_t)b0 * NN * DIM;
        int R = rowsC;

        // 1) LN of token-shifted x -> hat1 (s2)
        ln_kernel_f<DIM, 1><<<R, 256, 0, stream>>>(xc, hat1);
        // 2) merged h+qk GEMM on pipe_core (48 KiB LDS -> 3 blocks/CU; N = 17 x 128)
        gemm_pipe<<<dim3((R / 128) * (NHQ / 128)), 256, 0, stream>>>(
            hat1, WT_hq, bias_hq, hq, R, NHQ, DIM, NHQ);
        // 3+4+5) merged dwconv: h transposed-write + qk conv+affine
        {
            int nDual = (HID / 64) * (NN / 64) * CB;
            int nQk   = (DQK / 64) * (NN / 64) * CB;
            dwconv_both<<<nDual + nQk, 256, 0, stream>>>(
                hq, dw_h, hidT, dw_qk, gamma, beta,
                quadq, quadk, linq, linkT, rowsC, nDual);
        }
        // 6+7) merged scores + linkv (both depend only on dwconv outputs)
        score_linkv<<<4 * G + 16 * G, 256, 0, stream>>>(
            quadq, quadk, P, hidT, linkT, linkvT, rowsC, 4 * G);
        // 8) exclusive cumsum over groups -> linkvb bf16
        cumsum_bf<<<(CB * DQK * HID) / (256 * 4), 256, 0, stream>>>(linkvT, linkvb);
        // 9) fused apply + gating -> outg (v,u from hidT), XCD-affine per group
        attn_apply_mfma<<<dim3(16 * G), 256, 0, stream>>>(P, hidT, linq, linkvb, outg, rowsC);
        // 10) LN(outg) -> hat2 (overwrites hat1, which is dead)
        ln_kernel_bf<1024><<<R, 256, 0, stream>>>(outg, hat2);
        // 11) fin_pre = silu(hat2 @ W_o' + bias_o')
        gemm_pipe<<<dim3((DIM / 128) * (R / 128)), 256, 0, stream>>>(
            hat2, WT_o, bias_o, fin_pre, R, DIM, 1024, DIM);
        // 12) d_out(fp32) = x + fin_pre + dwconv(fin_pre)
        dwconv_res<float><<<dim3(DIM / 64, NN / 64, CB), 256, 0, stream>>>(
            fin_pre, dw_o, xc, outc, DIM, DIM);
    }
}

// Round 12
// 380.474 us; speedup vs baseline: 1.2106x; 1.0159x over previous
//
#include <hip/hip_runtime.h>
#include <hip/hip_bf16.h>

typedef __hip_bfloat16 bf16;
typedef __attribute__((ext_vector_type(8))) short short8;
typedef __attribute__((ext_vector_type(4))) short short4v;
typedef __attribute__((ext_vector_type(2))) short short2v;
typedef __attribute__((ext_vector_type(4))) float float4v;
typedef __attribute__((ext_vector_type(2))) float float2v;
__device__ __forceinline__ float b2f(bf16 v){ return __bfloat162float(v); }
__device__ __forceinline__ bf16 f2b(float v){ return __float2bfloat16(v); }
__device__ __forceinline__ void stv(float* p, long i, float v){ p[i] = v; }
__device__ __forceinline__ void stv(bf16*  p, long i, float v){ p[i] = f2b(v); }

#define MFMA __builtin_amdgcn_mfma_f32_16x16x32_bf16
#define AS1(p) ((const __attribute__((address_space(1))) void*)(p))
#define AS3(p) ((__attribute__((address_space(3))) void*)(p))

// Problem constants
#define BB   8
#define NN   2048
#define DIM  512
#define HID  2048
#define DQK  128
#define GRP  256
#define NG   8
#define KW   17
#define BK   32
#define NHQ  2176   // merged N for h(2048) + qk(128) buffers (stride); 17 blocks of 128

// ---------------- LayerNorm: fp32 input, token-shift, float2-vectorized ------------------
template<int D, int SHIFT_HALF>
__global__ __launch_bounds__(256) void ln_kernel_f(const float* __restrict__ in,
                                                   bf16* __restrict__ out)
{
    int row = blockIdx.x;
    int t = row % NN;
    int tid = threadIdx.x;
    int c0 = tid * 2;                      // D = 512, 2 floats/thread
    float2v v2 = {0.f, 0.f};
    if (SHIFT_HALF && c0 < D / 2) {
        if (t > 0) v2 = *(const float2v*)(in + ((long)row - 1) * D + c0);
    } else {
        v2 = *(const float2v*)(in + (long)row * D + c0);
    }
    float s = v2[0] + v2[1];
    float ss = v2[0] * v2[0] + v2[1] * v2[1];
    for (int o = 32; o > 0; o >>= 1) { s += __shfl_down(s, o); ss += __shfl_down(ss, o); }
    __shared__ float sm[4], sm2[4];
    int wid = tid >> 6, lane = tid & 63;
    if (lane == 0) { sm[wid] = s; sm2[wid] = ss; }
    __syncthreads();
    if (tid == 0) {
        float a = 0.f, q = 0.f;
        for (int w = 0; w < 4; w++) { a += sm[w]; q += sm2[w]; }
        sm[0] = a; sm2[0] = q;
    }
    __syncthreads();
    float mean = sm[0] / D;
    float var  = fmaxf(sm2[0] / D - mean * mean, 0.f);
    float rs = rsqrtf(var + 1e-5f);
    union { short2v v; bf16 h[2]; } o2;
    o2.h[0] = f2b((v2[0] - mean) * rs);
    o2.h[1] = f2b((v2[1] - mean) * rs);
    *(short2v*)(out + (long)row * D + c0) = o2.v;
}

// vectorized bf16 LN: D=1024, each thread owns 4 contiguous cols (8B loads/stores)
template<int D>
__global__ __launch_bounds__(256) void ln_kernel_bf(const bf16* __restrict__ in,
                                                    bf16* __restrict__ out)
{
    int row = blockIdx.x;
    int tid = threadIdx.x;
    int c0 = tid * 4;
    union { short4v v; bf16 h[4]; } u;
    u.v = *(const short4v*)(in + (long)row * D + c0);
    float vals[4];
    float s = 0.f, ss = 0.f;
    #pragma unroll
    for (int i = 0; i < 4; i++) {
        float v = b2f(u.h[i]);
        vals[i] = v; s += v; ss += v * v;
    }
    for (int o = 32; o > 0; o >>= 1) { s += __shfl_down(s, o); ss += __shfl_down(ss, o); }
    __shared__ float sm[4], sm2[4];
    int wid = tid >> 6, lane = tid & 63;
    if (lane == 0) { sm[wid] = s; sm2[wid] = ss; }
    __syncthreads();
    if (tid == 0) {
        float a = 0.f, q = 0.f;
        for (int w = 0; w < 4; w++) { a += sm[w]; q += sm2[w]; }
        sm[0] = a; sm2[0] = q;
    }
    __syncthreads();
    float mean = sm[0] / D;
    float var  = fmaxf(sm2[0] / D - mean * mean, 0.f);
    float rs = rsqrtf(var + 1e-5f);
    union { short4v v; bf16 h[4]; } o4;
    #pragma unroll
    for (int i = 0; i < 4; i++) o4.h[i] = f2b((vals[i] - mean) * rs);
    *(short4v*)(out + (long)row * D + c0) = o4.v;
}

// ---------------- merged weight prep: all 3 WT in one launch -----------------------------
__global__ __launch_bounds__(256) void prep_all(
    const float* __restrict__ W_h,  const float* __restrict__ g_h,  bf16* __restrict__ WT_h,
    const float* __restrict__ W_qk, const float* __restrict__ g_qk, bf16* __restrict__ WT_qk,
    const float* __restrict__ W_o,  const float* __restrict__ g_o,  bf16* __restrict__ WT_o)
{
    int i = blockIdx.x;
    const float *W, *g; bf16* WT; int K, N, k0, n0;
    if (i < 1024) {                 // W_h: K=512 (16 kb), N=2048 (64 nb)
        W = W_h; g = g_h; WT = WT_h; K = DIM; N = HID;
        k0 = (i & 15) * 32; n0 = (i >> 4) * 32;
    } else if (i < 1088) {          // W_qk: K=512 (16 kb), N=128 (4 nb)
        int j = i - 1024;
        W = W_qk; g = g_qk; WT = WT_qk; K = DIM; N = DQK;
        k0 = (j & 15) * 32; n0 = (j >> 4) * 32;
    } else {                        // W_o: K=1024 (32 kb), N=512 (16 nb)
        int j = i - 1088;
        W = W_o; g = g_o; WT = WT_o; K = 1024; N = DIM;
        k0 = (j & 31) * 32; n0 = (j >> 5) * 32;
    }
    __shared__ float Ws[32][33];
    int tid = threadIdx.x;
    for (int l = 0; l < 4; l++) {
        int e = tid + 256 * l;
        int kk = e >> 5, nn = e & 31;
        Ws[kk][nn] = g[k0 + kk] * W[(size_t)(k0 + kk) * N + n0 + nn];
    }
    __syncthreads();
    for (int l = 0; l < 4; l++) {
        int e = tid + 256 * l;
        int nn = e >> 5, kk = e & 31;
        WT[(size_t)(n0 + nn) * K + k0 + kk] = f2b(Ws[kk][nn]);
    }
}

// ---------------- merged bias init --------------------------------------------------------
__global__ __launch_bounds__(256) void bias_init3(
    const float* __restrict__ b_h, const float* __restrict__ b_qk,
    const float* __restrict__ b_o, float* __restrict__ bias_hq,
    float* __restrict__ bias_o)
{
    int n = blockIdx.x * 256 + threadIdx.x;
    if (n < HID)                 bias_hq[n] = b_h[n];
    else if (n < NHQ)            bias_hq[n] = b_qk[n - HID];
    else if (n < NHQ + DIM)      bias_o[n - NHQ] = b_o[n - NHQ];
}

// ---------------- merged bias reduce (parallel over K, atomics — r5-proven) --------------
#define BKC 64
__global__ __launch_bounds__(256) void bias_reduce3(
    const float* __restrict__ W_h,  const float* __restrict__ lnb_h,
    const float* __restrict__ W_qk, const float* __restrict__ lnb_qk,
    const float* __restrict__ W_o,  const float* __restrict__ lnb_o,
    float* __restrict__ bias_hq, float* __restrict__ bias_o)
{
    int i = blockIdx.x;
    const float *W, *lnb; float* out; int N, n, k0;
    if (i < 64) {                   // W_h: N=2048 (8 nb), K=512 (8 kb)
        W = W_h; lnb = lnb_h; out = bias_hq; N = HID;
        n = (i & 7) * 256 + threadIdx.x; k0 = (i >> 3) * BKC;
    } else if (i < 72) {            // W_qk: N=128 (1 nb), K=512 (8 kb)
        int j = i - 64;
        W = W_qk; lnb = lnb_qk; out = bias_hq + HID; N = DQK;
        n = threadIdx.x; k0 = j * BKC;
    } else {                        // W_o: N=512 (2 nb), K=1024 (16 kb)
        int j = i - 72;
        W = W_o; lnb = lnb_o; out = bias_o; N = DIM;
        n = (j & 1) * 256 + threadIdx.x; k0 = (j >> 1) * BKC;
    }
    if (n >= N) return;
    float s = 0.f;
    #pragma unroll 8
    for (int k = k0; k < k0 + BKC; k++) s += lnb[k] * W[(size_t)k * N + n];
    atomicAdd(&out[n], s);
}

// ====== T2 pair-swizzle for 64B-row LDS tiles (rule 21: linear dest, swizzled src) =======
// Tile [R rows][32 bf16]; two rows form a 128B pair of 8 16B granules.
// Logical granule j = ((row&1)<<2)|g stored at slot j^(pair&7).
// stage: per lane, phys slot = lane&7 of pair c*8+(lane>>3) -> compute logical (row,g)
// and load from the matching GLOBAL address; LDS dest stays linear (wave base + lane*16).
__device__ __forceinline__ void stage_tile(const bf16* base, size_t ld, bf16* dst,
                                           int wave, int lane)
{
    #pragma unroll
    for (int cc = 0; cc < 2; cc++) {
        int c = wave * 2 + cc;
        int pair = c * 8 + (lane >> 3);
        int jj   = (lane & 7) ^ (pair & 7);
        int row  = pair * 2 + (jj >> 2);
        int gg   = jj & 3;
        const bf16* gp = base + (size_t)row * ld + gg * 8;
        __builtin_amdgcn_global_load_lds(AS1(gp), AS3(dst + c * 512), 16, 0, 0);
    }
}

// read logical (row, g) from a pair-swizzled tile
__device__ __forceinline__ short8 pipefrag(const bf16* h, int row, int g)
{
    int pair = row >> 1;
    int jj = ((row & 1) << 2) | g;
    return *(const short8*)(h + pair * 64 + ((jj ^ (pair & 7)) << 3));
}

// ============ shared 3-slot pipelined 128x128 GEMM core (T3/T4/T5 + T2 swizzle) ==========
#define PIPE_SLOT 8192   // As(128x32) + Bs(128x32) bf16 = 16 KiB; 3 slots = 48 KiB

__device__ __forceinline__ void pipe_core(
    const bf16* __restrict__ Abase, size_t ldA,
    const bf16* __restrict__ Bbase, size_t ldB,
    int nit, bf16* lds, int wave, int lane, float4v acc[4][4])
{
    auto stage = [&](int it, int slot) {
        bf16* As = lds + slot * PIPE_SLOT;
        stage_tile(Abase + (size_t)it * 32, ldA, As, wave, lane);
        stage_tile(Bbase + (size_t)it * 32, ldB, As + 4096, wave, lane);
    };
    stage(0, 0);
    stage(1, 1);
    asm volatile("s_waitcnt vmcnt(4)" ::: "memory");
    __builtin_amdgcn_s_barrier();
    __builtin_amdgcn_sched_barrier(0);

    int wm = wave & 1, wn = wave >> 1;
    int col = lane & 15, quad = lane >> 4;
    int slot = 0;
    for (int it = 0; it < nit; it++) {
        const bf16* As = lds + slot * PIPE_SLOT;
        const bf16* Bs = As + 4096;
        short8 a[4], b[4];
        #pragma unroll
        for (int t = 0; t < 4; t++) {
            a[t] = pipefrag(As, wm * 64 + t * 16 + col, quad);
            b[t] = pipefrag(Bs, wn * 64 + t * 16 + col, quad);
        }
        int nslot = slot + 1; if (nslot == 3) nslot = 0;
        int pslot = nslot + 1; if (pslot == 3) pslot = 0;   // (slot+2)%3
        if (it + 2 < nit) stage(it + 2, pslot);
        asm volatile("s_waitcnt lgkmcnt(0)" ::: "memory");
        __builtin_amdgcn_sched_barrier(0);
        __builtin_amdgcn_s_setprio(1);
        #pragma unroll
        for (int i = 0; i < 4; i++)
            #pragma unroll
            for (int j = 0; j < 4; j++)
                acc[i][j] = MFMA(a[i], b[j], acc[i][j], 0, 0, 0);
        __builtin_amdgcn_s_setprio(0);
        __builtin_amdgcn_sched_barrier(0);
        if (it + 2 < nit) { asm volatile("s_waitcnt vmcnt(4)" ::: "memory"); }
        else              { asm volatile("s_waitcnt vmcnt(0)" ::: "memory"); }
        __builtin_amdgcn_s_barrier();
        __builtin_amdgcn_sched_barrier(0);
        slot = nslot;
    }
}

// ---------------- pipelined MFMA GEMM: C = silu(A@B^T + bias); XCD-affine m-blocks -------
__global__ __launch_bounds__(256) void gemm_pipe(
    const bf16* __restrict__ A, const bf16* __restrict__ BT,
    const float* __restrict__ bias, bf16* __restrict__ C,
    int M, int N, int K, int ldC)
{
    __shared__ __align__(16) bf16 lds[3 * PIPE_SLOT];
    int nb = N >> 7;
    int i = blockIdx.x;
    int xcd = i & 7, r = i >> 3;
    int m0 = (xcd + 8 * (r / nb)) << 7;   // same-A-panel blocks share an XCD
    int n0 = (r % nb) << 7;
    int tid = threadIdx.x, wave = tid >> 6, lane = tid & 63;
    float4v acc[4][4] = {};
    pipe_core(A + (size_t)m0 * K, K, BT + (size_t)n0 * K, K, K / 32,
              lds, wave, lane, acc);
    int wm = wave & 1, wn = wave >> 1;
    int col = lane & 15, quad = lane >> 4;
    for (int i2 = 0; i2 < 4; i2++) {
        for (int j = 0; j < 4; j++) {
            int n = n0 + wn * 64 + j * 16 + col;
            float bs = bias[n];
            for (int r2 = 0; r2 < 4; r2++) {
                int m = m0 + wm * 64 + i2 * 16 + quad * 4 + r2;
                float v = acc[i2][j][r2] + bs;
                v = v / (1.f + __expf(-v));
                C[(size_t)m * ldC + n] = f2b(v);
            }
        }
    }
}

// ======== merged attn_score + linkv (one launch; both pipe_core; XCD-affine) =============
__global__ __launch_bounds__(256) void score_linkv(
    const bf16* __restrict__ quadq, const bf16* __restrict__ quadk,
    bf16* __restrict__ P,
    const bf16* __restrict__ hidT, const bf16* __restrict__ linkT,
    float* __restrict__ linkvT, int rowsC, int nScore)
{
    __shared__ __align__(16) bf16 lds[3 * PIPE_SLOT];
    int tid = threadIdx.x, wave = tid >> 6, lane = tid & 63;
    if ((int)blockIdx.x < nScore) {
        // ---- attn scores: P = relu(QK^T/256)^2, causal ----
        int i = blockIdx.x;
        int xcd = i & 7, r = i >> 3;
        int g = xcd + 8 * (r >> 2);
        int t = r & 3, bi = t >> 1, bj = t & 1;
        bf16* Pg = P + (size_t)g * GRP * GRP;
        if (bj > bi) {   // fully masked tile: write zeros
            short8 z = {};
            int rr = tid >> 1, half = tid & 1;
            short* dst = (short*)Pg + (size_t)(bi * 128 + rr) * GRP + bj * 128 + half * 64;
            for (int q = 0; q < 8; q++) ((short8*)dst)[q] = z;
            return;
        }
        float4v acc[4][4] = {};
        const bf16* Ab = quadq + (size_t)(g * GRP + bi * 128) * DQK;
        const bf16* Bb = quadk + (size_t)(g * GRP + bj * 128) * DQK;
        pipe_core(Ab, DQK, Bb, DQK, DQK / 32, lds, wave, lane, acc);
        int wm = wave & 1, wn = wave >> 1;
        int col = lane & 15, quad = lane >> 4;
        for (int i2 = 0; i2 < 4; i2++) {
            for (int j = 0; j < 4; j++) {
                int jj = bj * 128 + wn * 64 + j * 16 + col;
                for (int r2 = 0; r2 < 4; r2++) {
                    int ii = bi * 128 + wm * 64 + i2 * 16 + quad * 4 + r2;
                    float s = acc[i2][j][r2] * (1.f / GRP);
                    s = fmaxf(s, 0.f); s = s * s;
                    if (jj > ii) s = 0.f;
                    Pg[(size_t)ii * GRP + jj] = f2b(s);
                }
            }
        }
    } else {
        // ---- linkv: linkvT[g][e][d] = (hidT_g @ linkT_g^T)/256 ----
        int i = blockIdx.x - nScore;       // nScore % 8 == 0 -> XCD parity preserved
        int xcd = i & 7, r = i >> 3;
        int g = xcd + 8 * (r >> 4);
        int eb = r & 15;
        int e0 = eb * 128;
        float4v acc[4][4] = {};
        pipe_core(hidT + (size_t)e0 * rowsC + g * GRP, rowsC,
                  linkT + g * GRP, rowsC, GRP / 32, lds, wave, lane, acc);
        float* out = linkvT + (size_t)g * (HID * DQK);
        int wm = wave & 1, wn = wave >> 1;
        int col = lane & 15, quad = lane >> 4;
        for (int i2 = 0; i2 < 4; i2++) {
            for (int j = 0; j < 4; j++) {
                int d = wn * 64 + j * 16 + col;
                for (int r2 = 0; r2 < 4; r2++) {
                    int e = e0 + wm * 64 + i2 * 16 + quad * 4 + r2;
                    out[(size_t)e * DQK + d] = acc[i2][j][r2] * (1.f / GRP);
                }
            }
        }
    }
}

// ---------------- exclusive cumsum over group axis, fp32 in -> bf16 out (x4 vec) ---------
__global__ void cumsum_bf(const float* __restrict__ in, bf16* __restrict__ out)
{
    long idx4 = (long)blockIdx.x * blockDim.x + threadIdx.x;   // 4 elems per thread
    int b = (int)(idx4 / (DQK * HID / 4));
    long off = (idx4 % (DQK * HID / 4)) * 4;
    const float* pi = in + (long)b * NG * DQK * HID + off;
    bf16* po = out + (long)b * NG * DQK * HID + off;
    float4v run = {0.f, 0.f, 0.f, 0.f};
    for (int gi = 0; gi < NG; gi++) {
        short4v o4;
        union { short s; bf16 h; } cv;
        #pragma unroll
        for (int k = 0; k < 4; k++) { cv.h = f2b(run[k]); o4[k] = cv.s; }
        *(short4v*)(po + (long)gi * DQK * HID) = o4;
        run += *(const float4v*)(pi + (long)gi * DQK * HID);
    }
}

// ---------------- fused attn apply MFMA + gating — 3-slot pipelined + T2 swizzle ---------
#define AP_SLOT (256 * BK + 128 * BK)   // 12288 bf16 = 24 KiB per slot

__global__ __launch_bounds__(256) void attn_apply_mfma(
    const bf16* __restrict__ P, const bf16* __restrict__ hidT,
    const bf16* __restrict__ linq, const bf16* __restrict__ linkvb,
    bf16* __restrict__ outg, int rowsC)
{
    int ib = blockIdx.x;
    int xcd = ib & 7, rb = ib >> 3;
    int g = xcd + 8 * (rb >> 4);          // all 16 e-blocks of a group share an XCD
    int e0 = (rb & 15) * 64;
    __shared__ __align__(16) bf16 lds[3 * AP_SLOT];
    int tid = threadIdx.x, wave = tid >> 6, lane = tid & 63;
    const bf16* Pg = P + (size_t)g * GRP * GRP;
    const bf16* Lg = linkvb + (size_t)g * (HID * DQK);

    // stage iteration 'it' (0..7: quad j0=it*32; 8..11: lin d0=(it-8)*32) into 'slot'
    // LDS dest linear; global source inverse-permuted (pair swizzle, rule 21)
    auto stage = [&](int it, int slot) {
        bf16* As = lds + slot * AP_SLOT;
        bf16* Bs = As + 256 * BK;
        if (it < 8) {
            int j0 = it * 32;
            for (int cc = 0; cc < 4; cc++) {
                int c = wave * 4 + cc;
                int pair = c * 8 + (lane >> 3);
                int jj = (lane & 7) ^ (pair & 7);
                int row = pair * 2 + (jj >> 2);
                int gg = jj & 3;
                const bf16* ga = Pg + (size_t)row * GRP + j0 + gg * 8;
                __builtin_amdgcn_global_load_lds(AS1(ga), AS3(As + c * 512), 16, 0, 0);
            }
            for (int cc = 0; cc < 2; cc++) {
                int c = wave * 2 + cc;
                int pair = c * 8 + (lane >> 3);
                int jj = (lane & 7) ^ (pair & 7);
                int row = pair * 2 + (jj >> 2);
                int gg = jj & 3;
                int er = (row < 64) ? (e0 + row) : (1024 + e0 + (row - 64));
                const bf16* gb = hidT + (size_t)er * rowsC + g * GRP + j0 + gg * 8;
                __builtin_amdgcn_global_load_lds(AS1(gb), AS3(Bs + c * 512), 16, 0, 0);
            }
        } else {
            int d0 = (it - 8) * 32;
            for (int cc = 0; cc < 4; cc++) {
                int c = wave * 4 + cc;
                int pair = c * 8 + (lane >> 3);
                int jj = (lane & 7) ^ (pair & 7);
                int row = pair * 2 + (jj >> 2);
                int gg = jj & 3;
                const bf16* ga = linq + (size_t)(g * GRP + row) * DQK + d0 + gg * 8;
                __builtin_amdgcn_global_load_lds(AS1(ga), AS3(As + c * 512), 16, 0, 0);
            }
            for (int cc = 0; cc < 2; cc++) {
                int c = wave * 2 + cc;
                int pair = c * 8 + (lane >> 3);
                int jj = (lane & 7) ^ (pair & 7);
                int row = pair * 2 + (jj >> 2);
                int gg = jj & 3;
                int er = (row < 64) ? (e0 + row) : (1024 + e0 + (row - 64));
                const bf16* gb = Lg + (size_t)er * DQK + d0 + gg * 8;
                __builtin_amdgcn_global_load_lds(AS1(gb), AS3(Bs + c * 512), 16, 0, 0);
            }
        }
    };

    // prologue: slots 0 and 1 in flight; wait for slot 0 (6 loads of slot1 may remain)
    stage(0, 0);
    stage(1, 1);
    asm volatile("s_waitcnt vmcnt(6)" ::: "memory");
    __builtin_amdgcn_s_barrier();
    __builtin_amdgcn_sched_barrier(0);

    float4v acc[4][8] = {};
    int col = lane & 15, quad = lane >> 4;
    int slot = 0;
    for (int it = 0; it < 12; it++) {
        const bf16* As = lds + slot * AP_SLOT;
        const bf16* Bs = As + 256 * BK;
        short8 a[4], b[8];
        #pragma unroll
        for (int t = 0; t < 4; t++)
            a[t] = pipefrag(As, wave * 64 + t * 16 + col, quad);
        #pragma unroll
        for (int t = 0; t < 8; t++)
            b[t] = pipefrag(Bs, t * 16 + col, quad);
        int nslot = slot + 1; if (nslot == 3) nslot = 0;
        int pslot = nslot + 1; if (pslot == 3) pslot = 0;   // (slot+2)%3
        if (it + 2 < 12) stage(it + 2, pslot);
        asm volatile("s_waitcnt lgkmcnt(0)" ::: "memory");
        __builtin_amdgcn_sched_barrier(0);
        __builtin_amdgcn_s_setprio(1);
        #pragma unroll
        for (int i = 0; i < 4; i++)
            #pragma unroll
            for (int j = 0; j < 8; j++)
                acc[i][j] = MFMA(a[i], b[j], acc[i][j], 0, 0, 0);
        __builtin_amdgcn_s_setprio(0);
        __builtin_amdgcn_sched_barrier(0);
        if (it + 2 < 12) { asm volatile("s_waitcnt vmcnt(6)" ::: "memory"); }
        else             { asm volatile("s_waitcnt vmcnt(0)" ::: "memory"); }
        __builtin_amdgcn_s_barrier();
        __builtin_amdgcn_sched_barrier(0);
        slot = nslot;
    }

    // epilogue with gating: v,u loaded as short4 over the 4 consecutive tokens (r dim)
    for (int mt = 0; mt < 4; mt++) {
        int tokg0 = g * GRP + wave * 64 + mt * 16 + quad * 4;
        for (int nt = 0; nt < 4; nt++) {
            int e = e0 + nt * 16 + col;
            union { short4v v; bf16 h[4]; } v4, u4;
            v4.v = *(const short4v*)(hidT + (size_t)e * rowsC + tokg0);
            u4.v = *(const short4v*)(hidT + (size_t)(1024 + e) * rowsC + tokg0);
            #pragma unroll
            for (int r = 0; r < 4; r++) {
                float av = acc[mt][nt][r];
                float au = acc[mt][nt + 4][r];
                float v = b2f(v4.h[r]);
                float u = b2f(u4.h[r]);
                float gate = 1.f / (1.f + __expf(-av * u));
                outg[(size_t)(tokg0 + r) * 1024 + e] = f2b(au * v * gate);
            }
        }
    }
}

// ======== merged dwconv: h-path (hidT only) + qk-path (affine split), one launch =========
__global__ __launch_bounds__(256) void dwconv_both(
    const bf16* __restrict__ hq, const float* __restrict__ dw_h,
    bf16* __restrict__ hidT,
    const float* __restrict__ dw_qk,
    const float* __restrict__ gamma, const float* __restrict__ beta,
    bf16* __restrict__ quadq, bf16* __restrict__ quadk,
    bf16* __restrict__ linq, bf16* __restrict__ linkT,
    int rowsC, int nDual)
{
    __shared__ float s[80][64];
    __shared__ bf16 o[64][72];   // [ch][tok], row stride 144 B (16B-aligned)
    int tid = threadIdx.x;
    if ((int)blockIdx.x < nDual) {
        // ---- h path: hidT = h + dwconv(h), transposed write only ----
        int i = blockIdx.x;
        int c0 = (i & 31) * 64;            // HID/64 = 32
        int t0 = ((i >> 5) & 31) * 64;     // NN/64 = 32
        int b  = i >> 10;
        const bf16* base = hq + (size_t)b * NN * NHQ + c0;
        {
            int ch8 = (tid & 7) * 8, rw = tid >> 3;
            #pragma unroll
            for (int ps = 0; ps < 3; ps++) {
                int tt = rw + ps * 32;
                if (tt < 80) {
                    int t = t0 + tt - 8;
                    union { short8 v; bf16 h[8]; } u; u.v = short8{};
                    if (t >= 0 && t < NN)
                        u.v = *(const short8*)(base + (size_t)t * NHQ + ch8);
                    float* sp = &s[tt][ch8];
                    #pragma unroll
                    for (int k = 0; k < 8; k++) sp[k] = b2f(u.h[k]);
                }
            }
        }
        __syncthreads();
        int c = tid & 63, rp = tid >> 6;
        float w[KW];
        for (int k = 0; k < KW; k++) w[k] = dw_h[k * HID + c0 + c];
        for (int l = 0; l < 16; l++) {
            int r = rp + l * 4;
            float acc = s[r + 8][c];
            for (int k = 0; k < KW; k++) acc += s[r + k][c] * w[k];
            o[c][r] = f2b(acc);
        }
        __syncthreads();
        // write hidT (ch-major [ch][rowsC]) as short8
        {
            int t8 = (tid & 7) * 8, ch = tid >> 3;
            #pragma unroll
            for (int ps = 0; ps < 2; ps++) {
                int cc = ch + ps * 32;
                short8 v = *(const short8*)(&o[cc][t8]);
                *(short8*)(hidT + (size_t)(c0 + cc) * rowsC + b * NN + t0 + t8) = v;
            }
        }
    } else {
        // ---- qk path: conv + 4-way affine -> quadq/quadk/linq/linkT ----
        int i = blockIdx.x - nDual;
        int c0 = (i & 1) * 64;             // DQK/64 = 2
        int t0 = ((i >> 1) & 31) * 64;
        int b  = i >> 6;
        const bf16* base = hq + HID + (size_t)b * NN * NHQ + c0;
        {
            int ch8 = (tid & 7) * 8, rw = tid >> 3;
            #pragma unroll
            for (int ps = 0; ps < 3; ps++) {
                int tt = rw + ps * 32;
                if (tt < 80) {
                    int t = t0 + tt - 8;
                    union { short8 v; bf16 h[8]; } u; u.v = short8{};
                    if (t >= 0 && t < NN)
                        u.v = *(const short8*)(base + (size_t)t * NHQ + ch8);
                    float* sp = &s[tt][ch8];
                    #pragma unroll
                    for (int k = 0; k < 8; k++) sp[k] = b2f(u.h[k]);
                }
            }
        }
        __syncthreads();
        int c = tid & 63, rp = tid >> 6;
        float w[KW];
        for (int k = 0; k < KW; k++) w[k] = dw_qk[k * DQK + c0 + c];
        float ga0 = gamma[0 * DQK + c0 + c], be0 = beta[0 * DQK + c0 + c];
        float ga1 = gamma[1 * DQK + c0 + c], be1 = beta[1 * DQK + c0 + c];
        float ga2 = gamma[2 * DQK + c0 + c], be2 = beta[2 * DQK + c0 + c];
        float ga3 = gamma[3 * DQK + c0 + c], be3 = beta[3 * DQK + c0 + c];
        for (int l = 0; l < 16; l++) {
            int r = rp + l * 4;
            float acc = s[r + 8][c];
            for (int k = 0; k < KW; k++) acc += s[r + k][c] * w[k];
            size_t tok = (size_t)b * NN + t0 + r;
            quadq[tok * DQK + c0 + c] = f2b(acc * ga0 + be0);
            linq [tok * DQK + c0 + c] = f2b(acc * ga1 + be1);
            quadk[tok * DQK + c0 + c] = f2b(acc * ga2 + be2);
            o[c][r] = f2b(acc * ga3 + be3);
        }
        __syncthreads();
        // transposed write of linkT rows c0..c0+63
        int t8 = (tid & 7) * 8, ch = tid >> 3;
        #pragma unroll
        for (int ps = 0; ps < 2; ps++) {
            int cc = ch + ps * 32;
            short8 v = *(const short8*)(&o[cc][t8]);
            *(short8*)(linkT + (size_t)(c0 + cc) * rowsC + b * NN + t0 + t8) = v;
        }
    }
}

// ---------------- dwconv (generic, vectorized staging) -----------------------------------
template<typename TO>
__global__ __launch_bounds__(256) void dwconv_res(
    const bf16* __restrict__ src, const float* __restrict__ dw,
    const float* __restrict__ xres, TO* __restrict__ dst, int C, int ldS)
{
    int c0 = blockIdx.x * 64;
    int t0 = blockIdx.y * 64;
    int b  = blockIdx.z;
    __shared__ float s[80][64];
    int tid = threadIdx.x;
    int c = tid & 63;
    int rp = tid >> 6;
    const bf16* base = src + (size_t)b * NN * ldS + c0;
    {
        int ch8 = (tid & 7) * 8, rw = tid >> 3;
        #pragma unroll
        for (int ps = 0; ps < 3; ps++) {
            int tt = rw + ps * 32;
            if (tt < 80) {
                int t = t0 + tt - 8;
                union { short8 v; bf16 h[8]; } u; u.v = short8{};
                if (t >= 0 && t < NN)
                    u.v = *(const short8*)(base + (size_t)t * ldS + ch8);
                float* sp = &s[tt][ch8];
                #pragma unroll
                for (int k = 0; k < 8; k++) sp[k] = b2f(u.h[k]);
            }
        }
    }
    __syncthreads();
    float w[KW];
    for (int k = 0; k < KW; k++) w[k] = dw[k * C + c0 + c];
    for (int l = 0; l < 16; l++) {
        int r = rp + l * 4;
        float acc = s[r + 8][c];
        for (int k = 0; k < KW; k++) acc += s[r + k][c] * w[k];
        long gidx = ((long)b * NN + t0 + r) * C + c0 + c;
        if (xres) acc += xres[gidx];
        stv(dst, gidx, acc);
    }
}

extern "C" void kernel_launch(void* const* d_in, const int* in_sizes, int n_in,
                              void* d_out, int out_size, void* d_ws, size_t ws_size,
                              hipStream_t stream)
{
    const float* x      = (const float*)d_in[0];
    const float* ln_h_g = (const float*)d_in[1];
    const float* ln_h_b = (const float*)d_in[2];
    const float* W_h    = (const float*)d_in[3];
    const float* b_h    = (const float*)d_in[4];
    const float* dw_h   = (const float*)d_in[5];
    const float* ln_qk_g= (const float*)d_in[6];
    const float* ln_qk_b= (const float*)d_in[7];
    const float* W_qk   = (const float*)d_in[8];
    const float* b_qk   = (const float*)d_in[9];
    const float* dw_qk  = (const float*)d_in[10];
    const float* gamma  = (const float*)d_in[11];
    const float* beta   = (const float*)d_in[12];
    const float* ln_o_g = (const float*)d_in[13];
    const float* ln_o_b = (const float*)d_in[14];
    const float* W_o    = (const float*)d_in[15];
    const float* b_o    = (const float*)d_in[16];
    const float* dw_o   = (const float*)d_in[17];
    float* outp = (float*)d_out;

    // ---- fixed region ----
    char* p = (char*)d_ws;
    bf16* WT_hq = (bf16*)p;  p += (size_t)NHQ * DIM * 2;
    bf16* WT_o  = (bf16*)p;  p += (size_t)DIM * 1024 * 2;
    float* bias_hq = (float*)p; p += NHQ * 4;
    float* bias_o  = (float*)p; p += DIM * 4;
    p = (char*)(((uintptr_t)p + 255) & ~(uintptr_t)255);
    size_t fixed = (size_t)(p - (char*)d_ws);
    bf16* WT_h  = WT_hq;
    bf16* WT_qk = WT_hq + (size_t)HID * DIM;

    auto bytes_for = [fixed](int cb) -> size_t {
        size_t rows = (size_t)cb * NN;
        return fixed
             + rows * NHQ * 2           // s1 hq / linkvT / fin_pre
             + rows * 1024 * 2          // s2 hat1 -> hat2
             + rows * HID * 2           // s3 hidT
             + rows * 1024 * 2          // s4 outg
             + (size_t)cb * NG * GRP * GRP * 2   // s5 P
             + 4 * rows * DQK * 2       // s6 linkT + quadq/quadk/linq
             + rows * 1024 * 2          // s11 linkvb
             + 4096;
    };
    int CB = 1;
    if (bytes_for(8) <= ws_size) CB = 8;
    else if (bytes_for(4) <= ws_size) CB = 4;
    else if (bytes_for(2) <= ws_size) CB = 2;
    const int rowsC = CB * NN;
    const size_t rows = (size_t)rowsC;

    char* s1 = p;               p += rows * NHQ * 2;   // hq -> linkvT -> fin_pre
    char* s2 = p;               p += rows * 1024 * 2;  // hat1 (512-wide) -> hat2 (1024-wide)
    char* s3 = p;               p += rows * HID * 2;   // hidT
    char* s4 = p;               p += rows * 1024 * 2;  // outg
    char* s5 = p;               p += (size_t)CB * NG * GRP * GRP * 2;  // P
    char* s6 = p;               p += rows * DQK * 2;   // linkT
    char* s8 = p;               p += rows * DQK * 2;   // quadq
    char* s9 = p;               p += rows * DQK * 2;   // quadk
    char* s10 = p;              p += rows * DQK * 2;   // linq
    char* s11 = p;              p += rows * 1024 * 2;  // linkvb (bf16 cumsum out)

    bf16*  hq      = (bf16*)s1;
    float* linkvT  = (float*)s1;
    bf16*  fin_pre = (bf16*)s1;
    bf16*  hat1    = (bf16*)s2;   // dead after step 2; hat2 overwrites at step 10
    bf16*  hat2    = (bf16*)s2;
    bf16*  hidT    = (bf16*)s3;
    bf16*  outg    = (bf16*)s4;
    bf16*  P       = (bf16*)s5;
    bf16*  linkT   = (bf16*)s6;
    bf16*  quadq   = (bf16*)s8;
    bf16*  quadk   = (bf16*)s9;
    bf16*  linq    = (bf16*)s10;
    bf16*  linkvb  = (bf16*)s11;

    // ---- weight prep: 3 launches total ----
    prep_all<<<1600, 256, 0, stream>>>(W_h, ln_h_g, WT_h,
                                       W_qk, ln_qk_g, WT_qk,
                                       W_o, ln_o_g, WT_o);
    bias_init3<<<(NHQ + DIM + 255) / 256, 256, 0, stream>>>(b_h, b_qk, b_o, bias_hq, bias_o);
    bias_reduce3<<<104, 256, 0, stream>>>(W_h, ln_h_b, W_qk, ln_qk_b, W_o, ln_o_b,
                                          bias_hq, bias_o);

    const int G = CB * NG;   // groups per chunk
    for (int b0 = 0; b0 < BB; b0 += CB) {
        const float* xc = x    + (size_t)b0 * NN * DIM;
        float* outc     = outp + (size_t)b0 * NN * DIM;
        int R = rowsC;

        // 1) LN of token-shifted x -> hat1 (s2)
        ln_kernel_f<DIM, 1><<<R, 256, 0, stream>>>(xc, hat1);
        // 2) merged h+qk GEMM on pipe_core (48 KiB LDS; N = 17 x 128)
        gemm_pipe<<<dim3((R / 128) * (NHQ / 128)), 256, 0, stream>>>(
            hat1, WT_hq, bias_hq, hq, R, NHQ, DIM, NHQ);
        // 3+4+5) merged dwconv: h transposed-write + qk conv+affine
        {
            int nDual = (HID / 64) * (NN / 64) * CB;
            int nQk   = (DQK / 64) * (NN / 64) * CB;
            dwconv_both<<<nDual + nQk, 256, 0, stream>>>(
                hq, dw_h, hidT, dw_qk, gamma, beta,
                quadq, quadk, linq, linkT, rowsC, nDual);
        }
        // 6+7) merged scores + linkv (both depend only on dwconv outputs)
        score_linkv<<<4 * G + 16 * G, 256, 0, stream>>>(
            quadq, quadk, P, hidT, linkT, linkvT, rowsC, 4 * G);
        // 8) exclusive cumsum over groups -> linkvb bf16
        cumsum_bf<<<(CB * DQK * HID) / (256 * 4), 256, 0, stream>>>(linkvT, linkvb);
        // 9) fused apply + gating -> outg (v,u from hidT), XCD-affine per group
        attn_apply_mfma<<<dim3(16 * G), 256, 0, stream>>>(P, hidT, linq, linkvb, outg, rowsC);
        // 10) LN(outg) -> hat2 (overwrites hat1, which is dead)
        ln_kernel_bf<1024><<<R, 256, 0, stream>>>(outg, hat2);
        // 11) fin_pre = silu(hat2 @ W_o' + bias_o')
        gemm_pipe<<<dim3((DIM / 128) * (R / 128)), 256, 0, stream>>>(
            hat2, WT_o, bias_o, fin_pre, R, DIM, 1024, DIM);
        // 12) d_out(fp32) = x + fin_pre + dwconv(fin_pre)
        dwconv_res<float><<<dim3(DIM / 64, NN / 64, CB), 256, 0, stream>>>(
            fin_pre, dw_o, xc, outc, DIM, DIM);
    }
}